// Round 8
// baseline (956.858 us; speedup 1.0000x reference)
//
#include <hip/hip_runtime.h>
#include <math.h>

// ProGAT: B=8,S=512,NB=23,INIT=512,E=256,R=3,T=2
// R8: mega-kernel with HAND-ROLLED agent-scope grid barrier (~2-4us) instead
// of cg::grid.sync (~63us measured in R7). Convert folded in as phase P0.

#define BSZ   8
#define SEQ   512
#define NBR   23
#define EMB   256
#define INITD 512
#define BS    (BSZ*SEQ)     // 4096
#define G3    (3*EMB)       // 768
#define NEGV  -9e8f

typedef __attribute__((ext_vector_type(8))) short short8;
typedef __attribute__((ext_vector_type(4))) float f32x4;

__device__ __forceinline__ float lrelu(float x){ return x > 0.f ? x : 0.01f*x; }
__device__ __forceinline__ float elu1 (float x){ return x > 0.f ? x : (expf(x)-1.f); }
__device__ __forceinline__ float sigm (float x){ return 1.f/(1.f+expf(-x)); }
__device__ __forceinline__ float bf2f(ushort u){
    union { unsigned int i; float f; } v; v.i = ((unsigned int)u) << 16; return v.f;
}
__device__ __forceinline__ ushort f2bf(float f){
    union { float f; unsigned int i; } v; v.f = f;
    unsigned int u = v.i;
    return (ushort)((u + 0x7FFFu + ((u >> 16) & 1u)) >> 16);   // RNE
}

__device__ __forceinline__ void gload_lds16(const void* g, void* l) {
    __builtin_amdgcn_global_load_lds(
        (const __attribute__((address_space(1))) unsigned int*)g,
        (__attribute__((address_space(3))) unsigned int*)l,
        16, 0, 0);
}

// sense-reversing grid barrier; cnt/gen in global memory, agent scope.
// Requires all blocks co-resident (cooperative launch).
__device__ __forceinline__ void grid_barrier(unsigned* cnt, unsigned* gen, unsigned nb) {
    __syncthreads();
    if (threadIdx.x == 0) {
        unsigned g = __hip_atomic_load(gen, __ATOMIC_ACQUIRE, __HIP_MEMORY_SCOPE_AGENT);
        unsigned arrived = __hip_atomic_fetch_add(cnt, 1u, __ATOMIC_ACQ_REL, __HIP_MEMORY_SCOPE_AGENT);
        if (arrived == nb - 1u) {
            __hip_atomic_store(cnt, 0u, __ATOMIC_RELAXED, __HIP_MEMORY_SCOPE_AGENT);
            __hip_atomic_fetch_add(gen, 1u, __ATOMIC_ACQ_REL, __HIP_MEMORY_SCOPE_AGENT);
        } else {
            while (__hip_atomic_load(gen, __ATOMIC_ACQUIRE, __HIP_MEMORY_SCOPE_AGENT) == g)
                __builtin_amdgcn_s_sleep(2);
        }
    }
    __syncthreads();
}

template<int BN> struct GemmLdsT {
    ushort A[2][128][64];
    ushort B[2][BN][64];
};

union MegaLds {
    GemmLdsT<128> g;                                      // 64 KiB
    struct { float w_s[SEQ]; float red[256]; } pv;
    struct { float xs[EMB]; float hs[EMB]; float gis[192]; float ghs[192]; } st;
    float red256[256];
};

// grid-stride fp32->bf16 segment convert
__device__ __forceinline__ void conv_seg(const float* __restrict__ s,
                                         ushort* __restrict__ d, int n,
                                         int bid, int gsz)
{
    for (size_t i = ((size_t)bid * 256 + threadIdx.x) * 8; i < (size_t)n;
         i += (size_t)gsz * 256 * 8) {
        float4 a = *reinterpret_cast<const float4*>(s + i);
        float4 b = *reinterpret_cast<const float4*>(s + i + 4);
        uint4 o;
        o.x = (unsigned)f2bf(a.x) | ((unsigned)f2bf(a.y) << 16);
        o.y = (unsigned)f2bf(a.z) | ((unsigned)f2bf(a.w) << 16);
        o.z = (unsigned)f2bf(b.x) | ((unsigned)f2bf(b.y) << 16);
        o.w = (unsigned)f2bf(b.z) | ((unsigned)f2bf(b.w) << 16);
        *reinterpret_cast<uint4*>(d + i) = o;
    }
}

// ---- C = act(A @ W^T + bias); MFMA 16x16x32 bf16, 128xBN tile, BK=64,
// global_load_lds staging (linear dest, inverse-swizzled source), dbuf.
template<int BN, int ACT, bool WF32, bool WBF>
__device__ __forceinline__ void gemm_dev(
    const ushort* __restrict__ A, const ushort* __restrict__ W,
    const float* __restrict__ bias,
    float* __restrict__ C, ushort* __restrict__ Cbf,
    int N, int K, int bx, int by, GemmLdsT<BN>& L)
{
    constexpr int FN = BN / 32;
    const int tid = threadIdx.x;
    const int m0 = bx * 128, n0 = by * BN;
    const int wv = tid >> 6, lane = tid & 63;
    const int fr = lane & 15, grp = lane >> 4;
    const int kc = K >> 3;
    const int mh = wv & 1, nh = wv >> 1;
    const int lrow = lane >> 3;
    const int csrc = (lane & 7) ^ lrow;

    f32x4 acc[4][FN];
    #pragma unroll
    for (int i = 0; i < 4; ++i)
        #pragma unroll
        for (int n = 0; n < FN; ++n) acc[i][n] = (f32x4){0.f,0.f,0.f,0.f};

    auto stage = [&](int c, int k0) {
        const int kch = (k0 >> 3) + csrc;
        #pragma unroll
        for (int i = 0; i < 4; ++i) {
            const int s = (wv << 2) + i;
            const ushort* g = A + ((size_t)(m0 + (s << 3) + lrow) * kc + kch) * 8;
            gload_lds16(g, &L.A[c][s << 3][0]);
        }
        #pragma unroll
        for (int i = 0; i < FN; ++i) {
            const int s = wv * FN + i;
            const ushort* g = W + ((size_t)(n0 + (s << 3) + lrow) * kc + kch) * 8;
            gload_lds16(g, &L.B[c][s << 3][0]);
        }
    };

    auto compute = [&](int c) {
        #pragma unroll
        for (int ks = 0; ks < 2; ++ks) {
            short8 af[4];
            #pragma unroll
            for (int i = 0; i < 4; ++i) {
                const int ar = (mh << 6) + (i << 4) + fr;
                af[i] = *reinterpret_cast<const short8*>(
                    &L.A[c][ar][(((ks << 2) + grp) ^ (ar & 7)) << 3]);
            }
            #pragma unroll
            for (int n = 0; n < FN; ++n) {
                const int br = nh * (BN/2) + (n << 4) + fr;
                short8 bv = *reinterpret_cast<const short8*>(
                    &L.B[c][br][(((ks << 2) + grp) ^ (br & 7)) << 3]);
                #pragma unroll
                for (int i = 0; i < 4; ++i)
                    acc[i][n] = __builtin_amdgcn_mfma_f32_16x16x32_bf16(
                        af[i], bv, acc[i][n], 0, 0, 0);
            }
        }
    };

    const int KT = K >> 6;
    stage(0, 0);
    __syncthreads();
    int cur = 0;
    for (int kt = 1; kt < KT; ++kt) {
        stage(cur ^ 1, kt << 6);
        compute(cur);
        __syncthreads();
        cur ^= 1;
    }
    compute(cur);

    // D layout (m89): col = lane&15, row = (lane>>4)*4 + j
    #pragma unroll
    for (int i = 0; i < 4; ++i) {
        const int mrow = m0 + (mh << 6) + (i << 4) + (grp << 2);
        #pragma unroll
        for (int n = 0; n < FN; ++n) {
            const int col = n0 + nh * (BN/2) + (n << 4) + fr;
            const float bv = bias[col];
            #pragma unroll
            for (int j = 0; j < 4; ++j) {
                float t = acc[i][n][j] + bv;
                if (ACT == 1) t = lrelu(t);
                size_t off = (size_t)(mrow + j) * N + col;
                if (WF32) C[off] = t;
                if (WBF)  Cbf[off] = f2bf(t);
            }
        }
    }
}

// dot2: 32 rows per vb (4 waves x 8 rows)
__device__ __forceinline__ void dot2_body(
    int b, const float* __restrict__ center, const float* __restrict__ nbrbase,
    const float* __restrict__ alignWd, float* __restrict__ cdot, float* __restrict__ ndot)
{
    const int lane = threadIdx.x & 63;
    const int wv   = threadIdx.x >> 6;
    const int e    = lane << 2;
    const int rb   = b * 32 + wv * 8;
    float4 w0 = *reinterpret_cast<const float4*>(&alignWd[e]);
    float4 w1 = *reinterpret_cast<const float4*>(&alignWd[EMB + e]);
    #pragma unroll
    for (int i = 0; i < 8; ++i) {
        const int r = rb + i;
        float4 xc = *reinterpret_cast<const float4*>(&center[(size_t)r*EMB + e]);
        float4 xn = *reinterpret_cast<const float4*>(&nbrbase[(size_t)r*EMB + e]);
        float ac = xc.x*w0.x + xc.y*w0.y + xc.z*w0.z + xc.w*w0.w;
        float an = xn.x*w1.x + xn.y*w1.y + xn.z*w1.z + xn.w*w1.w;
        #pragma unroll
        for (int off = 32; off; off >>= 1) {
            ac += __shfl_xor(ac, off, 64);
            an += __shfl_xor(an, off, 64);
        }
        if (lane == 0) { cdot[r] = ac; ndot[r] = an; }
    }
}

// attn: 8 rows per vb (4 waves x 2 rows)
__device__ __forceinline__ void attn_body(
    int vb, const float* __restrict__ cdot, const float* __restrict__ ndot,
    const int* __restrict__ idx, const ushort* __restrict__ nt,
    float alignBd, ushort* __restrict__ ctxbf)
{
    const int lane = threadIdx.x & 63;
    const int wv   = threadIdx.x >> 6;
    #pragma unroll
    for (int it = 0; it < 2; ++it) {
        const int r = vb*8 + wv*2 + it;
        const int b = r >> 9;
        float sc = -3e38f, vm = 0.f; int row = 0;
        if (lane < NBR) {
            int j = idx[(size_t)r*NBR + lane];
            int valid = (j >= 0);
            int jj = valid ? j : j + SEQ;   // JAX wrap: f[-1] = last row
            row = b*SEQ + jj;
            vm = (float)valid;
            sc = lrelu(cdot[r] + ndot[row] + alignBd) + (valid ? 0.f : NEGV);
        }
        float m = sc;
        #pragma unroll
        for (int off = 32; off; off >>= 1) m = fmaxf(m, __shfl_xor(m, off, 64));
        float ev = (lane < NBR) ? expf(sc - m) : 0.f;
        float s = ev;
        #pragma unroll
        for (int off = 32; off; off >>= 1) s += __shfl_xor(s, off, 64);
        float wgt = ev * vm / s;
        float acc0 = 0.f, acc1 = 0.f, acc2 = 0.f, acc3 = 0.f;
        const int e = lane << 2;
        #pragma unroll 1
        for (int n = 0; n < NBR; ++n) {
            float wn = __shfl(wgt, n, 64);
            int   rn = __shfl(row, n, 64);
            ushort4 v = *reinterpret_cast<const ushort4*>(&nt[(size_t)rn*EMB + e]);
            acc0 += wn * bf2f(v.x); acc1 += wn * bf2f(v.y);
            acc2 += wn * bf2f(v.z); acc3 += wn * bf2f(v.w);
        }
        uint2 o;
        o.x = (unsigned)f2bf(elu1(acc0)) | ((unsigned)f2bf(elu1(acc1)) << 16);
        o.y = (unsigned)f2bf(elu1(acc2)) | ((unsigned)f2bf(elu1(acc3)) << 16);
        *reinterpret_cast<uint2*>(&ctxbf[(size_t)r*EMB + e]) = o;
    }
}

// gru: 8 rows per vb (4 waves x 2 rows)
__device__ __forceinline__ void gru_body(
    int vb, const ushort* __restrict__ gibf, const ushort* __restrict__ ghbf,
    const float* __restrict__ hprev,
    float* __restrict__ hout, ushort* __restrict__ hbf,
    float* __restrict__ actout, ushort* __restrict__ actbf)
{
    #pragma unroll
    for (int it = 0; it < 2; ++it) {
        const size_t r = (size_t)vb*8 + it*4 + (threadIdx.x >> 6);
        const int    e = (threadIdx.x & 63) << 2;
        const size_t gb = r*G3 + e, hb = r*EMB + e;
        ushort4 ir4 = *reinterpret_cast<const ushort4*>(&gibf[gb]);
        ushort4 iz4 = *reinterpret_cast<const ushort4*>(&gibf[gb + EMB]);
        ushort4 in4 = *reinterpret_cast<const ushort4*>(&gibf[gb + 2*EMB]);
        ushort4 hr4 = *reinterpret_cast<const ushort4*>(&ghbf[gb]);
        ushort4 hz4 = *reinterpret_cast<const ushort4*>(&ghbf[gb + EMB]);
        ushort4 hn4 = *reinterpret_cast<const ushort4*>(&ghbf[gb + 2*EMB]);
        float4 hp4 = *reinterpret_cast<const float4*>(&hprev[hb]);
        const float ir_[4] = {bf2f(ir4.x),bf2f(ir4.y),bf2f(ir4.z),bf2f(ir4.w)};
        const float iz_[4] = {bf2f(iz4.x),bf2f(iz4.y),bf2f(iz4.z),bf2f(iz4.w)};
        const float in_[4] = {bf2f(in4.x),bf2f(in4.y),bf2f(in4.z),bf2f(in4.w)};
        const float hr_[4] = {bf2f(hr4.x),bf2f(hr4.y),bf2f(hr4.z),bf2f(hr4.w)};
        const float hz_[4] = {bf2f(hz4.x),bf2f(hz4.y),bf2f(hz4.z),bf2f(hz4.w)};
        const float hn_[4] = {bf2f(hn4.x),bf2f(hn4.y),bf2f(hn4.z),bf2f(hn4.w)};
        const float hp_[4] = {hp4.x,hp4.y,hp4.z,hp4.w};
        float hv[4], av[4];
        #pragma unroll
        for (int i = 0; i < 4; ++i) {
            float rg = sigm(ir_[i] + hr_[i]);
            float z  = sigm(iz_[i] + hz_[i]);
            float n  = tanhf(in_[i] + rg*hn_[i]);
            hv[i] = (1.f - z)*n + z*hp_[i];
            av[i] = fmaxf(hv[i], 0.f);
        }
        *reinterpret_cast<float4*>(&hout[hb])   = make_float4(hv[0],hv[1],hv[2],hv[3]);
        *reinterpret_cast<float4*>(&actout[hb]) = make_float4(av[0],av[1],av[2],av[3]);
        uint2 hp, ap;
        hp.x = (unsigned)f2bf(hv[0]) | ((unsigned)f2bf(hv[1]) << 16);
        hp.y = (unsigned)f2bf(hv[2]) | ((unsigned)f2bf(hv[3]) << 16);
        ap.x = (unsigned)f2bf(av[0]) | ((unsigned)f2bf(av[1]) << 16);
        ap.y = (unsigned)f2bf(av[2]) | ((unsigned)f2bf(av[3]) << 16);
        *reinterpret_cast<uint2*>(&hbf[hb])   = hp;
        *reinterpret_cast<uint2*>(&actbf[hb]) = ap;
    }
}

// seqsum: one vb per batch
__device__ __forceinline__ void seqsum_body(
    int b, const float* __restrict__ act, const float* __restrict__ mask,
    const float* __restrict__ saW, float* __restrict__ seqfeat,
    float* __restrict__ cmol, float* red)
{
    const int e = threadIdx.x;
    float acc = 0.f;
    for (int s = 0; s < SEQ; ++s)
        acc += act[((size_t)b*SEQ + s)*EMB + e] * mask[b*SEQ + s];
    seqfeat[b*EMB + e] = acc;
    red[e] = fmaxf(acc, 0.f) * saW[e];
    __syncthreads();
    for (int off = 128; off; off >>= 1) {
        if (e < off) red[e] += red[e + off];
        __syncthreads();
    }
    if (e == 0) cmol[b] = red[0];
}

// seqscore: 32 rows per vb
__device__ __forceinline__ void seqscore_body(
    int b2, const float* __restrict__ act, const float* __restrict__ saW,
    float* __restrict__ ad)
{
    const int lane = threadIdx.x & 63;
    const int wv   = threadIdx.x >> 6;
    const int e    = lane << 2;
    const int rb   = b2 * 32 + wv * 8;
    float4 w1 = *reinterpret_cast<const float4*>(&saW[EMB + e]);
    #pragma unroll
    for (int i = 0; i < 8; ++i) {
        const int r = rb + i;
        float4 xa = *reinterpret_cast<const float4*>(&act[(size_t)r*EMB + e]);
        float an = xa.x*w1.x + xa.y*w1.y + xa.z*w1.z + xa.w*w1.w;
        #pragma unroll
        for (int off = 32; off; off >>= 1) an += __shfl_xor(an, off, 64);
        if (lane == 0) ad[r] = an;
    }
}

// seqpv: softmax (redundant per block) + 32-row PV strip
__device__ __forceinline__ void seqpv_body(
    int st, int b, const float* __restrict__ ad, const float* __restrict__ mask,
    float saB0, const float* __restrict__ cmol, const float* __restrict__ tf,
    float* __restrict__ partial, float* w_s, float* red)
{
    const int tid = threadIdx.x;
    float mk0 = mask[b*SEQ + tid], mk1 = mask[b*SEQ + 256 + tid];
    float cb = cmol[b];
    float s0 = lrelu(cb + ad[b*SEQ + tid] + saB0)       + (mk0 == 0.f ? NEGV : 0.f);
    float s1 = lrelu(cb + ad[b*SEQ + 256 + tid] + saB0) + (mk1 == 0.f ? NEGV : 0.f);
    red[tid] = fmaxf(s0, s1); __syncthreads();
    for (int off = 128; off; off >>= 1) {
        if (tid < off) red[tid] = fmaxf(red[tid], red[tid + off]);
        __syncthreads();
    }
    float m = red[0]; __syncthreads();
    float e0 = expf(s0 - m), e1 = expf(s1 - m);
    red[tid] = e0 + e1; __syncthreads();
    for (int off = 128; off; off >>= 1) {
        if (tid < off) red[tid] += red[tid + off];
        __syncthreads();
    }
    float inv = 1.f / red[0];
    w_s[tid]       = e0 * inv * mk0;
    w_s[tid + 256] = e1 * inv * mk1;
    __syncthreads();
    float acc = 0.f;
    const int s0i = st * 32;
    #pragma unroll 4
    for (int s = s0i; s < s0i + 32; ++s)
        acc += w_s[s] * tf[((size_t)b*SEQ + s)*EMB + tid];
    partial[((size_t)b*16 + st)*EMB + tid] = acc;
}

// seqstep: vb = (b, quarter q), 32 vbs, 256 threads
template<int T0>
__device__ __forceinline__ void seqstep_body(
    int vb, const float* __restrict__ partial, const float* __restrict__ sfin,
    const ushort* __restrict__ wih, const float* __restrict__ bih,
    const ushort* __restrict__ whh, const float* __restrict__ bhh,
    float* __restrict__ sgi, float* __restrict__ sfout,
    float* __restrict__ actseq,
    float* xs, float* hs, float* gis, float* ghs)
{
    const int b = vb >> 2, q = vb & 3;
    const int tid = threadIdx.x, lane = tid & 63, wv = tid >> 6;
    {
        hs[tid] = sfin[b*EMB + tid];
        if (T0) {
            float a = 0.f;
            #pragma unroll
            for (int st = 0; st < 16; ++st)
                a += partial[((size_t)b*16 + st)*EMB + tid];
            xs[tid] = elu1(a);
        }
    }
    if (!T0) {
        for (int l = tid; l < 192; l += 256) {
            int g = (l >> 6)*EMB + (q << 6) + (l & 63);
            gis[l] = sgi[b*G3 + g];
        }
    }
    __syncthreads();
    const int nrows = T0 ? 384 : 192;
    const int rpw = nrows >> 2;               // 4 waves
    for (int i = 0; i < rpw; ++i) {
        const int l = wv * rpw + i;
        const int iswih = T0 && (l < 192);
        const int ll = (T0 && l >= 192) ? l - 192 : l;
        const int g = (ll >> 6)*EMB + (q << 6) + (ll & 63);
        const ushort* Wm = iswih ? wih : whh;
        ushort4 w4 = *reinterpret_cast<const ushort4*>(&Wm[(size_t)g*EMB + (lane << 2)]);
        float4 x4 = *reinterpret_cast<const float4*>(iswih ? &xs[lane << 2] : &hs[lane << 2]);
        float d = bf2f(w4.x)*x4.x + bf2f(w4.y)*x4.y + bf2f(w4.z)*x4.z + bf2f(w4.w)*x4.w;
        #pragma unroll
        for (int off = 32; off; off >>= 1) d += __shfl_xor(d, off, 64);
        if (lane == 0) {
            if (iswih) {
                d += bih[g];
                gis[ll] = d;
                sgi[b*G3 + g] = d;
            } else {
                ghs[ll] = d + bhh[g];
            }
        }
    }
    __syncthreads();
    if (tid < 64) {
        const int e = (q << 6) + tid;
        float rg = sigm(gis[tid]       + ghs[tid]);
        float z  = sigm(gis[64 + tid]  + ghs[64 + tid]);
        float n  = tanhf(gis[128 + tid] + rg*ghs[128 + tid]);
        float hv = (1.f - z)*n + z*hs[e];
        sfout[b*EMB + e]  = hv;
        actseq[b*EMB + e] = fmaxf(hv, 0.f);
    }
}

struct Params {
    const float *amino, *embW, *nbW, *attW, *gwih, *gwhh, *satW, *sgwih, *sgwhh;
    const float *mask, *embB, *nbB, *alignW, *alignB, *attB, *gbih, *gbhh;
    const float *saW, *saB, *satB, *sgbih, *sgbhh;
    const int* idx;
    unsigned *bar_cnt, *bar_gen;
    float *feat, *nbase, *h, *tf, *cdot, *ndot, *ad, *seqfeat, *sf2, *cmol, *sgi, *partial;
    ushort *aminobf, *featbf, *nbasebf, *actbf, *hbf, *ctxbf, *ntb, *gibf, *ghbf;
    ushort *embWbf, *nbWbf, *attWbf, *gwihbf, *gwhhbf, *satWbf, *sgwihbf, *sgwhhbf;
    float *act, *actseq;
};

__global__ __launch_bounds__(256, 2) void mega_kernel(Params p) {
    __shared__ MegaLds L;
    const int bid = blockIdx.x, gsz = gridDim.x;
    const unsigned nb = gridDim.x;
    #define GSYNC() grid_barrier(p.bar_cnt, p.bar_gen, nb)

    // P0: bf16 conversion (9 segments, grid-stride)
    conv_seg(p.amino, p.aminobf, BS*INITD, bid, gsz);
    conv_seg(p.embW,  p.embWbf,  EMB*INITD, bid, gsz);
    conv_seg(p.nbW,   p.nbWbf,   EMB*INITD, bid, gsz);
    conv_seg(p.attW,  p.attWbf,  3*EMB*EMB, bid, gsz);
    conv_seg(p.gwih,  p.gwihbf,  3*G3*EMB, bid, gsz);
    conv_seg(p.gwhh,  p.gwhhbf,  3*G3*EMB, bid, gsz);
    conv_seg(p.satW,  p.satWbf,  EMB*EMB, bid, gsz);
    conv_seg(p.sgwih, p.sgwihbf, G3*EMB, bid, gsz);
    conv_seg(p.sgwhh, p.sgwhhbf, G3*EMB, bid, gsz);
    GSYNC();

    // P1: featnbase (BN=64), NVB=256
    for (int vb = bid; vb < 256; vb += gsz) {
        if (vb < 128)
            gemm_dev<64,1,true,true>(p.aminobf, p.embWbf, p.embB, p.feat, p.featbf,
                                     EMB, INITD, vb & 31, vb >> 5, *(GemmLdsT<64>*)&L);
        else {
            int b = vb - 128;
            gemm_dev<64,1,true,true>(p.aminobf, p.nbWbf, p.nbB, p.nbase, p.nbasebf,
                                     EMB, INITD, b & 31, b >> 5, *(GemmLdsT<64>*)&L);
        }
        __syncthreads();
    }
    GSYNC();

    for (int d = 0; d < 3; ++d) {
        const float*  center  = (d == 0) ? p.feat    : p.act;
        const float*  nbrbase = (d == 0) ? p.nbase   : p.act;
        const ushort* nbrbf   = (d == 0) ? p.nbasebf : p.actbf;
        const float*  hprev   = (d == 0) ? p.feat    : p.h;
        const ushort* hprevbf = (d == 0) ? p.featbf  : p.hbf;
        const ushort* attWd  = p.attWbf  + (size_t)d*EMB*EMB;
        const ushort* gwhhd  = p.gwhhbf  + (size_t)d*G3*EMB;
        const ushort* gwihd  = p.gwihbf  + (size_t)d*G3*EMB;
        const float*  attBd  = p.attB + d*EMB;
        const float*  gbhhd  = p.gbhh + d*G3;
        const float*  gbihd  = p.gbih + d*G3;
        const float*  alignWd = p.alignW + d*2*EMB;
        const float   alignBd = p.alignB[d];

        // P2: nt gemm (64) + gh gemm (192) + dot2 (128) = 384 vb
        for (int vb = bid; vb < 384; vb += gsz) {
            if (vb < 64)
                gemm_dev<128,0,false,true>(nbrbf, attWd, attBd, nullptr, p.ntb,
                                           EMB, EMB, vb & 31, vb >> 5, L.g);
            else if (vb < 256) {
                int b = vb - 64;
                gemm_dev<128,0,false,true>(hprevbf, gwhhd, gbhhd, nullptr, p.ghbf,
                                           G3, EMB, b & 31, b >> 5, L.g);
            } else {
                dot2_body(vb - 256, center, nbrbase, alignWd, p.cdot, p.ndot);
            }
            __syncthreads();
        }
        GSYNC();

        // P3: attn, NVB=512 (8 rows each)
        for (int vb = bid; vb < 512; vb += gsz)
            attn_body(vb, p.cdot, p.ndot, p.idx, p.ntb, alignBd, p.ctxbf);
        GSYNC();

        // P4: gi gemm, NVB=192
        for (int vb = bid; vb < 192; vb += gsz) {
            gemm_dev<128,0,false,true>(p.ctxbf, gwihd, gbihd, nullptr, p.gibf,
                                       G3, EMB, vb & 31, vb >> 5, L.g);
            __syncthreads();
        }
        GSYNC();

        // P5: gru, NVB=512 (8 rows each)
        for (int vb = bid; vb < 512; vb += gsz)
            gru_body(vb, p.gibf, p.ghbf, hprev, p.h, p.hbf, p.act, p.actbf);
        GSYNC();
    }

    // P6: tf gemm (64) + seqsum (8) + seqscore (128) = 200 vb
    for (int vb = bid; vb < 200; vb += gsz) {
        if (vb < 64)
            gemm_dev<128,0,true,false>(p.actbf, p.satWbf, p.satB, p.tf, nullptr,
                                       EMB, EMB, vb & 31, vb >> 5, L.g);
        else if (vb < 72)
            seqsum_body(vb - 64, p.act, p.mask, p.saW, p.seqfeat, p.cmol, L.red256);
        else
            seqscore_body(vb - 72, p.act, p.saW, p.ad);
        __syncthreads();
    }
    GSYNC();

    // P7: seqpv, NVB=128
    for (int vb = bid; vb < 128; vb += gsz) {
        seqpv_body(vb & 15, vb >> 4, p.ad, p.mask, p.saB[0], p.cmol, p.tf,
                   p.partial, L.pv.w_s, L.pv.red);
        __syncthreads();
    }
    GSYNC();

    // P8: seqstep T0, NVB=32
    for (int vb = bid; vb < 32; vb += gsz) {
        seqstep_body<1>(vb, p.partial, p.seqfeat, p.sgwihbf, p.sgbih,
                        p.sgwhhbf, p.sgbhh, p.sgi, p.sf2, p.actseq,
                        L.st.xs, L.st.hs, L.st.gis, L.st.ghs);
        __syncthreads();
    }
    GSYNC();

    // P9: seqstep T1, NVB=32
    for (int vb = bid; vb < 32; vb += gsz) {
        seqstep_body<0>(vb, p.partial, p.sf2, p.sgwihbf, p.sgbih,
                        p.sgwhhbf, p.sgbhh, p.sgi, p.seqfeat, p.actseq,
                        L.st.xs, L.st.hs, L.st.gis, L.st.ghs);
        __syncthreads();
    }
    #undef GSYNC
}

extern "C" void kernel_launch(void* const* d_in, const int* in_sizes, int n_in,
                              void* d_out, int out_size, void* d_ws, size_t ws_size,
                              hipStream_t stream) {
    (void)in_sizes; (void)n_in; (void)out_size; (void)ws_size;
    char* cur = (char*)d_ws;
    auto alloc = [&](size_t bytes) -> char* {
        char* p = cur; cur += (bytes + 255) & ~(size_t)255; return p;
    };
    Params prm;
    prm.bar_cnt = (unsigned*)alloc(256);     // own 256B line
    prm.bar_gen = (unsigned*)alloc(256);
    prm.feat    = (float*)alloc((size_t)BS*EMB*4);
    prm.nbase   = (float*)alloc((size_t)BS*EMB*4);
    prm.h       = (float*)alloc((size_t)BS*EMB*4);
    prm.tf      = (float*)alloc((size_t)BS*EMB*4);
    prm.cdot    = (float*)alloc(BS*4);
    prm.ndot    = (float*)alloc(BS*4);
    prm.ad      = (float*)alloc(BS*4);
    prm.seqfeat = (float*)alloc(BSZ*EMB*4);
    prm.sf2     = (float*)alloc(BSZ*EMB*4);
    prm.cmol    = (float*)alloc(64*4);
    prm.sgi     = (float*)alloc(BSZ*G3*4);
    prm.partial = (float*)alloc((size_t)BSZ*16*EMB*4);
    prm.aminobf = (ushort*)alloc((size_t)BS*INITD*2);
    prm.featbf  = (ushort*)alloc((size_t)BS*EMB*2);
    prm.nbasebf = (ushort*)alloc((size_t)BS*EMB*2);
    prm.actbf   = (ushort*)alloc((size_t)BS*EMB*2);
    prm.hbf     = (ushort*)alloc((size_t)BS*EMB*2);
    prm.ctxbf   = (ushort*)alloc((size_t)BS*EMB*2);
    prm.ntb     = (ushort*)alloc((size_t)BS*EMB*2);
    prm.gibf    = (ushort*)alloc((size_t)BS*G3*2);
    prm.ghbf    = (ushort*)alloc((size_t)BS*G3*2);
    prm.embWbf  = (ushort*)alloc((size_t)EMB*INITD*2);
    prm.nbWbf   = (ushort*)alloc((size_t)EMB*INITD*2);
    prm.attWbf  = (ushort*)alloc((size_t)3*EMB*EMB*2);
    prm.gwihbf  = (ushort*)alloc((size_t)3*G3*EMB*2);
    prm.gwhhbf  = (ushort*)alloc((size_t)3*G3*EMB*2);
    prm.satWbf  = (ushort*)alloc((size_t)EMB*EMB*2);
    prm.sgwihbf = (ushort*)alloc((size_t)G3*EMB*2);
    prm.sgwhhbf = (ushort*)alloc((size_t)G3*EMB*2);
    prm.amino = (const float*)d_in[0];
    prm.mask  = (const float*)d_in[1];
    prm.embW  = (const float*)d_in[2];
    prm.embB  = (const float*)d_in[3];
    prm.nbW   = (const float*)d_in[4];
    prm.nbB   = (const float*)d_in[5];
    prm.alignW= (const float*)d_in[6];
    prm.alignB= (const float*)d_in[7];
    prm.attW  = (const float*)d_in[8];
    prm.attB  = (const float*)d_in[9];
    prm.gwih  = (const float*)d_in[10];
    prm.gwhh  = (const float*)d_in[11];
    prm.gbih  = (const float*)d_in[12];
    prm.gbhh  = (const float*)d_in[13];
    prm.saW   = (const float*)d_in[14];
    prm.saB   = (const float*)d_in[15];
    prm.satW  = (const float*)d_in[16];
    prm.satB  = (const float*)d_in[17];
    prm.sgwih = (const float*)d_in[18];
    prm.sgbih = (const float*)d_in[19];
    prm.sgwhh = (const float*)d_in[20];
    prm.sgbhh = (const float*)d_in[21];
    prm.idx   = (const int*)d_in[22];
    prm.actseq = (float*)d_out;
    prm.act    = (float*)d_out + BSZ*EMB;

    // deterministic barrier state each call (d_ws is poisoned once by harness)
    hipMemsetAsync(prm.bar_cnt, 0, 512, stream);

    int maxb = 0;
    if (hipOccupancyMaxActiveBlocksPerMultiprocessor(
            &maxb, (const void*)mega_kernel, 256, 0) != hipSuccess || maxb < 1)
        maxb = 1;
    int grid = (maxb >= 2) ? 512 : 256;
    void* args[] = { (void*)&prm };
    hipLaunchCooperativeKernel((const void*)mega_kernel, dim3(grid), dim3(256),
                               args, 0, stream);
}

// Round 9
// 321.534 us; speedup vs baseline: 2.9759x; 2.9759x over previous
//
#include <hip/hip_runtime.h>
#include <math.h>

// ProGAT: B=8,S=512,NB=23,INIT=512,E=256,R=3,T=2
// R9: back to multi-dispatch (grid sync costs ~70us on MI355X - R7/R8).
// Serial chain cut 18->12 dispatches: gather commutes with attend linear map
// (ctx = elu(attW@ctxpre + wsum*attB)), so each round = gather(C) + fusedD
// (attend GEMM + gi GEMM + gh GEMM + GRU + next-round dot2, all row-local).

#define BSZ   8
#define SEQ   512
#define NBR   23
#define EMB   256
#define INITD 512
#define BS    (BSZ*SEQ)     // 4096
#define G3    (3*EMB)       // 768
#define NEGV  -9e8f

typedef __attribute__((ext_vector_type(8))) short short8;
typedef __attribute__((ext_vector_type(4))) float f32x4;

__device__ __forceinline__ float lrelu(float x){ return x > 0.f ? x : 0.01f*x; }
__device__ __forceinline__ float elu1 (float x){ return x > 0.f ? x : (expf(x)-1.f); }
__device__ __forceinline__ float sigm (float x){ return 1.f/(1.f+expf(-x)); }
__device__ __forceinline__ float bf2f(ushort u){
    union { unsigned int i; float f; } v; v.i = ((unsigned int)u) << 16; return v.f;
}
__device__ __forceinline__ ushort f2bf(float f){
    union { float f; unsigned int i; } v; v.f = f;
    unsigned int u = v.i;
    return (ushort)((u + 0x7FFFu + ((u >> 16) & 1u)) >> 16);   // RNE
}

__device__ __forceinline__ void gload_lds16(const void* g, void* l) {
    __builtin_amdgcn_global_load_lds(
        (const __attribute__((address_space(1))) unsigned int*)g,
        (__attribute__((address_space(3))) unsigned int*)l,
        16, 0, 0);
}

// ---- fp32 -> bf16 converter, 9 segments in one dispatch (blockIdx.y = seg)
__global__ __launch_bounds__(256) void convert9_kernel(
    const float* s0, ushort* d0, int n0,
    const float* s1, ushort* d1, int n1,
    const float* s2, ushort* d2, int n2,
    const float* s3, ushort* d3, int n3,
    const float* s4, ushort* d4, int n4,
    const float* s5, ushort* d5, int n5,
    const float* s6, ushort* d6, int n6,
    const float* s7, ushort* d7, int n7,
    const float* s8, ushort* d8, int n8)
{
    const float* srcs[9] = {s0,s1,s2,s3,s4,s5,s6,s7,s8};
    ushort* dsts[9] = {d0,d1,d2,d3,d4,d5,d6,d7,d8};
    int ns[9] = {n0,n1,n2,n3,n4,n5,n6,n7,n8};
    int seg = blockIdx.y;
    const float* s = srcs[seg]; ushort* d = dsts[seg]; int n = ns[seg];
    size_t i = ((size_t)blockIdx.x * 256 + threadIdx.x) * 8;
    size_t stride = (size_t)gridDim.x * 256 * 8;
    for (; i < (size_t)n; i += stride) {
        float4 a = *reinterpret_cast<const float4*>(s + i);
        float4 b = *reinterpret_cast<const float4*>(s + i + 4);
        uint4 o;
        o.x = (unsigned)f2bf(a.x) | ((unsigned)f2bf(a.y) << 16);
        o.y = (unsigned)f2bf(a.z) | ((unsigned)f2bf(a.w) << 16);
        o.z = (unsigned)f2bf(b.x) | ((unsigned)f2bf(b.y) << 16);
        o.w = (unsigned)f2bf(b.z) | ((unsigned)f2bf(b.w) << 16);
        *reinterpret_cast<uint4*>(d + i) = o;
    }
}

// ---- 128x64 MFMA GEMM (K=512) for feat/nbase; global_load_lds staging
struct GemmLds64 { ushort A[2][128][64]; ushort B[2][64][64]; };

template<int ACT>
__device__ __forceinline__ void gemm64_dev(
    const ushort* __restrict__ A, const ushort* __restrict__ W,
    const float* __restrict__ bias,
    float* __restrict__ C, ushort* __restrict__ Cbf,
    int N, int K, int bx, int by, GemmLds64& L)
{
    const int tid = threadIdx.x;
    const int m0 = bx * 128, n0 = by * 64;
    const int wv = tid >> 6, lane = tid & 63;
    const int fr = lane & 15, grp = lane >> 4;
    const int kc = K >> 3;
    const int mh = wv & 1, nh = wv >> 1;
    const int lrow = lane >> 3;
    const int csrc = (lane & 7) ^ lrow;

    f32x4 acc[4][2];
    #pragma unroll
    for (int i = 0; i < 4; ++i)
        #pragma unroll
        for (int n = 0; n < 2; ++n) acc[i][n] = (f32x4){0.f,0.f,0.f,0.f};

    auto stage = [&](int c, int k0) {
        const int kch = (k0 >> 3) + csrc;
        #pragma unroll
        for (int i = 0; i < 4; ++i) {
            const int s = (wv << 2) + i;
            gload_lds16(A + ((size_t)(m0 + (s << 3) + lrow) * kc + kch) * 8,
                        &L.A[c][s << 3][0]);
        }
        #pragma unroll
        for (int i = 0; i < 2; ++i) {
            const int s = (wv << 1) + i;
            gload_lds16(W + ((size_t)(n0 + (s << 3) + lrow) * kc + kch) * 8,
                        &L.B[c][s << 3][0]);
        }
    };
    auto compute = [&](int c) {
        #pragma unroll
        for (int ks = 0; ks < 2; ++ks) {
            short8 af[4];
            #pragma unroll
            for (int i = 0; i < 4; ++i) {
                const int ar = (mh << 6) + (i << 4) + fr;
                af[i] = *reinterpret_cast<const short8*>(
                    &L.A[c][ar][(((ks << 2) + grp) ^ (ar & 7)) << 3]);
            }
            #pragma unroll
            for (int n = 0; n < 2; ++n) {
                const int br = (nh << 5) + (n << 4) + fr;
                short8 bv = *reinterpret_cast<const short8*>(
                    &L.B[c][br][(((ks << 2) + grp) ^ (br & 7)) << 3]);
                #pragma unroll
                for (int i = 0; i < 4; ++i)
                    acc[i][n] = __builtin_amdgcn_mfma_f32_16x16x32_bf16(
                        af[i], bv, acc[i][n], 0, 0, 0);
            }
        }
    };

    const int KT = K >> 6;
    stage(0, 0);
    __syncthreads();
    int cur = 0;
    for (int kt = 1; kt < KT; ++kt) {
        stage(cur ^ 1, kt << 6);
        compute(cur);
        __syncthreads();
        cur ^= 1;
    }
    compute(cur);

    #pragma unroll
    for (int i = 0; i < 4; ++i) {
        const int mrow = m0 + (mh << 6) + (i << 4) + (grp << 2);
        #pragma unroll
        for (int n = 0; n < 2; ++n) {
            const int col = n0 + (nh << 5) + (n << 4) + fr;
            const float bv = bias[col];
            #pragma unroll
            for (int j = 0; j < 4; ++j) {
                float t = acc[i][n][j] + bv;
                if (ACT == 1) t = lrelu(t);
                size_t off = (size_t)(mrow + j) * N + col;
                if (C)   C[off] = t;
                if (Cbf) Cbf[off] = f2bf(t);
            }
        }
    }
}

// ---- fat: feat GEMM (0..127) + nbase GEMM (128..255), K=512
__global__ __launch_bounds__(256) void featnbase_kernel(
    const ushort* __restrict__ aminobf,
    const ushort* __restrict__ embWbf, const float* __restrict__ embB,
    float* __restrict__ feat, ushort* __restrict__ featbf,
    const ushort* __restrict__ nbWbf, const float* __restrict__ nbB,
    float* __restrict__ nbase, ushort* __restrict__ nbasebf)
{
    __shared__ GemmLds64 L;
    int blk = blockIdx.x;
    if (blk < 128)
        gemm64_dev<1>(aminobf, embWbf, embB, feat, featbf, EMB, INITD, blk & 31, blk >> 5, L);
    else {
        blk -= 128;
        gemm64_dev<1>(aminobf, nbWbf, nbB, nbase, nbasebf, EMB, INITD, blk & 31, blk >> 5, L);
    }
}

// ---- dot2 for round 0: 128 blocks x 32 rows
__global__ __launch_bounds__(256) void dot2_kernel(
    const float* __restrict__ center, const float* __restrict__ nbrbase,
    const float* __restrict__ alignWd,
    float* __restrict__ cdot, float* __restrict__ ndot)
{
    const int lane = threadIdx.x & 63;
    const int wv   = threadIdx.x >> 6;
    const int e    = lane << 2;
    const int rb   = blockIdx.x * 32 + wv * 8;
    float4 w0 = *reinterpret_cast<const float4*>(&alignWd[e]);
    float4 w1 = *reinterpret_cast<const float4*>(&alignWd[EMB + e]);
    #pragma unroll
    for (int i = 0; i < 8; ++i) {
        const int r = rb + i;
        float4 xc = *reinterpret_cast<const float4*>(&center[(size_t)r*EMB + e]);
        float4 xn = *reinterpret_cast<const float4*>(&nbrbase[(size_t)r*EMB + e]);
        float ac = xc.x*w0.x + xc.y*w0.y + xc.z*w0.z + xc.w*w0.w;
        float an = xn.x*w1.x + xn.y*w1.y + xn.z*w1.z + xn.w*w1.w;
        #pragma unroll
        for (int off = 32; off; off >>= 1) {
            ac += __shfl_xor(ac, off, 64);
            an += __shfl_xor(an, off, 64);
        }
        if (lane == 0) { cdot[r] = ac; ndot[r] = an; }
    }
}

// ---- C: gather. 1 wave per row, 4 rows/block. ctxpre = sum_n w_n*nbr[row_n],
// wsum = sum_n w_n (elu/attend deferred to D by linearity).
__global__ __launch_bounds__(256) void gather_kernel(
    const float* __restrict__ cdot, const float* __restrict__ ndot,
    const int* __restrict__ idx, const ushort* __restrict__ nbr,
    const float* __restrict__ alignBd,
    ushort* __restrict__ ctxprebf, float* __restrict__ wsum)
{
    const int lane = threadIdx.x & 63;
    const int r = blockIdx.x * 4 + (threadIdx.x >> 6);
    const int b = r >> 9;
    float sc = -3e38f, vm = 0.f; int row = 0;
    if (lane < NBR) {
        int j = idx[(size_t)r*NBR + lane];
        int valid = (j >= 0);
        int jj = valid ? j : j + SEQ;       // JAX wrap: f[-1] = last row
        row = b*SEQ + jj;
        vm = (float)valid;
        sc = lrelu(cdot[r] + ndot[row] + alignBd[0]) + (valid ? 0.f : NEGV);
    }
    float m = sc;
    #pragma unroll
    for (int off = 32; off; off >>= 1) m = fmaxf(m, __shfl_xor(m, off, 64));
    float ev = (lane < NBR) ? expf(sc - m) : 0.f;
    float s = ev;
    #pragma unroll
    for (int off = 32; off; off >>= 1) s += __shfl_xor(s, off, 64);
    float wgt = ev * vm / s;
    float ws = wgt;
    #pragma unroll
    for (int off = 32; off; off >>= 1) ws += __shfl_xor(ws, off, 64);
    float acc0 = 0.f, acc1 = 0.f, acc2 = 0.f, acc3 = 0.f;
    const int e = lane << 2;
    #pragma unroll 1
    for (int n = 0; n < NBR; ++n) {
        float wn = __shfl(wgt, n, 64);
        int   rn = __shfl(row, n, 64);
        ushort4 v = *reinterpret_cast<const ushort4*>(&nbr[(size_t)rn*EMB + e]);
        acc0 += wn * bf2f(v.x); acc1 += wn * bf2f(v.y);
        acc2 += wn * bf2f(v.z); acc3 += wn * bf2f(v.w);
    }
    uint2 o;
    o.x = (unsigned)f2bf(acc0) | ((unsigned)f2bf(acc1) << 16);
    o.y = (unsigned)f2bf(acc2) | ((unsigned)f2bf(acc3) << 16);
    *reinterpret_cast<uint2*>(&ctxprebf[(size_t)r*EMB + e]) = o;
    if (lane == 0) wsum[r] = ws;
}

// ---- D: per 16-row block: ctx=elu(attW@ctxpre+wsum*attB); gi=wih@ctx;
// gh=whh@hprev; GRU; next-round dot2 (or seqscore ad if LAST). 512 thr.
struct DLds {
    ushort ctxpre[16][256];
    ushort ctx[16][256];
    ushort hpv[16][256];
    ushort gis[16][768];
    ushort ghs[16][768];
    float  wsum_s[16];
};

__device__ __forceinline__ void unpack8(uint4 v, float* o) {
    o[0]=bf2f((ushort)(v.x&0xffff)); o[1]=bf2f((ushort)(v.x>>16));
    o[2]=bf2f((ushort)(v.y&0xffff)); o[3]=bf2f((ushort)(v.y>>16));
    o[4]=bf2f((ushort)(v.z&0xffff)); o[5]=bf2f((ushort)(v.z>>16));
    o[6]=bf2f((ushort)(v.w&0xffff)); o[7]=bf2f((ushort)(v.w>>16));
}

template<int LAST>
__global__ __launch_bounds__(512, 4) void fusedD_kernel(
    const ushort* __restrict__ ctxprebf, const float* __restrict__ wsum,
    const ushort* __restrict__ attWd, const float* __restrict__ attBd,
    const ushort* __restrict__ gwihd, const float* __restrict__ gbihd,
    const ushort* __restrict__ gwhhd, const float* __restrict__ gbhhd,
    const float* __restrict__ hprev, const ushort* __restrict__ hprevbf,
    const float* __restrict__ nextW,
    float* __restrict__ hout, ushort* __restrict__ hbf,
    float* __restrict__ actout, ushort* __restrict__ actbf,
    float* __restrict__ cdotO, float* __restrict__ ndotO)
{
    __shared__ DLds L;
    const int tid = threadIdx.x;
    const int r0 = blockIdx.x * 16;

    {   // stage ctxpre + hprevbf (swizzled: chunk c -> c ^ (row&7)) + wsum
        const int ri = tid >> 5, c = tid & 31;
        uint4 v = *reinterpret_cast<const uint4*>(&ctxprebf[(size_t)(r0+ri)*EMB + (c<<3)]);
        *reinterpret_cast<uint4*>(&L.ctxpre[ri][(c ^ (ri&7)) << 3]) = v;
        uint4 h = *reinterpret_cast<const uint4*>(&hprevbf[(size_t)(r0+ri)*EMB + (c<<3)]);
        *reinterpret_cast<uint4*>(&L.hpv[ri][(c ^ (ri&7)) << 3]) = h;
        if (tid < 16) L.wsum_s[tid] = wsum[r0 + tid];
    }
    __syncthreads();

    const int wv = tid >> 6, lane = tid & 63;
    const int fr = lane & 15, grp = lane >> 4;

    {   // attend: wave owns cols wv*32 + f*16 + fr, f in 0..1
        f32x4 acc[2] = {(f32x4){0,0,0,0},(f32x4){0,0,0,0}};
        #pragma unroll
        for (int kt = 0; kt < 8; ++kt) {
            short8 af = *reinterpret_cast<const short8*>(
                &L.ctxpre[fr][((((kt<<2)+grp) ^ (fr&7)) << 3)]);
            #pragma unroll
            for (int f = 0; f < 2; ++f) {
                const int col = (wv<<5) + (f<<4) + fr;
                short8 bv = *reinterpret_cast<const short8*>(
                    &attWd[(size_t)col*EMB + (kt<<5) + (grp<<3)]);
                acc[f] = __builtin_amdgcn_mfma_f32_16x16x32_bf16(af, bv, acc[f], 0, 0, 0);
            }
        }
        #pragma unroll
        for (int f = 0; f < 2; ++f) {
            const int col = (wv<<5) + (f<<4) + fr;
            const float bb = attBd[col];
            const int ch = col >> 3;
            #pragma unroll
            for (int j = 0; j < 4; ++j) {
                const int row = (grp<<2) + j;
                float t = elu1(acc[f][j] + L.wsum_s[row]*bb);
                L.ctx[row][(((ch ^ (row&7)) << 3) | (col & 7))] = f2bf(t);
            }
        }
    }
    __syncthreads();

    {   // gi: cols wv*96 + f*16 + fr, f in 0..5, A = ctx
        f32x4 acc[6];
        #pragma unroll
        for (int f = 0; f < 6; ++f) acc[f] = (f32x4){0,0,0,0};
        #pragma unroll
        for (int kt = 0; kt < 8; ++kt) {
            short8 af = *reinterpret_cast<const short8*>(
                &L.ctx[fr][((((kt<<2)+grp) ^ (fr&7)) << 3)]);
            #pragma unroll
            for (int f = 0; f < 6; ++f) {
                const int col = wv*96 + (f<<4) + fr;
                short8 bv = *reinterpret_cast<const short8*>(
                    &gwihd[(size_t)col*EMB + (kt<<5) + (grp<<3)]);
                acc[f] = __builtin_amdgcn_mfma_f32_16x16x32_bf16(af, bv, acc[f], 0, 0, 0);
            }
        }
        #pragma unroll
        for (int f = 0; f < 6; ++f) {
            const int col = wv*96 + (f<<4) + fr;
            const float bb = gbihd[col];
            #pragma unroll
            for (int j = 0; j < 4; ++j)
                L.gis[(grp<<2)+j][col] = f2bf(acc[f][j] + bb);
        }
        // gh: A = hprev
        #pragma unroll
        for (int f = 0; f < 6; ++f) acc[f] = (f32x4){0,0,0,0};
        #pragma unroll
        for (int kt = 0; kt < 8; ++kt) {
            short8 af = *reinterpret_cast<const short8*>(
                &L.hpv[fr][((((kt<<2)+grp) ^ (fr&7)) << 3)]);
            #pragma unroll
            for (int f = 0; f < 6; ++f) {
                const int col = wv*96 + (f<<4) + fr;
                short8 bv = *reinterpret_cast<const short8*>(
                    &gwhhd[(size_t)col*EMB + (kt<<5) + (grp<<3)]);
                acc[f] = __builtin_amdgcn_mfma_f32_16x16x32_bf16(af, bv, acc[f], 0, 0, 0);
            }
        }
        #pragma unroll
        for (int f = 0; f < 6; ++f) {
            const int col = wv*96 + (f<<4) + fr;
            const float bb = gbhhd[col];
            #pragma unroll
            for (int j = 0; j < 4; ++j)
                L.ghs[(grp<<2)+j][col] = f2bf(acc[f][j] + bb);
        }
    }
    __syncthreads();

    {   // GRU + next-round dots: 16 rows x 32 threads, 8 e per thread
        const int row = tid >> 5, sub = tid & 31;
        const int e0 = sub << 3;
        const size_t r = (size_t)r0 + row;
        uint4 giA = *reinterpret_cast<const uint4*>(&L.gis[row][e0]);
        uint4 giB = *reinterpret_cast<const uint4*>(&L.gis[row][256 + e0]);
        uint4 giC = *reinterpret_cast<const uint4*>(&L.gis[row][512 + e0]);
        uint4 ghA = *reinterpret_cast<const uint4*>(&L.ghs[row][e0]);
        uint4 ghB = *reinterpret_cast<const uint4*>(&L.ghs[row][256 + e0]);
        uint4 ghC = *reinterpret_cast<const uint4*>(&L.ghs[row][512 + e0]);
        float4 hp0 = *reinterpret_cast<const float4*>(&hprev[r*EMB + e0]);
        float4 hp1 = *reinterpret_cast<const float4*>(&hprev[r*EMB + e0 + 4]);
        float ir_[8], iz_[8], in_[8], hr_[8], hz_[8], hn_[8];
        unpack8(giA, ir_); unpack8(giB, iz_); unpack8(giC, in_);
        unpack8(ghA, hr_); unpack8(ghB, hz_); unpack8(ghC, hn_);
        const float hp_[8] = {hp0.x,hp0.y,hp0.z,hp0.w,hp1.x,hp1.y,hp1.z,hp1.w};
        float hv8[8], av8[8];
        #pragma unroll
        for (int i = 0; i < 8; ++i) {
            float rg = sigm(ir_[i] + hr_[i]);
            float z  = sigm(iz_[i] + hz_[i]);
            float n  = tanhf(in_[i] + rg*hn_[i]);
            hv8[i] = (1.f - z)*n + z*hp_[i];
            av8[i] = fmaxf(hv8[i], 0.f);
        }
        *reinterpret_cast<float4*>(&hout[r*EMB + e0])       = make_float4(hv8[0],hv8[1],hv8[2],hv8[3]);
        *reinterpret_cast<float4*>(&hout[r*EMB + e0 + 4])   = make_float4(hv8[4],hv8[5],hv8[6],hv8[7]);
        *reinterpret_cast<float4*>(&actout[r*EMB + e0])     = make_float4(av8[0],av8[1],av8[2],av8[3]);
        *reinterpret_cast<float4*>(&actout[r*EMB + e0 + 4]) = make_float4(av8[4],av8[5],av8[6],av8[7]);
        uint4 hb, ab;
        hb.x = (unsigned)f2bf(hv8[0]) | ((unsigned)f2bf(hv8[1]) << 16);
        hb.y = (unsigned)f2bf(hv8[2]) | ((unsigned)f2bf(hv8[3]) << 16);
        hb.z = (unsigned)f2bf(hv8[4]) | ((unsigned)f2bf(hv8[5]) << 16);
        hb.w = (unsigned)f2bf(hv8[6]) | ((unsigned)f2bf(hv8[7]) << 16);
        ab.x = (unsigned)f2bf(av8[0]) | ((unsigned)f2bf(av8[1]) << 16);
        ab.y = (unsigned)f2bf(av8[2]) | ((unsigned)f2bf(av8[3]) << 16);
        ab.z = (unsigned)f2bf(av8[4]) | ((unsigned)f2bf(av8[5]) << 16);
        ab.w = (unsigned)f2bf(av8[6]) | ((unsigned)f2bf(av8[7]) << 16);
        *reinterpret_cast<uint4*>(&hbf[r*EMB + e0])   = hb;
        *reinterpret_cast<uint4*>(&actbf[r*EMB + e0]) = ab;
        // dots on fresh act values
        float pc = 0.f, pn = 0.f;
        float4 w1a = *reinterpret_cast<const float4*>(&nextW[EMB + e0]);
        float4 w1b = *reinterpret_cast<const float4*>(&nextW[EMB + e0 + 4]);
        pn = av8[0]*w1a.x + av8[1]*w1a.y + av8[2]*w1a.z + av8[3]*w1a.w
           + av8[4]*w1b.x + av8[5]*w1b.y + av8[6]*w1b.z + av8[7]*w1b.w;
        if (!LAST) {
            float4 w0a = *reinterpret_cast<const float4*>(&nextW[e0]);
            float4 w0b = *reinterpret_cast<const float4*>(&nextW[e0 + 4]);
            pc = av8[0]*w0a.x + av8[1]*w0a.y + av8[2]*w0a.z + av8[3]*w0a.w
               + av8[4]*w0b.x + av8[5]*w0b.y + av8[6]*w0b.z + av8[7]*w0b.w;
        }
        #pragma unroll
        for (int off = 16; off; off >>= 1) {
            pn += __shfl_xor(pn, off, 32);
            if (!LAST) pc += __shfl_xor(pc, off, 32);
        }
        if (sub == 0) {
            if (!LAST) cdotO[r] = pc;
            ndotO[r] = pn;
        }
    }
}

// ---- fat: tf GEMM (0..127, BN=64) + seqsum (128..135)
__global__ __launch_bounds__(256) void seqpre_kernel(
    const ushort* __restrict__ actbf, const ushort* __restrict__ satWbf,
    const float* __restrict__ satB, float* __restrict__ tf,
    const float* __restrict__ act, const float* __restrict__ mask,
    const float* __restrict__ saW,
    float* __restrict__ seqfeat, float* __restrict__ cmol)
{
    __shared__ GemmLds64 L;
    int blk = blockIdx.x;
    if (blk < 128) {
        gemm64_dev<0>(actbf, satWbf, satB, tf, nullptr, EMB, EMB, blk & 31, blk >> 5, L);
    } else {
        const int b = blk - 128;
        const int e = threadIdx.x;
        float acc = 0.f;
        for (int s = 0; s < SEQ; ++s)
            acc += act[((size_t)b*SEQ + s)*EMB + e] * mask[b*SEQ + s];
        seqfeat[b*EMB + e] = acc;
        float* red = reinterpret_cast<float*>(&L);
        red[e] = fmaxf(acc, 0.f) * saW[e];
        __syncthreads();
        for (int off = 128; off; off >>= 1) {
            if (e < off) red[e] += red[e + off];
            __syncthreads();
        }
        if (e == 0) cmol[b] = red[0];
    }
}

// softmax (redundant per block) + PV strip: block (st,b) -> partial[b,st,:]
__global__ __launch_bounds__(256) void seqpv2_kernel(
    const float* __restrict__ ad, const float* __restrict__ mask,
    const float* __restrict__ saB, const float* __restrict__ cmol,
    const float* __restrict__ tf, float* __restrict__ partial)
{
    const int st = blockIdx.x, b = blockIdx.y;
    const int tid = threadIdx.x;
    __shared__ float w_s[SEQ];
    __shared__ float red[256];
    float mk0 = mask[b*SEQ + tid], mk1 = mask[b*SEQ + 256 + tid];
    float cb = cmol[b], bb = saB[0];
    float s0 = lrelu(cb + ad[b*SEQ + tid] + bb)       + (mk0 == 0.f ? NEGV : 0.f);
    float s1 = lrelu(cb + ad[b*SEQ + 256 + tid] + bb) + (mk1 == 0.f ? NEGV : 0.f);
    red[tid] = fmaxf(s0, s1); __syncthreads();
    for (int off = 128; off; off >>= 1) {
        if (tid < off) red[tid] = fmaxf(red[tid], red[tid + off]);
        __syncthreads();
    }
    float m = red[0]; __syncthreads();
    float e0 = expf(s0 - m), e1 = expf(s1 - m);
    red[tid] = e0 + e1; __syncthreads();
    for (int off = 128; off; off >>= 1) {
        if (tid < off) red[tid] += red[tid + off];
        __syncthreads();
    }
    float inv = 1.f / red[0];
    w_s[tid]       = e0 * inv * mk0;
    w_s[tid + 256] = e1 * inv * mk1;
    __syncthreads();
    float acc = 0.f;
    const int s0i = st * 32;
    #pragma unroll 4
    for (int s = s0i; s < s0i + 32; ++s)
        acc += w_s[s] * tf[((size_t)b*SEQ + s)*EMB + tid];
    partial[((size_t)b*16 + st)*EMB + tid] = acc;
}

// ---- fused sequence tail: both GRU steps, 1 block per batch, 512 thr
__global__ __launch_bounds__(512) void seqtail_kernel(
    const float* __restrict__ partial, const float* __restrict__ seqfeatIn,
    const ushort* __restrict__ wihbf, const float* __restrict__ bih,
    const ushort* __restrict__ whhbf, const float* __restrict__ bhh,
    float* __restrict__ actseq)
{
    const int b = blockIdx.x;
    const int tid = threadIdx.x, lane = tid & 63, wv = tid >> 6;
    __shared__ float xs[EMB], hs[EMB], gis[G3], ghs[G3];
    if (tid < EMB) {
        hs[tid] = seqfeatIn[b*EMB + tid];
        float a = 0.f;
        #pragma unroll
        for (int st = 0; st < 16; ++st)
            a += partial[((size_t)b*16 + st)*EMB + tid];
        xs[tid] = elu1(a);
    }
    __syncthreads();
    // gi (invariant over T) + gh step 1: 768 rows each, 8 waves x 96
    for (int i = 0; i < 96; ++i) {
        const int l = wv * 96 + i;
        ushort4 wi = *reinterpret_cast<const ushort4*>(&wihbf[(size_t)l*EMB + (lane << 2)]);
        ushort4 wh = *reinterpret_cast<const ushort4*>(&whhbf[(size_t)l*EMB + (lane << 2)]);
        float4 x4 = *reinterpret_cast<const float4*>(&xs[lane << 2]);
        float4 h4 = *reinterpret_cast<const float4*>(&hs[lane << 2]);
        float di = bf2f(wi.x)*x4.x + bf2f(wi.y)*x4.y + bf2f(wi.z)*x4.z + bf2f(wi.w)*x4.w;
        float dh = bf2f(wh.x)*h4.x + bf2f(wh.y)*h4.y + bf2f(wh.z)*h4.z + bf2f(wh.w)*h4.w;
        #pragma unroll
        for (int off = 32; off; off >>= 1) {
            di += __shfl_xor(di, off, 64);
            dh += __shfl_xor(dh, off, 64);
        }
        if (lane == 0) { gis[l] = di + bih[l]; ghs[l] = dh + bhh[l]; }
    }
    __syncthreads();
    if (tid < EMB) {
        float rg = sigm(gis[tid] + ghs[tid]);
        float z  = sigm(gis[EMB + tid] + ghs[EMB + tid]);
        float n  = tanhf(gis[2*EMB + tid] + rg*ghs[2*EMB + tid]);
        hs[tid] = (1.f - z)*n + z*hs[tid];
    }
    __syncthreads();
    // gh step 2 with updated hs
    for (int i = 0; i < 96; ++i) {
        const int l = wv * 96 + i;
        ushort4 wh = *reinterpret_cast<const ushort4*>(&whhbf[(size_t)l*EMB + (lane << 2)]);
        float4 h4 = *reinterpret_cast<const float4*>(&hs[lane << 2]);
        float dh = bf2f(wh.x)*h4.x + bf2f(wh.y)*h4.y + bf2f(wh.z)*h4.z + bf2f(wh.w)*h4.w;
        #pragma unroll
        for (int off = 32; off; off >>= 1) dh += __shfl_xor(dh, off, 64);
        if (lane == 0) ghs[l] = dh + bhh[l];
    }
    __syncthreads();
    if (tid < EMB) {
        float rg = sigm(gis[tid] + ghs[tid]);
        float z  = sigm(gis[EMB + tid] + ghs[EMB + tid]);
        float n  = tanhf(gis[2*EMB + tid] + rg*ghs[2*EMB + tid]);
        float hv = (1.f - z)*n + z*hs[tid];
        actseq[b*EMB + tid] = fmaxf(hv, 0.f);
    }
}

extern "C" void kernel_launch(void* const* d_in, const int* in_sizes, int n_in,
                              void* d_out, int out_size, void* d_ws, size_t ws_size,
                              hipStream_t stream) {
    (void)in_sizes; (void)n_in; (void)out_size; (void)ws_size;
    const float* amino  = (const float*)d_in[0];
    const float* mask   = (const float*)d_in[1];
    const float* embW   = (const float*)d_in[2];
    const float* embB   = (const float*)d_in[3];
    const float* nbW    = (const float*)d_in[4];
    const float* nbB    = (const float*)d_in[5];
    const float* alignW = (const float*)d_in[6];
    const float* alignB = (const float*)d_in[7];
    const float* attW   = (const float*)d_in[8];
    const float* attB   = (const float*)d_in[9];
    const float* gwih   = (const float*)d_in[10];
    const float* gwhh   = (const float*)d_in[11];
    const float* gbih   = (const float*)d_in[12];
    const float* gbhh   = (const float*)d_in[13];
    const float* saW    = (const float*)d_in[14];
    const float* saB    = (const float*)d_in[15];
    const float* satW   = (const float*)d_in[16];
    const float* satB   = (const float*)d_in[17];
    const float* sgwih  = (const float*)d_in[18];
    const float* sgbih  = (const float*)d_in[19];
    const float* sgwhh  = (const float*)d_in[20];
    const float* sgbhh  = (const float*)d_in[21];
    const int*   idx    = (const int*)d_in[22];

    char* cur = (char*)d_ws;
    auto alloc = [&](size_t bytes) -> char* {
        char* p = cur; cur += (bytes + 255) & ~(size_t)255; return p;
    };
    float* feat    = (float*)alloc((size_t)BS*EMB*4);
    float* nbase   = (float*)alloc((size_t)BS*EMB*4);
    float* h       = (float*)alloc((size_t)BS*EMB*4);
    float* tf      = (float*)alloc((size_t)BS*EMB*4);
    float* cdot    = (float*)alloc(BS*4);
    float* ndot    = (float*)alloc(BS*4);   // doubles as ad after round 2
    float* wsum    = (float*)alloc(BS*4);
    float* seqfeat = (float*)alloc(BSZ*EMB*4);
    float* cmol    = (float*)alloc(64*4);
    float* partial = (float*)alloc((size_t)BSZ*16*EMB*4);
    ushort* aminobf  = (ushort*)alloc((size_t)BS*INITD*2);
    ushort* featbf   = (ushort*)alloc((size_t)BS*EMB*2);
    ushort* nbasebf  = (ushort*)alloc((size_t)BS*EMB*2);
    ushort* actbf    = (ushort*)alloc((size_t)BS*EMB*2);
    ushort* hbf      = (ushort*)alloc((size_t)BS*EMB*2);
    ushort* ctxprebf = (ushort*)alloc((size_t)BS*EMB*2);
    ushort* embWbf   = (ushort*)alloc((size_t)EMB*INITD*2);
    ushort* nbWbf    = (ushort*)alloc((size_t)EMB*INITD*2);
    ushort* attWbf   = (ushort*)alloc((size_t)3*EMB*EMB*2);
    ushort* gwihbf   = (ushort*)alloc((size_t)3*G3*EMB*2);
    ushort* gwhhbf   = (ushort*)alloc((size_t)3*G3*EMB*2);
    ushort* satWbf   = (ushort*)alloc((size_t)EMB*EMB*2);
    ushort* sgwihbf  = (ushort*)alloc((size_t)G3*EMB*2);
    ushort* sgwhhbf  = (ushort*)alloc((size_t)G3*EMB*2);

    float* out    = (float*)d_out;
    float* actseq = out;               // (B,E)
    float* act    = out + BSZ*EMB;     // (B,S,E)

    convert9_kernel<<<dim3(1024, 9), 256, 0, stream>>>(
        amino, aminobf, BS*INITD,
        embW,  embWbf,  EMB*INITD,
        nbW,   nbWbf,   EMB*INITD,
        attW,  attWbf,  3*EMB*EMB,
        gwih,  gwihbf,  3*G3*EMB,
        gwhh,  gwhhbf,  3*G3*EMB,
        satW,  satWbf,  EMB*EMB,
        sgwih, sgwihbf, G3*EMB,
        sgwhh, sgwhhbf, G3*EMB);

    featnbase_kernel<<<256, 256, 0, stream>>>(
        aminobf, embWbf, embB, feat, featbf, nbWbf, nbB, nbase, nbasebf);

    dot2_kernel<<<128, 256, 0, stream>>>(feat, nbase, alignW, cdot, ndot);

    for (int d = 0; d < 3; ++d) {
        const ushort* nbrbf   = (d == 0) ? nbasebf : actbf;
        const float*  hprev   = (d == 0) ? feat    : h;
        const ushort* hprevbf = (d == 0) ? featbf  : hbf;
        gather_kernel<<<BS/4, 256, 0, stream>>>(
            cdot, ndot, idx, nbrbf, alignB + d, ctxprebf, wsum);
        if (d < 2) {
            fusedD_kernel<0><<<BS/16, 512, 0, stream>>>(
                ctxprebf, wsum, attWbf + (size_t)d*EMB*EMB, attB + d*EMB,
                gwihbf + (size_t)d*G3*EMB, gbih + d*G3,
                gwhhbf + (size_t)d*G3*EMB, gbhh + d*G3,
                hprev, hprevbf, alignW + (d+1)*2*EMB,
                h, hbf, act, actbf, cdot, ndot);
        } else {
            fusedD_kernel<1><<<BS/16, 512, 0, stream>>>(
                ctxprebf, wsum, attWbf + (size_t)d*EMB*EMB, attB + d*EMB,
                gwihbf + (size_t)d*G3*EMB, gbih + d*G3,
                gwhhbf + (size_t)d*G3*EMB, gbhh + d*G3,
                hprev, hprevbf, saW,
                h, hbf, act, actbf, cdot, ndot);   // ndot <- ad
        }
    }

    seqpre_kernel<<<136, 256, 0, stream>>>(
        actbf, satWbf, satB, tf, act, mask, saW, seqfeat, cmol);
    seqpv2_kernel<<<dim3(16, BSZ), 256, 0, stream>>>(ndot, mask, saB, cmol, tf, partial);
    seqtail_kernel<<<BSZ, 512, 0, stream>>>(
        partial, seqfeat, sgwihbf, sgbih, sgwhhbf, sgbhh, actseq);
}

// Round 10
// 238.553 us; speedup vs baseline: 4.0111x; 1.3479x over previous
//
#include <hip/hip_runtime.h>
#include <math.h>

// ProGAT: B=8,S=512,NB=23,INIT=512,E=256,R=3,T=2
// R10: 10 dispatches. fusedE = gather+attend+gi+gh+GRU+next-dot per round
// (gather inlined: its inputs cdot/ndot/actbf are complete before dispatch).
// Tail reverted to R5's parallel 32-block seqstep (R9's 8-block seqtail was
// a 135us latency disaster).

#define BSZ   8
#define SEQ   512
#define NBR   23
#define EMB   256
#define INITD 512
#define BS    (BSZ*SEQ)     // 4096
#define G3    (3*EMB)       // 768
#define NEGV  -9e8f

typedef __attribute__((ext_vector_type(8))) short short8;
typedef __attribute__((ext_vector_type(4))) float f32x4;

__device__ __forceinline__ float lrelu(float x){ return x > 0.f ? x : 0.01f*x; }
__device__ __forceinline__ float elu1 (float x){ return x > 0.f ? x : (expf(x)-1.f); }
__device__ __forceinline__ float sigm (float x){ return 1.f/(1.f+expf(-x)); }
__device__ __forceinline__ float bf2f(ushort u){
    union { unsigned int i; float f; } v; v.i = ((unsigned int)u) << 16; return v.f;
}
__device__ __forceinline__ ushort f2bf(float f){
    union { float f; unsigned int i; } v; v.f = f;
    unsigned int u = v.i;
    return (ushort)((u + 0x7FFFu + ((u >> 16) & 1u)) >> 16);   // RNE
}
__device__ __forceinline__ unsigned pk2(float a, float b){
    return (unsigned)f2bf(a) | ((unsigned)f2bf(b) << 16);
}
__device__ __forceinline__ void unpack8(uint4 v, float* o) {
    o[0]=bf2f((ushort)(v.x&0xffff)); o[1]=bf2f((ushort)(v.x>>16));
    o[2]=bf2f((ushort)(v.y&0xffff)); o[3]=bf2f((ushort)(v.y>>16));
    o[4]=bf2f((ushort)(v.z&0xffff)); o[5]=bf2f((ushort)(v.z>>16));
    o[6]=bf2f((ushort)(v.w&0xffff)); o[7]=bf2f((ushort)(v.w>>16));
}

__device__ __forceinline__ void gload_lds16(const void* g, void* l) {
    __builtin_amdgcn_global_load_lds(
        (const __attribute__((address_space(1))) unsigned int*)g,
        (__attribute__((address_space(3))) unsigned int*)l,
        16, 0, 0);
}

// ---- fp32 -> bf16 converter, 9 segments in one dispatch (blockIdx.y = seg)
__global__ __launch_bounds__(256) void convert9_kernel(
    const float* s0, ushort* d0, int n0,
    const float* s1, ushort* d1, int n1,
    const float* s2, ushort* d2, int n2,
    const float* s3, ushort* d3, int n3,
    const float* s4, ushort* d4, int n4,
    const float* s5, ushort* d5, int n5,
    const float* s6, ushort* d6, int n6,
    const float* s7, ushort* d7, int n7,
    const float* s8, ushort* d8, int n8)
{
    const float* srcs[9] = {s0,s1,s2,s3,s4,s5,s6,s7,s8};
    ushort* dsts[9] = {d0,d1,d2,d3,d4,d5,d6,d7,d8};
    int ns[9] = {n0,n1,n2,n3,n4,n5,n6,n7,n8};
    int seg = blockIdx.y;
    const float* s = srcs[seg]; ushort* d = dsts[seg]; int n = ns[seg];
    size_t i = ((size_t)blockIdx.x * 256 + threadIdx.x) * 8;
    size_t stride = (size_t)gridDim.x * 256 * 8;
    for (; i < (size_t)n; i += stride) {
        float4 a = *reinterpret_cast<const float4*>(s + i);
        float4 b = *reinterpret_cast<const float4*>(s + i + 4);
        uint4 o;
        o.x = pk2(a.x, a.y); o.y = pk2(a.z, a.w);
        o.z = pk2(b.x, b.y); o.w = pk2(b.z, b.w);
        *reinterpret_cast<uint4*>(d + i) = o;
    }
}

// ---- 128x64 MFMA GEMM; global_load_lds staging, dbuf
struct GemmLds64 { ushort A[2][128][64]; ushort B[2][64][64]; };

template<int ACT>
__device__ __forceinline__ void gemm64_dev(
    const ushort* __restrict__ A, const ushort* __restrict__ W,
    const float* __restrict__ bias,
    float* __restrict__ C, ushort* __restrict__ Cbf,
    int N, int K, int bx, int by, GemmLds64& L)
{
    const int tid = threadIdx.x;
    const int m0 = bx * 128, n0 = by * 64;
    const int wv = tid >> 6, lane = tid & 63;
    const int fr = lane & 15, grp = lane >> 4;
    const int kc = K >> 3;
    const int mh = wv & 1, nh = wv >> 1;
    const int lrow = lane >> 3;
    const int csrc = (lane & 7) ^ lrow;

    f32x4 acc[4][2];
    #pragma unroll
    for (int i = 0; i < 4; ++i)
        #pragma unroll
        for (int n = 0; n < 2; ++n) acc[i][n] = (f32x4){0.f,0.f,0.f,0.f};

    auto stage = [&](int c, int k0) {
        const int kch = (k0 >> 3) + csrc;
        #pragma unroll
        for (int i = 0; i < 4; ++i) {
            const int s = (wv << 2) + i;
            gload_lds16(A + ((size_t)(m0 + (s << 3) + lrow) * kc + kch) * 8,
                        &L.A[c][s << 3][0]);
        }
        #pragma unroll
        for (int i = 0; i < 2; ++i) {
            const int s = (wv << 1) + i;
            gload_lds16(W + ((size_t)(n0 + (s << 3) + lrow) * kc + kch) * 8,
                        &L.B[c][s << 3][0]);
        }
    };
    auto compute = [&](int c) {
        #pragma unroll
        for (int ks = 0; ks < 2; ++ks) {
            short8 af[4];
            #pragma unroll
            for (int i = 0; i < 4; ++i) {
                const int ar = (mh << 6) + (i << 4) + fr;
                af[i] = *reinterpret_cast<const short8*>(
                    &L.A[c][ar][(((ks << 2) + grp) ^ (ar & 7)) << 3]);
            }
            #pragma unroll
            for (int n = 0; n < 2; ++n) {
                const int br = (nh << 5) + (n << 4) + fr;
                short8 bv = *reinterpret_cast<const short8*>(
                    &L.B[c][br][(((ks << 2) + grp) ^ (br & 7)) << 3]);
                #pragma unroll
                for (int i = 0; i < 4; ++i)
                    acc[i][n] = __builtin_amdgcn_mfma_f32_16x16x32_bf16(
                        af[i], bv, acc[i][n], 0, 0, 0);
            }
        }
    };

    const int KT = K >> 6;
    stage(0, 0);
    __syncthreads();
    int cur = 0;
    for (int kt = 1; kt < KT; ++kt) {
        stage(cur ^ 1, kt << 6);
        compute(cur);
        __syncthreads();
        cur ^= 1;
    }
    compute(cur);

    #pragma unroll
    for (int i = 0; i < 4; ++i) {
        const int mrow = m0 + (mh << 6) + (i << 4) + (grp << 2);
        #pragma unroll
        for (int n = 0; n < 2; ++n) {
            const int col = n0 + (nh << 5) + (n << 4) + fr;
            const float bv = bias[col];
            #pragma unroll
            for (int j = 0; j < 4; ++j) {
                float t = acc[i][n][j] + bv;
                if (ACT == 1) t = lrelu(t);
                size_t off = (size_t)(mrow + j) * N + col;
                if (C)   C[off] = t;
                if (Cbf) Cbf[off] = f2bf(t);
            }
        }
    }
}

// ---- fat: feat GEMM (0..127) + nbase GEMM (128..255), K=512
__global__ __launch_bounds__(256) void featnbase_kernel(
    const ushort* __restrict__ aminobf,
    const ushort* __restrict__ embWbf, const float* __restrict__ embB,
    float* __restrict__ feat, ushort* __restrict__ featbf,
    const ushort* __restrict__ nbWbf, const float* __restrict__ nbB,
    float* __restrict__ nbase, ushort* __restrict__ nbasebf)
{
    __shared__ GemmLds64 L;
    int blk = blockIdx.x;
    if (blk < 128)
        gemm64_dev<1>(aminobf, embWbf, embB, feat, featbf, EMB, INITD, blk & 31, blk >> 5, L);
    else {
        blk -= 128;
        gemm64_dev<1>(aminobf, nbWbf, nbB, nbase, nbasebf, EMB, INITD, blk & 31, blk >> 5, L);
    }
}

// ---- dot2 for round 0: 128 blocks x 32 rows
__global__ __launch_bounds__(256) void dot2_kernel(
    const float* __restrict__ center, const float* __restrict__ nbrbase,
    const float* __restrict__ alignWd,
    float* __restrict__ cdot, float* __restrict__ ndot)
{
    const int lane = threadIdx.x & 63;
    const int wv   = threadIdx.x >> 6;
    const int e    = lane << 2;
    const int rb   = blockIdx.x * 32 + wv * 8;
    float4 w0 = *reinterpret_cast<const float4*>(&alignWd[e]);
    float4 w1 = *reinterpret_cast<const float4*>(&alignWd[EMB + e]);
    #pragma unroll
    for (int i = 0; i < 8; ++i) {
        const int r = rb + i;
        float4 xc = *reinterpret_cast<const float4*>(&center[(size_t)r*EMB + e]);
        float4 xn = *reinterpret_cast<const float4*>(&nbrbase[(size_t)r*EMB + e]);
        float ac = xc.x*w0.x + xc.y*w0.y + xc.z*w0.z + xc.w*w0.w;
        float an = xn.x*w1.x + xn.y*w1.y + xn.z*w1.z + xn.w*w1.w;
        #pragma unroll
        for (int off = 32; off; off >>= 1) {
            ac += __shfl_xor(ac, off, 64);
            an += __shfl_xor(an, off, 64);
        }
        if (lane == 0) { cdot[r] = ac; ndot[r] = an; }
    }
}

// ---- fusedE: per 16-row block (512 thr):
// A: gather (softmax over 23 nbrs; ctxpre -> LDS) + stage hprevbf
// B: ctx = elu(attW@ctxpre + wsum*attB)    (MFMA, B streamed from L2)
// C: gi = wih@ctx; gh = whh@hprev          (MFMA)
// D: GRU + next-round dot2 (or seq ad if LAST)
struct DLds {
    ushort ctxpre[16][256];
    ushort ctx[16][256];
    ushort hpv[16][256];
    ushort gis[16][768];
    ushort ghs[16][768];
    float  wsum_s[16];
};

template<int LAST>
__global__ __launch_bounds__(512, 4) void fusedE_kernel(
    const float* __restrict__ cdot, const float* __restrict__ ndot,
    const int* __restrict__ idx, const ushort* __restrict__ nbr,
    const float* __restrict__ alignBd,
    const ushort* __restrict__ attWd, const float* __restrict__ attBd,
    const ushort* __restrict__ gwihd, const float* __restrict__ gbihd,
    const ushort* __restrict__ gwhhd, const float* __restrict__ gbhhd,
    const float* __restrict__ hprev, const ushort* __restrict__ hprevbf,
    const float* __restrict__ nextW,
    float* __restrict__ hout, ushort* __restrict__ hbf,
    float* __restrict__ actout, ushort* __restrict__ actbf,
    float* __restrict__ cdotO, float* __restrict__ ndotO)
{
    __shared__ DLds L;
    const int tid = threadIdx.x;
    const int r0 = blockIdx.x * 16;

    {   // Phase A: gather + hprev staging. 16 groups x 32 lanes.
        const int row16 = tid >> 5, sub = tid & 31;
        const int r = r0 + row16, b = r >> 9;
        uint4 hsrc = *reinterpret_cast<const uint4*>(&hprevbf[(size_t)r*EMB + (sub<<3)]);
        *reinterpret_cast<uint4*>(&L.hpv[row16][(sub ^ (row16&7)) << 3]) = hsrc;
        float sc = -3e38f, vm = 0.f; int rn = 0;
        if (sub < NBR) {
            int j = idx[(size_t)r*NBR + sub];
            int valid = (j >= 0);
            int jj = valid ? j : j + SEQ;   // JAX wrap: f[-1] = last row
            rn = b*SEQ + jj;
            vm = (float)valid;
            sc = lrelu(cdot[r] + ndot[rn] + alignBd[0]) + (valid ? 0.f : NEGV);
        }
        float m = sc;
        #pragma unroll
        for (int off = 16; off; off >>= 1) m = fmaxf(m, __shfl_xor(m, off, 32));
        float ev = (sub < NBR) ? expf(sc - m) : 0.f;
        float s = ev;
        #pragma unroll
        for (int off = 16; off; off >>= 1) s += __shfl_xor(s, off, 32);
        float wgt = ev * vm / s;
        float ws = wgt;
        #pragma unroll
        for (int off = 16; off; off >>= 1) ws += __shfl_xor(ws, off, 32);
        float a8[8] = {};
        const int e0 = sub << 3;
        #pragma unroll 1
        for (int n = 0; n < NBR; ++n) {
            float wn = __shfl(wgt, n, 32);
            int   rr = __shfl(rn, n, 32);
            uint4 v = *reinterpret_cast<const uint4*>(&nbr[(size_t)rr*EMB + e0]);
            float x[8]; unpack8(v, x);
            #pragma unroll
            for (int i = 0; i < 8; ++i) a8[i] += wn * x[i];
        }
        uint4 o;
        o.x = pk2(a8[0],a8[1]); o.y = pk2(a8[2],a8[3]);
        o.z = pk2(a8[4],a8[5]); o.w = pk2(a8[6],a8[7]);
        *reinterpret_cast<uint4*>(&L.ctxpre[row16][(sub ^ (row16&7)) << 3]) = o;
        if (sub == 0) L.wsum_s[row16] = ws;
    }
    __syncthreads();

    const int wv = tid >> 6, lane = tid & 63;
    const int fr = lane & 15, grp = lane >> 4;

    {   // Phase B: attend. wave owns cols wv*32 + f*16 + fr, f in 0..1
        f32x4 acc[2] = {(f32x4){0,0,0,0},(f32x4){0,0,0,0}};
        #pragma unroll
        for (int kt = 0; kt < 8; ++kt) {
            short8 af = *reinterpret_cast<const short8*>(
                &L.ctxpre[fr][((((kt<<2)+grp) ^ (fr&7)) << 3)]);
            #pragma unroll
            for (int f = 0; f < 2; ++f) {
                const int col = (wv<<5) + (f<<4) + fr;
                short8 bv = *reinterpret_cast<const short8*>(
                    &attWd[(size_t)col*EMB + (kt<<5) + (grp<<3)]);
                acc[f] = __builtin_amdgcn_mfma_f32_16x16x32_bf16(af, bv, acc[f], 0, 0, 0);
            }
        }
        #pragma unroll
        for (int f = 0; f < 2; ++f) {
            const int col = (wv<<5) + (f<<4) + fr;
            const float bb = attBd[col];
            const int ch = col >> 3;
            #pragma unroll
            for (int j = 0; j < 4; ++j) {
                const int row = (grp<<2) + j;
                float t = elu1(acc[f][j] + L.wsum_s[row]*bb);
                L.ctx[row][(((ch ^ (row&7)) << 3) | (col & 7))] = f2bf(t);
            }
        }
    }
    __syncthreads();

    {   // Phase C: gi (A=ctx) and gh (A=hprev); cols wv*96 + f*16 + fr
        f32x4 acc[6];
        #pragma unroll
        for (int f = 0; f < 6; ++f) acc[f] = (f32x4){0,0,0,0};
        #pragma unroll
        for (int kt = 0; kt < 8; ++kt) {
            short8 af = *reinterpret_cast<const short8*>(
                &L.ctx[fr][((((kt<<2)+grp) ^ (fr&7)) << 3)]);
            #pragma unroll
            for (int f = 0; f < 6; ++f) {
                const int col = wv*96 + (f<<4) + fr;
                short8 bv = *reinterpret_cast<const short8*>(
                    &gwihd[(size_t)col*EMB + (kt<<5) + (grp<<3)]);
                acc[f] = __builtin_amdgcn_mfma_f32_16x16x32_bf16(af, bv, acc[f], 0, 0, 0);
            }
        }
        #pragma unroll
        for (int f = 0; f < 6; ++f) {
            const int col = wv*96 + (f<<4) + fr;
            const float bb = gbihd[col];
            #pragma unroll
            for (int j = 0; j < 4; ++j)
                L.gis[(grp<<2)+j][col] = f2bf(acc[f][j] + bb);
        }
        #pragma unroll
        for (int f = 0; f < 6; ++f) acc[f] = (f32x4){0,0,0,0};
        #pragma unroll
        for (int kt = 0; kt < 8; ++kt) {
            short8 af = *reinterpret_cast<const short8*>(
                &L.hpv[fr][((((kt<<2)+grp) ^ (fr&7)) << 3)]);
            #pragma unroll
            for (int f = 0; f < 6; ++f) {
                const int col = wv*96 + (f<<4) + fr;
                short8 bv = *reinterpret_cast<const short8*>(
                    &gwhhd[(size_t)col*EMB + (kt<<5) + (grp<<3)]);
                acc[f] = __builtin_amdgcn_mfma_f32_16x16x32_bf16(af, bv, acc[f], 0, 0, 0);
            }
        }
        #pragma unroll
        for (int f = 0; f < 6; ++f) {
            const int col = wv*96 + (f<<4) + fr;
            const float bb = gbhhd[col];
            #pragma unroll
            for (int j = 0; j < 4; ++j)
                L.ghs[(grp<<2)+j][col] = f2bf(acc[f][j] + bb);
        }
    }
    __syncthreads();

    {   // Phase D: GRU + next-round dots. 16 rows x 32 threads, 8 e/thread
        const int row = tid >> 5, sub = tid & 31;
        const int e0 = sub << 3;
        const size_t r = (size_t)r0 + row;
        uint4 giA = *reinterpret_cast<const uint4*>(&L.gis[row][e0]);
        uint4 giB = *reinterpret_cast<const uint4*>(&L.gis[row][256 + e0]);
        uint4 giC = *reinterpret_cast<const uint4*>(&L.gis[row][512 + e0]);
        uint4 ghA = *reinterpret_cast<const uint4*>(&L.ghs[row][e0]);
        uint4 ghB = *reinterpret_cast<const uint4*>(&L.ghs[row][256 + e0]);
        uint4 ghC = *reinterpret_cast<const uint4*>(&L.ghs[row][512 + e0]);
        float4 hp0 = *reinterpret_cast<const float4*>(&hprev[r*EMB + e0]);
        float4 hp1 = *reinterpret_cast<const float4*>(&hprev[r*EMB + e0 + 4]);
        float ir_[8], iz_[8], in_[8], hr_[8], hz_[8], hn_[8];
        unpack8(giA, ir_); unpack8(giB, iz_); unpack8(giC, in_);
        unpack8(ghA, hr_); unpack8(ghB, hz_); unpack8(ghC, hn_);
        const float hp_[8] = {hp0.x,hp0.y,hp0.z,hp0.w,hp1.x,hp1.y,hp1.z,hp1.w};
        float hv8[8], av8[8];
        #pragma unroll
        for (int i = 0; i < 8; ++i) {
            float rg = sigm(ir_[i] + hr_[i]);
            float z  = sigm(iz_[i] + hz_[i]);
            float n  = tanhf(in_[i] + rg*hn_[i]);
            hv8[i] = (1.f - z)*n + z*hp_[i];
            av8[i] = fmaxf(hv8[i], 0.f);
        }
        *reinterpret_cast<float4*>(&hout[r*EMB + e0])       = make_float4(hv8[0],hv8[1],hv8[2],hv8[3]);
        *reinterpret_cast<float4*>(&hout[r*EMB + e0 + 4])   = make_float4(hv8[4],hv8[5],hv8[6],hv8[7]);
        *reinterpret_cast<float4*>(&actout[r*EMB + e0])     = make_float4(av8[0],av8[1],av8[2],av8[3]);
        *reinterpret_cast<float4*>(&actout[r*EMB + e0 + 4]) = make_float4(av8[4],av8[5],av8[6],av8[7]);
        uint4 hb, ab;
        hb.x = pk2(hv8[0],hv8[1]); hb.y = pk2(hv8[2],hv8[3]);
        hb.z = pk2(hv8[4],hv8[5]); hb.w = pk2(hv8[6],hv8[7]);
        ab.x = pk2(av8[0],av8[1]); ab.y = pk2(av8[2],av8[3]);
        ab.z = pk2(av8[4],av8[5]); ab.w = pk2(av8[6],av8[7]);
        *reinterpret_cast<uint4*>(&hbf[r*EMB + e0])   = hb;
        *reinterpret_cast<uint4*>(&actbf[r*EMB + e0]) = ab;
        float pc = 0.f, pn = 0.f;
        float4 w1a = *reinterpret_cast<const float4*>(&nextW[EMB + e0]);
        float4 w1b = *reinterpret_cast<const float4*>(&nextW[EMB + e0 + 4]);
        pn = av8[0]*w1a.x + av8[1]*w1a.y + av8[2]*w1a.z + av8[3]*w1a.w
           + av8[4]*w1b.x + av8[5]*w1b.y + av8[6]*w1b.z + av8[7]*w1b.w;
        if (!LAST) {
            float4 w0a = *reinterpret_cast<const float4*>(&nextW[e0]);
            float4 w0b = *reinterpret_cast<const float4*>(&nextW[e0 + 4]);
            pc = av8[0]*w0a.x + av8[1]*w0a.y + av8[2]*w0a.z + av8[3]*w0a.w
               + av8[4]*w0b.x + av8[5]*w0b.y + av8[6]*w0b.z + av8[7]*w0b.w;
        }
        #pragma unroll
        for (int off = 16; off; off >>= 1) {
            pn += __shfl_xor(pn, off, 32);
            if (!LAST) pc += __shfl_xor(pc, off, 32);
        }
        if (sub == 0) {
            if (!LAST) cdotO[r] = pc;
            ndotO[r] = pn;
        }
    }
}

// ---- fat: tf GEMM (0..127, BN=64) + seqsum (128..135)
__global__ __launch_bounds__(256) void seqpre_kernel(
    const ushort* __restrict__ actbf, const ushort* __restrict__ satWbf,
    const float* __restrict__ satB, float* __restrict__ tf,
    const float* __restrict__ act, const float* __restrict__ mask,
    const float* __restrict__ saW,
    float* __restrict__ seqfeat, float* __restrict__ cmol)
{
    __shared__ GemmLds64 L;
    int blk = blockIdx.x;
    if (blk < 128) {
        gemm64_dev<0>(actbf, satWbf, satB, tf, nullptr, EMB, EMB, blk & 31, blk >> 5, L);
    } else {
        const int b = blk - 128;
        const int e = threadIdx.x;
        float acc = 0.f;
        for (int s = 0; s < SEQ; ++s)
            acc += act[((size_t)b*SEQ + s)*EMB + e] * mask[b*SEQ + s];
        seqfeat[b*EMB + e] = acc;
        float* red = reinterpret_cast<float*>(&L);
        red[e] = fmaxf(acc, 0.f) * saW[e];
        __syncthreads();
        for (int off = 128; off; off >>= 1) {
            if (e < off) red[e] += red[e + off];
            __syncthreads();
        }
        if (e == 0) cmol[b] = red[0];
    }
}

// softmax (redundant per block) + PV strip: block (st,b) -> partial[b,st,:]
__global__ __launch_bounds__(256) void seqpv2_kernel(
    const float* __restrict__ ad, const float* __restrict__ mask,
    const float* __restrict__ saB, const float* __restrict__ cmol,
    const float* __restrict__ tf, float* __restrict__ partial)
{
    const int st = blockIdx.x, b = blockIdx.y;
    const int tid = threadIdx.x;
    __shared__ float w_s[SEQ];
    __shared__ float red[256];
    float mk0 = mask[b*SEQ + tid], mk1 = mask[b*SEQ + 256 + tid];
    float cb = cmol[b], bb = saB[0];
    float s0 = lrelu(cb + ad[b*SEQ + tid] + bb)       + (mk0 == 0.f ? NEGV : 0.f);
    float s1 = lrelu(cb + ad[b*SEQ + 256 + tid] + bb) + (mk1 == 0.f ? NEGV : 0.f);
    red[tid] = fmaxf(s0, s1); __syncthreads();
    for (int off = 128; off; off >>= 1) {
        if (tid < off) red[tid] = fmaxf(red[tid], red[tid + off]);
        __syncthreads();
    }
    float m = red[0]; __syncthreads();
    float e0 = expf(s0 - m), e1 = expf(s1 - m);
    red[tid] = e0 + e1; __syncthreads();
    for (int off = 128; off; off >>= 1) {
        if (tid < off) red[tid] += red[tid + off];
        __syncthreads();
    }
    float inv = 1.f / red[0];
    w_s[tid]       = e0 * inv * mk0;
    w_s[tid + 256] = e1 * inv * mk1;
    __syncthreads();
    float acc = 0.f;
    const int s0i = st * 32;
    #pragma unroll 4
    for (int s = s0i; s < s0i + 32; ++s)
        acc += w_s[s] * tf[((size_t)b*SEQ + s)*EMB + tid];
    partial[((size_t)b*16 + st)*EMB + tid] = acc;
}

// Fused tail GRU step (R5-proven). Grid 32: (b, quarter q). 512 thr, 8 waves.
template<int T0>
__global__ __launch_bounds__(512) void seqstep_kernel(
    const float* __restrict__ partial, const float* __restrict__ sfin,
    const ushort* __restrict__ sgwihbf, const float* __restrict__ sgbih,
    const ushort* __restrict__ sgwhhbf, const float* __restrict__ sgbhh,
    float* __restrict__ sgi, float* __restrict__ sfout,
    float* __restrict__ actseq)
{
    const int b = blockIdx.x >> 2, q = blockIdx.x & 3;
    const int tid = threadIdx.x, lane = tid & 63, wv = tid >> 6;
    __shared__ float xs[EMB];
    __shared__ float hs[EMB];
    __shared__ float gis[192], ghs[192];
    if (tid < EMB) {
        hs[tid] = sfin[b*EMB + tid];
        if (T0) {
            float a = 0.f;
            #pragma unroll
            for (int st = 0; st < 16; ++st)
                a += partial[((size_t)b*16 + st)*EMB + tid];
            xs[tid] = elu1(a);
        }
    }
    if (!T0) {
        for (int l = tid; l < 192; l += 512) {
            int g = (l >> 6)*EMB + (q << 6) + (l & 63);
            gis[l] = sgi[b*G3 + g];
        }
    }
    __syncthreads();
    const int nrows = T0 ? 384 : 192;
    const int rpw = nrows >> 3;
    for (int i = 0; i < rpw; ++i) {
        const int l = wv * rpw + i;
        const int iswih = T0 && (l < 192);
        const int ll = (T0 && l >= 192) ? l - 192 : l;
        const int g = (ll >> 6)*EMB + (q << 6) + (ll & 63);
        const ushort* Wm = iswih ? sgwihbf : sgwhhbf;
        ushort4 w4 = *reinterpret_cast<const ushort4*>(&Wm[(size_t)g*EMB + (lane << 2)]);
        float4 x4 = *reinterpret_cast<const float4*>(iswih ? &xs[lane << 2] : &hs[lane << 2]);
        float d = bf2f(w4.x)*x4.x + bf2f(w4.y)*x4.y + bf2f(w4.z)*x4.z + bf2f(w4.w)*x4.w;
        #pragma unroll
        for (int off = 32; off; off >>= 1) d += __shfl_xor(d, off, 64);
        if (lane == 0) {
            if (iswih) {
                d += sgbih[g];
                gis[ll] = d;
                sgi[b*G3 + g] = d;
            } else {
                ghs[ll] = d + sgbhh[g];
            }
        }
    }
    __syncthreads();
    if (tid < 64) {
        const int e = (q << 6) + tid;
        float rg = sigm(gis[tid]       + ghs[tid]);
        float z  = sigm(gis[64 + tid]  + ghs[64 + tid]);
        float n  = tanhf(gis[128 + tid] + rg*ghs[128 + tid]);
        float hv = (1.f - z)*n + z*hs[e];
        sfout[b*EMB + e]  = hv;
        actseq[b*EMB + e] = fmaxf(hv, 0.f);
    }
}

extern "C" void kernel_launch(void* const* d_in, const int* in_sizes, int n_in,
                              void* d_out, int out_size, void* d_ws, size_t ws_size,
                              hipStream_t stream) {
    (void)in_sizes; (void)n_in; (void)out_size; (void)ws_size;
    const float* amino  = (const float*)d_in[0];
    const float* mask   = (const float*)d_in[1];
    const float* embW   = (const float*)d_in[2];
    const float* embB   = (const float*)d_in[3];
    const float* nbW    = (const float*)d_in[4];
    const float* nbB    = (const float*)d_in[5];
    const float* alignW = (const float*)d_in[6];
    const float* alignB = (const float*)d_in[7];
    const float* attW   = (const float*)d_in[8];
    const float* attB   = (const float*)d_in[9];
    const float* gwih   = (const float*)d_in[10];
    const float* gwhh   = (const float*)d_in[11];
    const float* gbih   = (const float*)d_in[12];
    const float* gbhh   = (const float*)d_in[13];
    const float* saW    = (const float*)d_in[14];
    const float* saB    = (const float*)d_in[15];
    const float* satW   = (const float*)d_in[16];
    const float* satB   = (const float*)d_in[17];
    const float* sgwih  = (const float*)d_in[18];
    const float* sgbih  = (const float*)d_in[19];
    const float* sgwhh  = (const float*)d_in[20];
    const float* sgbhh  = (const float*)d_in[21];
    const int*   idx    = (const int*)d_in[22];

    char* cur = (char*)d_ws;
    auto alloc = [&](size_t bytes) -> char* {
        char* p = cur; cur += (bytes + 255) & ~(size_t)255; return p;
    };
    float* feat    = (float*)alloc((size_t)BS*EMB*4);
    float* nbase   = (float*)alloc((size_t)BS*EMB*4);
    float* h       = (float*)alloc((size_t)BS*EMB*4);
    float* tf      = (float*)alloc((size_t)BS*EMB*4);
    float* cdot    = (float*)alloc(BS*4);
    float* ndot    = (float*)alloc(BS*4);   // doubles as ad after round 2
    float* seqfeat = (float*)alloc(BSZ*EMB*4);
    float* sf2     = (float*)alloc(BSZ*EMB*4);
    float* cmol    = (float*)alloc(64*4);
    float* sgi     = (float*)alloc(BSZ*G3*4);
    float* partial = (float*)alloc((size_t)BSZ*16*EMB*4);
    ushort* aminobf  = (ushort*)alloc((size_t)BS*INITD*2);
    ushort* featbf   = (ushort*)alloc((size_t)BS*EMB*2);
    ushort* nbasebf  = (ushort*)alloc((size_t)BS*EMB*2);
    ushort* actbf    = (ushort*)alloc((size_t)BS*EMB*2);
    ushort* hbf      = (ushort*)alloc((size_t)BS*EMB*2);
    ushort* embWbf   = (ushort*)alloc((size_t)EMB*INITD*2);
    ushort* nbWbf    = (ushort*)alloc((size_t)EMB*INITD*2);
    ushort* attWbf   = (ushort*)alloc((size_t)3*EMB*EMB*2);
    ushort* gwihbf   = (ushort*)alloc((size_t)3*G3*EMB*2);
    ushort* gwhhbf   = (ushort*)alloc((size_t)3*G3*EMB*2);
    ushort* satWbf   = (ushort*)alloc((size_t)EMB*EMB*2);
    ushort* sgwihbf  = (ushort*)alloc((size_t)G3*EMB*2);
    ushort* sgwhhbf  = (ushort*)alloc((size_t)G3*EMB*2);

    float* out    = (float*)d_out;
    float* actseq = out;               // (B,E)
    float* act    = out + BSZ*EMB;     // (B,S,E)

    convert9_kernel<<<dim3(1024, 9), 256, 0, stream>>>(
        amino, aminobf, BS*INITD,
        embW,  embWbf,  EMB*INITD,
        nbW,   nbWbf,   EMB*INITD,
        attW,  attWbf,  3*EMB*EMB,
        gwih,  gwihbf,  3*G3*EMB,
        gwhh,  gwhhbf,  3*G3*EMB,
        satW,  satWbf,  EMB*EMB,
        sgwih, sgwihbf, G3*EMB,
        sgwhh, sgwhhbf, G3*EMB);

    featnbase_kernel<<<256, 256, 0, stream>>>(
        aminobf, embWbf, embB, feat, featbf, nbWbf, nbB, nbase, nbasebf);

    dot2_kernel<<<128, 256, 0, stream>>>(feat, nbase, alignW, cdot, ndot);

    for (int d = 0; d < 3; ++d) {
        const ushort* nbrbf   = (d == 0) ? nbasebf : actbf;
        const float*  hprev   = (d == 0) ? feat    : h;
        const ushort* hprevbf = (d == 0) ? featbf  : hbf;
        if (d < 2) {
            fusedE_kernel<0><<<BS/16, 512, 0, stream>>>(
                cdot, ndot, idx, nbrbf, alignB + d,
                attWbf + (size_t)d*EMB*EMB, attB + d*EMB,
                gwihbf + (size_t)d*G3*EMB, gbih + d*G3,
                gwhhbf + (size_t)d*G3*EMB, gbhh + d*G3,
                hprev, hprevbf, alignW + (d+1)*2*EMB,
                h, hbf, act, actbf, cdot, ndot);
        } else {
            fusedE_kernel<1><<<BS/16, 512, 0, stream>>>(
                cdot, ndot, idx, nbrbf, alignB + d,
                attWbf + (size_t)d*EMB*EMB, attB + d*EMB,
                gwihbf + (size_t)d*G3*EMB, gbih + d*G3,
                gwhhbf + (size_t)d*G3*EMB, gbhh + d*G3,
                hprev, hprevbf, saW,
                h, hbf, act, actbf, cdot, ndot);   // ndot <- ad
        }
    }

    seqpre_kernel<<<136, 256, 0, stream>>>(
        actbf, satWbf, satB, tf, act, mask, saW, seqfeat, cmol);
    seqpv2_kernel<<<dim3(16, BSZ), 256, 0, stream>>>(ndot, mask, saB, cmol, tf, partial);
    seqstep_kernel<1><<<32, 512, 0, stream>>>(
        partial, seqfeat, sgwihbf, sgbih, sgwhhbf, sgbhh, sgi, sf2, actseq);
    seqstep_kernel<0><<<32, 512, 0, stream>>>(
        partial, sf2, sgwihbf, sgbih, sgwhhbf, sgbhh, sgi, seqfeat, actseq);
}

// Round 11
// 186.561 us; speedup vs baseline: 5.1289x; 1.2787x over previous
//
#include <hip/hip_runtime.h>
#include <math.h>

// ProGAT: B=8,S=512,NB=23,INIT=512,E=256,R=3,T=2
// R11: 13 dispatches. Round = gatherattend (gather+attend MFMA) + gigh
// (big-tile 128x64 GEMMs for gi/gh - R10's fusedE ran these as M=16 tiles
// at 3x the cost) + grudot (GRU + next-round dot2). Tail = R5 seqstep.

#define BSZ   8
#define SEQ   512
#define NBR   23
#define EMB   256
#define INITD 512
#define BS    (BSZ*SEQ)     // 4096
#define G3    (3*EMB)       // 768
#define NEGV  -9e8f

typedef __attribute__((ext_vector_type(8))) short short8;
typedef __attribute__((ext_vector_type(4))) float f32x4;

__device__ __forceinline__ float lrelu(float x){ return x > 0.f ? x : 0.01f*x; }
__device__ __forceinline__ float elu1 (float x){ return x > 0.f ? x : (expf(x)-1.f); }
__device__ __forceinline__ float sigm (float x){ return 1.f/(1.f+expf(-x)); }
__device__ __forceinline__ float bf2f(ushort u){
    union { unsigned int i; float f; } v; v.i = ((unsigned int)u) << 16; return v.f;
}
__device__ __forceinline__ ushort f2bf(float f){
    union { float f; unsigned int i; } v; v.f = f;
    unsigned int u = v.i;
    return (ushort)((u + 0x7FFFu + ((u >> 16) & 1u)) >> 16);   // RNE
}
__device__ __forceinline__ unsigned pk2(float a, float b){
    return (unsigned)f2bf(a) | ((unsigned)f2bf(b) << 16);
}
__device__ __forceinline__ void unpack8(uint4 v, float* o) {
    o[0]=bf2f((ushort)(v.x&0xffff)); o[1]=bf2f((ushort)(v.x>>16));
    o[2]=bf2f((ushort)(v.y&0xffff)); o[3]=bf2f((ushort)(v.y>>16));
    o[4]=bf2f((ushort)(v.z&0xffff)); o[5]=bf2f((ushort)(v.z>>16));
    o[6]=bf2f((ushort)(v.w&0xffff)); o[7]=bf2f((ushort)(v.w>>16));
}

__device__ __forceinline__ void gload_lds16(const void* g, void* l) {
    __builtin_amdgcn_global_load_lds(
        (const __attribute__((address_space(1))) unsigned int*)g,
        (__attribute__((address_space(3))) unsigned int*)l,
        16, 0, 0);
}

// ---- fp32 -> bf16 converter, 9 segments in one dispatch (blockIdx.y = seg)
__global__ __launch_bounds__(256) void convert9_kernel(
    const float* s0, ushort* d0, int n0,
    const float* s1, ushort* d1, int n1,
    const float* s2, ushort* d2, int n2,
    const float* s3, ushort* d3, int n3,
    const float* s4, ushort* d4, int n4,
    const float* s5, ushort* d5, int n5,
    const float* s6, ushort* d6, int n6,
    const float* s7, ushort* d7, int n7,
    const float* s8, ushort* d8, int n8)
{
    const float* srcs[9] = {s0,s1,s2,s3,s4,s5,s6,s7,s8};
    ushort* dsts[9] = {d0,d1,d2,d3,d4,d5,d6,d7,d8};
    int ns[9] = {n0,n1,n2,n3,n4,n5,n6,n7,n8};
    int seg = blockIdx.y;
    const float* s = srcs[seg]; ushort* d = dsts[seg]; int n = ns[seg];
    size_t i = ((size_t)blockIdx.x * 256 + threadIdx.x) * 8;
    size_t stride = (size_t)gridDim.x * 256 * 8;
    for (; i < (size_t)n; i += stride) {
        float4 a = *reinterpret_cast<const float4*>(s + i);
        float4 b = *reinterpret_cast<const float4*>(s + i + 4);
        uint4 o;
        o.x = pk2(a.x, a.y); o.y = pk2(a.z, a.w);
        o.z = pk2(b.x, b.y); o.w = pk2(b.z, b.w);
        *reinterpret_cast<uint4*>(d + i) = o;
    }
}

// ---- 128x64 MFMA GEMM; global_load_lds staging, dbuf
struct GemmLds64 { ushort A[2][128][64]; ushort B[2][64][64]; };

template<int ACT>
__device__ __forceinline__ void gemm64_dev(
    const ushort* __restrict__ A, const ushort* __restrict__ W,
    const float* __restrict__ bias,
    float* __restrict__ C, ushort* __restrict__ Cbf,
    int N, int K, int bx, int by, GemmLds64& L)
{
    const int tid = threadIdx.x;
    const int m0 = bx * 128, n0 = by * 64;
    const int wv = tid >> 6, lane = tid & 63;
    const int fr = lane & 15, grp = lane >> 4;
    const int kc = K >> 3;
    const int mh = wv & 1, nh = wv >> 1;
    const int lrow = lane >> 3;
    const int csrc = (lane & 7) ^ lrow;

    f32x4 acc[4][2];
    #pragma unroll
    for (int i = 0; i < 4; ++i)
        #pragma unroll
        for (int n = 0; n < 2; ++n) acc[i][n] = (f32x4){0.f,0.f,0.f,0.f};

    auto stage = [&](int c, int k0) {
        const int kch = (k0 >> 3) + csrc;
        #pragma unroll
        for (int i = 0; i < 4; ++i) {
            const int s = (wv << 2) + i;
            gload_lds16(A + ((size_t)(m0 + (s << 3) + lrow) * kc + kch) * 8,
                        &L.A[c][s << 3][0]);
        }
        #pragma unroll
        for (int i = 0; i < 2; ++i) {
            const int s = (wv << 1) + i;
            gload_lds16(W + ((size_t)(n0 + (s << 3) + lrow) * kc + kch) * 8,
                        &L.B[c][s << 3][0]);
        }
    };
    auto compute = [&](int c) {
        #pragma unroll
        for (int ks = 0; ks < 2; ++ks) {
            short8 af[4];
            #pragma unroll
            for (int i = 0; i < 4; ++i) {
                const int ar = (mh << 6) + (i << 4) + fr;
                af[i] = *reinterpret_cast<const short8*>(
                    &L.A[c][ar][(((ks << 2) + grp) ^ (ar & 7)) << 3]);
            }
            #pragma unroll
            for (int n = 0; n < 2; ++n) {
                const int br = (nh << 5) + (n << 4) + fr;
                short8 bv = *reinterpret_cast<const short8*>(
                    &L.B[c][br][(((ks << 2) + grp) ^ (br & 7)) << 3]);
                #pragma unroll
                for (int i = 0; i < 4; ++i)
                    acc[i][n] = __builtin_amdgcn_mfma_f32_16x16x32_bf16(
                        af[i], bv, acc[i][n], 0, 0, 0);
            }
        }
    };

    const int KT = K >> 6;
    stage(0, 0);
    __syncthreads();
    int cur = 0;
    for (int kt = 1; kt < KT; ++kt) {
        stage(cur ^ 1, kt << 6);
        compute(cur);
        __syncthreads();
        cur ^= 1;
    }
    compute(cur);

    #pragma unroll
    for (int i = 0; i < 4; ++i) {
        const int mrow = m0 + (mh << 6) + (i << 4) + (grp << 2);
        #pragma unroll
        for (int n = 0; n < 2; ++n) {
            const int col = n0 + (nh << 5) + (n << 4) + fr;
            const float bv = bias[col];
            #pragma unroll
            for (int j = 0; j < 4; ++j) {
                float t = acc[i][n][j] + bv;
                if (ACT == 1) t = lrelu(t);
                size_t off = (size_t)(mrow + j) * N + col;
                if (C)   C[off] = t;
                if (Cbf) Cbf[off] = f2bf(t);
            }
        }
    }
}

// ---- fat: feat GEMM (0..127) + nbase GEMM (128..255), K=512
__global__ __launch_bounds__(256) void featnbase_kernel(
    const ushort* __restrict__ aminobf,
    const ushort* __restrict__ embWbf, const float* __restrict__ embB,
    float* __restrict__ feat, ushort* __restrict__ featbf,
    const ushort* __restrict__ nbWbf, const float* __restrict__ nbB,
    float* __restrict__ nbase, ushort* __restrict__ nbasebf)
{
    __shared__ GemmLds64 L;
    int blk = blockIdx.x;
    if (blk < 128)
        gemm64_dev<1>(aminobf, embWbf, embB, feat, featbf, EMB, INITD, blk & 31, blk >> 5, L);
    else {
        blk -= 128;
        gemm64_dev<1>(aminobf, nbWbf, nbB, nbase, nbasebf, EMB, INITD, blk & 31, blk >> 5, L);
    }
}

// ---- dot2 for round 0: 128 blocks x 32 rows
__global__ __launch_bounds__(256) void dot2_kernel(
    const float* __restrict__ center, const float* __restrict__ nbrbase,
    const float* __restrict__ alignWd,
    float* __restrict__ cdot, float* __restrict__ ndot)
{
    const int lane = threadIdx.x & 63;
    const int wv   = threadIdx.x >> 6;
    const int e    = lane << 2;
    const int rb   = blockIdx.x * 32 + wv * 8;
    float4 w0 = *reinterpret_cast<const float4*>(&alignWd[e]);
    float4 w1 = *reinterpret_cast<const float4*>(&alignWd[EMB + e]);
    #pragma unroll
    for (int i = 0; i < 8; ++i) {
        const int r = rb + i;
        float4 xc = *reinterpret_cast<const float4*>(&center[(size_t)r*EMB + e]);
        float4 xn = *reinterpret_cast<const float4*>(&nbrbase[(size_t)r*EMB + e]);
        float ac = xc.x*w0.x + xc.y*w0.y + xc.z*w0.z + xc.w*w0.w;
        float an = xn.x*w1.x + xn.y*w1.y + xn.z*w1.z + xn.w*w1.w;
        #pragma unroll
        for (int off = 32; off; off >>= 1) {
            ac += __shfl_xor(ac, off, 64);
            an += __shfl_xor(an, off, 64);
        }
        if (lane == 0) { cdot[r] = ac; ndot[r] = an; }
    }
}

// ---- D1: gather (softmax over 23 nbrs) + attend MFMA -> ctxbf (coalesced)
struct GALds { ushort ctxpre[16][256]; ushort ctx[16][256]; float wsum_s[16]; };

__global__ __launch_bounds__(512) void gatherattend_kernel(
    const float* __restrict__ cdot, const float* __restrict__ ndot,
    const int* __restrict__ idx, const ushort* __restrict__ nbr,
    const float* __restrict__ alignBd,
    const ushort* __restrict__ attWd, const float* __restrict__ attBd,
    ushort* __restrict__ ctxbf)
{
    __shared__ GALds L;
    const int tid = threadIdx.x;
    const int r0 = blockIdx.x * 16;

    {   // gather: 16 row-groups x 32 lanes; 23 loads fully unrolled
        const int row16 = tid >> 5, sub = tid & 31;
        const int r = r0 + row16, b = r >> 9;
        float sc = -3e38f, vm = 0.f; int rn = 0;
        if (sub < NBR) {
            int j = idx[(size_t)r*NBR + sub];
            int valid = (j >= 0);
            int jj = valid ? j : j + SEQ;   // JAX wrap: f[-1] = last row
            rn = b*SEQ + jj;
            vm = (float)valid;
            sc = lrelu(cdot[r] + ndot[rn] + alignBd[0]) + (valid ? 0.f : NEGV);
        }
        float m = sc;
        #pragma unroll
        for (int off = 16; off; off >>= 1) m = fmaxf(m, __shfl_xor(m, off, 32));
        float ev = (sub < NBR) ? expf(sc - m) : 0.f;
        float s = ev;
        #pragma unroll
        for (int off = 16; off; off >>= 1) s += __shfl_xor(s, off, 32);
        float wgt = ev * vm / s;
        float ws = wgt;
        #pragma unroll
        for (int off = 16; off; off >>= 1) ws += __shfl_xor(ws, off, 32);
        float a8[8] = {};
        const int e0 = sub << 3;
        #pragma unroll
        for (int n = 0; n < NBR; ++n) {
            float wn = __shfl(wgt, n, 32);
            int   rr = __shfl(rn, n, 32);
            uint4 v = *reinterpret_cast<const uint4*>(&nbr[(size_t)rr*EMB + e0]);
            float x[8]; unpack8(v, x);
            #pragma unroll
            for (int i = 0; i < 8; ++i) a8[i] += wn * x[i];
        }
        uint4 o;
        o.x = pk2(a8[0],a8[1]); o.y = pk2(a8[2],a8[3]);
        o.z = pk2(a8[4],a8[5]); o.w = pk2(a8[6],a8[7]);
        *reinterpret_cast<uint4*>(&L.ctxpre[row16][(sub ^ (row16&7)) << 3]) = o;
        if (sub == 0) L.wsum_s[row16] = ws;
    }
    __syncthreads();

    const int wv = tid >> 6, lane = tid & 63;
    const int fr = lane & 15, grp = lane >> 4;
    {   // attend: wave owns cols wv*32 + f*16 + fr, f in 0..1
        f32x4 acc[2] = {(f32x4){0,0,0,0},(f32x4){0,0,0,0}};
        #pragma unroll
        for (int kt = 0; kt < 8; ++kt) {
            short8 af = *reinterpret_cast<const short8*>(
                &L.ctxpre[fr][((((kt<<2)+grp) ^ (fr&7)) << 3)]);
            #pragma unroll
            for (int f = 0; f < 2; ++f) {
                const int col = (wv<<5) + (f<<4) + fr;
                short8 bv = *reinterpret_cast<const short8*>(
                    &attWd[(size_t)col*EMB + (kt<<5) + (grp<<3)]);
                acc[f] = __builtin_amdgcn_mfma_f32_16x16x32_bf16(af, bv, acc[f], 0, 0, 0);
            }
        }
        #pragma unroll
        for (int f = 0; f < 2; ++f) {
            const int col = (wv<<5) + (f<<4) + fr;
            const float bb = attBd[col];
            #pragma unroll
            for (int j = 0; j < 4; ++j) {
                const int row = (grp<<2) + j;
                L.ctx[row][col] = f2bf(elu1(acc[f][j] + L.wsum_s[row]*bb));
            }
        }
    }
    __syncthreads();
    {   // coalesced copy out: 512 thr x 16B = 16 rows x 512B
        const int row = tid >> 5, c = tid & 31;
        uint4 v = *reinterpret_cast<const uint4*>(&L.ctx[row][c << 3]);
        *reinterpret_cast<uint4*>(&ctxbf[(size_t)(r0+row)*EMB + (c << 3)]) = v;
    }
}

// ---- D2: fat gi (0..383) + gh (384..767) big-tile GEMMs, K=256, N=768
__global__ __launch_bounds__(256) void gigh_kernel(
    const ushort* __restrict__ ctxbf, const ushort* __restrict__ gwihd,
    const float* __restrict__ gbihd, ushort* __restrict__ gibf,
    const ushort* __restrict__ hprevbf, const ushort* __restrict__ gwhhd,
    const float* __restrict__ gbhhd, ushort* __restrict__ ghbf)
{
    __shared__ GemmLds64 L;
    int blk = blockIdx.x;
    if (blk < 384)
        gemm64_dev<0>(ctxbf, gwihd, gbihd, nullptr, gibf, G3, EMB, blk & 31, blk >> 5, L);
    else {
        blk -= 384;
        gemm64_dev<0>(hprevbf, gwhhd, gbhhd, nullptr, ghbf, G3, EMB, blk & 31, blk >> 5, L);
    }
}

// ---- D3: GRU + next-round dot2 (or seq ad if LAST). 256 blk x 512 thr.
template<int LAST>
__global__ __launch_bounds__(512) void grudot_kernel(
    const ushort* __restrict__ gibf, const ushort* __restrict__ ghbf,
    const float* __restrict__ hprev, const float* __restrict__ nextW,
    float* __restrict__ hout, ushort* __restrict__ hbf,
    float* __restrict__ actout, ushort* __restrict__ actbf,
    float* __restrict__ cdotO, float* __restrict__ ndotO)
{
    const int tid = threadIdx.x;
    const int row = tid >> 5, sub = tid & 31;
    const int e0 = sub << 3;
    const size_t r = (size_t)blockIdx.x * 16 + row;
    const size_t gb = r*G3;
    uint4 giA = *reinterpret_cast<const uint4*>(&gibf[gb + e0]);
    uint4 giB = *reinterpret_cast<const uint4*>(&gibf[gb + 256 + e0]);
    uint4 giC = *reinterpret_cast<const uint4*>(&gibf[gb + 512 + e0]);
    uint4 ghA = *reinterpret_cast<const uint4*>(&ghbf[gb + e0]);
    uint4 ghB = *reinterpret_cast<const uint4*>(&ghbf[gb + 256 + e0]);
    uint4 ghC = *reinterpret_cast<const uint4*>(&ghbf[gb + 512 + e0]);
    float4 hp0 = *reinterpret_cast<const float4*>(&hprev[r*EMB + e0]);
    float4 hp1 = *reinterpret_cast<const float4*>(&hprev[r*EMB + e0 + 4]);
    float ir_[8], iz_[8], in_[8], hr_[8], hz_[8], hn_[8];
    unpack8(giA, ir_); unpack8(giB, iz_); unpack8(giC, in_);
    unpack8(ghA, hr_); unpack8(ghB, hz_); unpack8(ghC, hn_);
    const float hp_[8] = {hp0.x,hp0.y,hp0.z,hp0.w,hp1.x,hp1.y,hp1.z,hp1.w};
    float hv8[8], av8[8];
    #pragma unroll
    for (int i = 0; i < 8; ++i) {
        float rg = sigm(ir_[i] + hr_[i]);
        float z  = sigm(iz_[i] + hz_[i]);
        float n  = tanhf(in_[i] + rg*hn_[i]);
        hv8[i] = (1.f - z)*n + z*hp_[i];
        av8[i] = fmaxf(hv8[i], 0.f);
    }
    *reinterpret_cast<float4*>(&hout[r*EMB + e0])       = make_float4(hv8[0],hv8[1],hv8[2],hv8[3]);
    *reinterpret_cast<float4*>(&hout[r*EMB + e0 + 4])   = make_float4(hv8[4],hv8[5],hv8[6],hv8[7]);
    *reinterpret_cast<float4*>(&actout[r*EMB + e0])     = make_float4(av8[0],av8[1],av8[2],av8[3]);
    *reinterpret_cast<float4*>(&actout[r*EMB + e0 + 4]) = make_float4(av8[4],av8[5],av8[6],av8[7]);
    uint4 hb, ab;
    hb.x = pk2(hv8[0],hv8[1]); hb.y = pk2(hv8[2],hv8[3]);
    hb.z = pk2(hv8[4],hv8[5]); hb.w = pk2(hv8[6],hv8[7]);
    ab.x = pk2(av8[0],av8[1]); ab.y = pk2(av8[2],av8[3]);
    ab.z = pk2(av8[4],av8[5]); ab.w = pk2(av8[6],av8[7]);
    *reinterpret_cast<uint4*>(&hbf[r*EMB + e0])   = hb;
    *reinterpret_cast<uint4*>(&actbf[r*EMB + e0]) = ab;
    float pc = 0.f, pn = 0.f;
    float4 w1a = *reinterpret_cast<const float4*>(&nextW[EMB + e0]);
    float4 w1b = *reinterpret_cast<const float4*>(&nextW[EMB + e0 + 4]);
    pn = av8[0]*w1a.x + av8[1]*w1a.y + av8[2]*w1a.z + av8[3]*w1a.w
       + av8[4]*w1b.x + av8[5]*w1b.y + av8[6]*w1b.z + av8[7]*w1b.w;
    if (!LAST) {
        float4 w0a = *reinterpret_cast<const float4*>(&nextW[e0]);
        float4 w0b = *reinterpret_cast<const float4*>(&nextW[e0 + 4]);
        pc = av8[0]*w0a.x + av8[1]*w0a.y + av8[2]*w0a.z + av8[3]*w0a.w
           + av8[4]*w0b.x + av8[5]*w0b.y + av8[6]*w0b.z + av8[7]*w0b.w;
    }
    #pragma unroll
    for (int off = 16; off; off >>= 1) {
        pn += __shfl_xor(pn, off, 32);
        if (!LAST) pc += __shfl_xor(pc, off, 32);
    }
    if (sub == 0) {
        if (!LAST) cdotO[r] = pc;
        ndotO[r] = pn;
    }
}

// ---- fat: tf GEMM (0..127, BN=64) + seqsum (128..135)
__global__ __launch_bounds__(256) void seqpre_kernel(
    const ushort* __restrict__ actbf, const ushort* __restrict__ satWbf,
    const float* __restrict__ satB, float* __restrict__ tf,
    const float* __restrict__ act, const float* __restrict__ mask,
    const float* __restrict__ saW,
    float* __restrict__ seqfeat, float* __restrict__ cmol)
{
    __shared__ GemmLds64 L;
    int blk = blockIdx.x;
    if (blk < 128) {
        gemm64_dev<0>(actbf, satWbf, satB, tf, nullptr, EMB, EMB, blk & 31, blk >> 5, L);
    } else {
        const int b = blk - 128;
        const int e = threadIdx.x;
        float acc = 0.f;
        for (int s = 0; s < SEQ; ++s)
            acc += act[((size_t)b*SEQ + s)*EMB + e] * mask[b*SEQ + s];
        seqfeat[b*EMB + e] = acc;
        float* red = reinterpret_cast<float*>(&L);
        red[e] = fmaxf(acc, 0.f) * saW[e];
        __syncthreads();
        for (int off = 128; off; off >>= 1) {
            if (e < off) red[e] += red[e + off];
            __syncthreads();
        }
        if (e == 0) cmol[b] = red[0];
    }
}

// softmax (redundant per block) + PV strip: block (st,b) -> partial[b,st,:]
__global__ __launch_bounds__(256) void seqpv2_kernel(
    const float* __restrict__ ad, const float* __restrict__ mask,
    const float* __restrict__ saB, const float* __restrict__ cmol,
    const float* __restrict__ tf, float* __restrict__ partial)
{
    const int st = blockIdx.x, b = blockIdx.y;
    const int tid = threadIdx.x;
    __shared__ float w_s[SEQ];
    __shared__ float red[256];
    float mk0 = mask[b*SEQ + tid], mk1 = mask[b*SEQ + 256 + tid];
    float cb = cmol[b], bb = saB[0];
    float s0 = lrelu(cb + ad[b*SEQ + tid] + bb)       + (mk0 == 0.f ? NEGV : 0.f);
    float s1 = lrelu(cb + ad[b*SEQ + 256 + tid] + bb) + (mk1 == 0.f ? NEGV : 0.f);
    red[tid] = fmaxf(s0, s1); __syncthreads();
    for (int off = 128; off; off >>= 1) {
        if (tid < off) red[tid] = fmaxf(red[tid], red[tid + off]);
        __syncthreads();
    }
    float m = red[0]; __syncthreads();
    float e0 = expf(s0 - m), e1 = expf(s1 - m);
    red[tid] = e0 + e1; __syncthreads();
    for (int off = 128; off; off >>= 1) {
        if (tid < off) red[tid] += red[tid + off];
        __syncthreads();
    }
    float inv = 1.f / red[0];
    w_s[tid]       = e0 * inv * mk0;
    w_s[tid + 256] = e1 * inv * mk1;
    __syncthreads();
    float acc = 0.f;
    const int s0i = st * 32;
    #pragma unroll 4
    for (int s = s0i; s < s0i + 32; ++s)
        acc += w_s[s] * tf[((size_t)b*SEQ + s)*EMB + tid];
    partial[((size_t)b*16 + st)*EMB + tid] = acc;
}

// Fused tail GRU step (R5-proven). Grid 32: (b, quarter q). 512 thr, 8 waves.
template<int T0>
__global__ __launch_bounds__(512) void seqstep_kernel(
    const float* __restrict__ partial, const float* __restrict__ sfin,
    const ushort* __restrict__ sgwihbf, const float* __restrict__ sgbih,
    const ushort* __restrict__ sgwhhbf, const float* __restrict__ sgbhh,
    float* __restrict__ sgi, float* __restrict__ sfout,
    float* __restrict__ actseq)
{
    const int b = blockIdx.x >> 2, q = blockIdx.x & 3;
    const int tid = threadIdx.x, lane = tid & 63, wv = tid >> 6;
    __shared__ float xs[EMB];
    __shared__ float hs[EMB];
    __shared__ float gis[192], ghs[192];
    if (tid < EMB) {
        hs[tid] = sfin[b*EMB + tid];
        if (T0) {
            float a = 0.f;
            #pragma unroll
            for (int st = 0; st < 16; ++st)
                a += partial[((size_t)b*16 + st)*EMB + tid];
            xs[tid] = elu1(a);
        }
    }
    if (!T0) {
        for (int l = tid; l < 192; l += 512) {
            int g = (l >> 6)*EMB + (q << 6) + (l & 63);
            gis[l] = sgi[b*G3 + g];
        }
    }
    __syncthreads();
    const int nrows = T0 ? 384 : 192;
    const int rpw = nrows >> 3;
    for (int i = 0; i < rpw; ++i) {
        const int l = wv * rpw + i;
        const int iswih = T0 && (l < 192);
        const int ll = (T0 && l >= 192) ? l - 192 : l;
        const int g = (ll >> 6)*EMB + (q << 6) + (ll & 63);
        const ushort* Wm = iswih ? sgwihbf : sgwhhbf;
        ushort4 w4 = *reinterpret_cast<const ushort4*>(&Wm[(size_t)g*EMB + (lane << 2)]);
        float4 x4 = *reinterpret_cast<const float4*>(iswih ? &xs[lane << 2] : &hs[lane << 2]);
        float d = bf2f(w4.x)*x4.x + bf2f(w4.y)*x4.y + bf2f(w4.z)*x4.z + bf2f(w4.w)*x4.w;
        #pragma unroll
        for (int off = 32; off; off >>= 1) d += __shfl_xor(d, off, 64);
        if (lane == 0) {
            if (iswih) {
                d += sgbih[g];
                gis[ll] = d;
                sgi[b*G3 + g] = d;
            } else {
                ghs[ll] = d + sgbhh[g];
            }
        }
    }
    __syncthreads();
    if (tid < 64) {
        const int e = (q << 6) + tid;
        float rg = sigm(gis[tid]       + ghs[tid]);
        float z  = sigm(gis[64 + tid]  + ghs[64 + tid]);
        float n  = tanhf(gis[128 + tid] + rg*ghs[128 + tid]);
        float hv = (1.f - z)*n + z*hs[e];
        sfout[b*EMB + e]  = hv;
        actseq[b*EMB + e] = fmaxf(hv, 0.f);
    }
}

extern "C" void kernel_launch(void* const* d_in, const int* in_sizes, int n_in,
                              void* d_out, int out_size, void* d_ws, size_t ws_size,
                              hipStream_t stream) {
    (void)in_sizes; (void)n_in; (void)out_size; (void)ws_size;
    const float* amino  = (const float*)d_in[0];
    const float* mask   = (const float*)d_in[1];
    const float* embW   = (const float*)d_in[2];
    const float* embB   = (const float*)d_in[3];
    const float* nbW    = (const float*)d_in[4];
    const float* nbB    = (const float*)d_in[5];
    const float* alignW = (const float*)d_in[6];
    const float* alignB = (const float*)d_in[7];
    const float* attW   = (const float*)d_in[8];
    const float* attB   = (const float*)d_in[9];
    const float* gwih   = (const float*)d_in[10];
    const float* gwhh   = (const float*)d_in[11];
    const float* gbih   = (const float*)d_in[12];
    const float* gbhh   = (const float*)d_in[13];
    const float* saW    = (const float*)d_in[14];
    const float* saB    = (const float*)d_in[15];
    const float* satW   = (const float*)d_in[16];
    const float* satB   = (const float*)d_in[17];
    const float* sgwih  = (const float*)d_in[18];
    const float* sgbih  = (const float*)d_in[19];
    const float* sgwhh  = (const float*)d_in[20];
    const float* sgbhh  = (const float*)d_in[21];
    const int*   idx    = (const int*)d_in[22];

    char* cur = (char*)d_ws;
    auto alloc = [&](size_t bytes) -> char* {
        char* p = cur; cur += (bytes + 255) & ~(size_t)255; return p;
    };
    float* feat    = (float*)alloc((size_t)BS*EMB*4);
    float* nbase   = (float*)alloc((size_t)BS*EMB*4);
    float* h       = (float*)alloc((size_t)BS*EMB*4);
    float* tf      = (float*)alloc((size_t)BS*EMB*4);
    float* cdot    = (float*)alloc(BS*4);
    float* ndot    = (float*)alloc(BS*4);   // doubles as ad after round 2
    float* seqfeat = (float*)alloc(BSZ*EMB*4);
    float* sf2     = (float*)alloc(BSZ*EMB*4);
    float* cmol    = (float*)alloc(64*4);
    float* sgi     = (float*)alloc(BSZ*G3*4);
    float* partial = (float*)alloc((size_t)BSZ*16*EMB*4);
    ushort* aminobf  = (ushort*)alloc((size_t)BS*INITD*2);
    ushort* featbf   = (ushort*)alloc((size_t)BS*EMB*2);
    ushort* nbasebf  = (ushort*)alloc((size_t)BS*EMB*2);
    ushort* actbf    = (ushort*)alloc((size_t)BS*EMB*2);
    ushort* hbf      = (ushort*)alloc((size_t)BS*EMB*2);
    ushort* ctxbf    = (ushort*)alloc((size_t)BS*EMB*2);
    ushort* gibf     = (ushort*)alloc((size_t)BS*G3*2);
    ushort* ghbf     = (ushort*)alloc((size_t)BS*G3*2);
    ushort* embWbf   = (ushort*)alloc((size_t)EMB*INITD*2);
    ushort* nbWbf    = (ushort*)alloc((size_t)EMB*INITD*2);
    ushort* attWbf   = (ushort*)alloc((size_t)3*EMB*EMB*2);
    ushort* gwihbf   = (ushort*)alloc((size_t)3*G3*EMB*2);
    ushort* gwhhbf   = (ushort*)alloc((size_t)3*G3*EMB*2);
    ushort* satWbf   = (ushort*)alloc((size_t)EMB*EMB*2);
    ushort* sgwihbf  = (ushort*)alloc((size_t)G3*EMB*2);
    ushort* sgwhhbf  = (ushort*)alloc((size_t)G3*EMB*2);

    float* out    = (float*)d_out;
    float* actseq = out;               // (B,E)
    float* act    = out + BSZ*EMB;     // (B,S,E)

    convert9_kernel<<<dim3(1024, 9), 256, 0, stream>>>(
        amino, aminobf, BS*INITD,
        embW,  embWbf,  EMB*INITD,
        nbW,   nbWbf,   EMB*INITD,
        attW,  attWbf,  3*EMB*EMB,
        gwih,  gwihbf,  3*G3*EMB,
        gwhh,  gwhhbf,  3*G3*EMB,
        satW,  satWbf,  EMB*EMB,
        sgwih, sgwihbf, G3*EMB,
        sgwhh, sgwhhbf, G3*EMB);

    featnbase_kernel<<<256, 256, 0, stream>>>(
        aminobf, embWbf, embB, feat, featbf, nbWbf, nbB, nbase, nbasebf);

    dot2_kernel<<<128, 256, 0, stream>>>(feat, nbase, alignW, cdot, ndot);

    for (int d = 0; d < 3; ++d) {
        const ushort* nbrbf   = (d == 0) ? nbasebf : actbf;
        const float*  hprev   = (d == 0) ? feat    : h;
        const ushort* hprevbf = (d == 0) ? featbf  : hbf;
        gatherattend_kernel<<<BS/16, 512, 0, stream>>>(
            cdot, ndot, idx, nbrbf, alignB + d,
            attWbf + (size_t)d*EMB*EMB, attB + d*EMB, ctxbf);
        gigh_kernel<<<768, 256, 0, stream>>>(
            ctxbf, gwihbf + (size_t)d*G3*EMB, gbih + d*G3, gibf,
            hprevbf, gwhhbf + (size_t)d*G3*EMB, gbhh + d*G3, ghbf);
        if (d < 2) {
            grudot_kernel<0><<<BS/16, 512, 0, stream>>>(
                gibf, ghbf, hprev, alignW + (d+1)*2*EMB,
                h, hbf, act, actbf, cdot, ndot);
        } else {
            grudot_kernel<1><<<BS/16, 512, 0, stream>>>(
                gibf, ghbf, hprev, saW,
                h, hbf, act, actbf, cdot, ndot);   // ndot <- ad
        }
    }

    seqpre_kernel<<<136, 256, 0, stream>>>(
        actbf, satWbf, satB, tf, act, mask, saW, seqfeat, cmol);
    seqpv2_kernel<<<dim3(16, BSZ), 256, 0, stream>>>(ndot, mask, saB, cmol, tf, partial);
    seqstep_kernel<1><<<32, 512, 0, stream>>>(
        partial, seqfeat, sgwihbf, sgbih, sgwhhbf, sgbhh, sgi, sf2, actseq);
    seqstep_kernel<0><<<32, 512, 0, stream>>>(
        partial, sf2, sgwihbf, sgbih, sgwhhbf, sgbhh, sgi, seqfeat, actseq);
}

// Round 12
// 177.037 us; speedup vs baseline: 5.4048x; 1.0538x over previous
//
#include <hip/hip_runtime.h>
#include <math.h>

// ProGAT: B=8,S=512,NB=23,INIT=512,E=256,R=3,T=2
// R12: R11 structure with head/tail trimmed: balanced convert (+seqfeat zero),
// bf16-only h/act state in rounds (f32 act only in LAST), seqfeat via
// atomics in grudot-LAST, seqpv folded into seqstepT0. 15 dispatches.

#define BSZ   8
#define SEQ   512
#define NBR   23
#define EMB   256
#define INITD 512
#define BS    (BSZ*SEQ)     // 4096
#define G3    (3*EMB)       // 768
#define NEGV  -9e8f

typedef __attribute__((ext_vector_type(8))) short short8;
typedef __attribute__((ext_vector_type(4))) float f32x4;

__device__ __forceinline__ float lrelu(float x){ return x > 0.f ? x : 0.01f*x; }
__device__ __forceinline__ float elu1 (float x){ return x > 0.f ? x : (expf(x)-1.f); }
__device__ __forceinline__ float sigm (float x){ return 1.f/(1.f+expf(-x)); }
__device__ __forceinline__ float bf2f(ushort u){
    union { unsigned int i; float f; } v; v.i = ((unsigned int)u) << 16; return v.f;
}
__device__ __forceinline__ ushort f2bf(float f){
    union { float f; unsigned int i; } v; v.f = f;
    unsigned int u = v.i;
    return (ushort)((u + 0x7FFFu + ((u >> 16) & 1u)) >> 16);   // RNE
}
__device__ __forceinline__ unsigned pk2(float a, float b){
    return (unsigned)f2bf(a) | ((unsigned)f2bf(b) << 16);
}
__device__ __forceinline__ void unpack8(uint4 v, float* o) {
    o[0]=bf2f((ushort)(v.x&0xffff)); o[1]=bf2f((ushort)(v.x>>16));
    o[2]=bf2f((ushort)(v.y&0xffff)); o[3]=bf2f((ushort)(v.y>>16));
    o[4]=bf2f((ushort)(v.z&0xffff)); o[5]=bf2f((ushort)(v.z>>16));
    o[6]=bf2f((ushort)(v.w&0xffff)); o[7]=bf2f((ushort)(v.w>>16));
}

__device__ __forceinline__ void gload_lds16(const void* g, void* l) {
    __builtin_amdgcn_global_load_lds(
        (const __attribute__((address_space(1))) unsigned int*)g,
        (__attribute__((address_space(3))) unsigned int*)l,
        16, 0, 0);
}

// ---- balanced flat converter: 9 bf16 segments + seqfeat zero-fill.
// Unit = 8 elems. Compile-time cumulative bounds.
__global__ __launch_bounds__(256) void convert_flat(
    const float* __restrict__ amino, ushort* __restrict__ aminobf,
    const float* __restrict__ embW,  ushort* __restrict__ embWbf,
    const float* __restrict__ nbW,   ushort* __restrict__ nbWbf,
    const float* __restrict__ attW,  ushort* __restrict__ attWbf,
    const float* __restrict__ gwih,  ushort* __restrict__ gwihbf,
    const float* __restrict__ gwhh,  ushort* __restrict__ gwhhbf,
    const float* __restrict__ satW,  ushort* __restrict__ satWbf,
    const float* __restrict__ sgwih, ushort* __restrict__ sgwihbf,
    const float* __restrict__ sgwhh, ushort* __restrict__ sgwhhbf,
    float* __restrict__ seqfeatZ)
{
    const unsigned stride = gridDim.x * 256;
    for (unsigned u = blockIdx.x*256 + threadIdx.x; u < 524544u; u += stride) {
        const float* s; ushort* d; unsigned lu;
        if      (u < 262144u) { s=amino; d=aminobf; lu=u; }
        else if (u < 278528u) { s=embW;  d=embWbf;  lu=u-262144u; }
        else if (u < 294912u) { s=nbW;   d=nbWbf;   lu=u-278528u; }
        else if (u < 319488u) { s=attW;  d=attWbf;  lu=u-294912u; }
        else if (u < 393216u) { s=gwih;  d=gwihbf;  lu=u-319488u; }
        else if (u < 466944u) { s=gwhh;  d=gwhhbf;  lu=u-393216u; }
        else if (u < 475136u) { s=satW;  d=satWbf;  lu=u-466944u; }
        else if (u < 499712u) { s=sgwih; d=sgwihbf; lu=u-475136u; }
        else if (u < 524288u) { s=sgwhh; d=sgwhhbf; lu=u-499712u; }
        else {
            unsigned i = (u - 524288u) * 8;   // 256 units x 8 = 2048 floats
            *reinterpret_cast<float4*>(&seqfeatZ[i])     = make_float4(0,0,0,0);
            *reinterpret_cast<float4*>(&seqfeatZ[i + 4]) = make_float4(0,0,0,0);
            continue;
        }
        size_t i = (size_t)lu * 8;
        float4 a = *reinterpret_cast<const float4*>(s + i);
        float4 b = *reinterpret_cast<const float4*>(s + i + 4);
        uint4 o;
        o.x = pk2(a.x, a.y); o.y = pk2(a.z, a.w);
        o.z = pk2(b.x, b.y); o.w = pk2(b.z, b.w);
        *reinterpret_cast<uint4*>(d + i) = o;
    }
}

// ---- 128x64 MFMA GEMM; global_load_lds staging, dbuf
struct GemmLds64 { ushort A[2][128][64]; ushort B[2][64][64]; };

template<int ACT>
__device__ __forceinline__ void gemm64_dev(
    const ushort* __restrict__ A, const ushort* __restrict__ W,
    const float* __restrict__ bias,
    float* __restrict__ C, ushort* __restrict__ Cbf,
    int N, int K, int bx, int by, GemmLds64& L)
{
    const int tid = threadIdx.x;
    const int m0 = bx * 128, n0 = by * 64;
    const int wv = tid >> 6, lane = tid & 63;
    const int fr = lane & 15, grp = lane >> 4;
    const int kc = K >> 3;
    const int mh = wv & 1, nh = wv >> 1;
    const int lrow = lane >> 3;
    const int csrc = (lane & 7) ^ lrow;

    f32x4 acc[4][2];
    #pragma unroll
    for (int i = 0; i < 4; ++i)
        #pragma unroll
        for (int n = 0; n < 2; ++n) acc[i][n] = (f32x4){0.f,0.f,0.f,0.f};

    auto stage = [&](int c, int k0) {
        const int kch = (k0 >> 3) + csrc;
        #pragma unroll
        for (int i = 0; i < 4; ++i) {
            const int s = (wv << 2) + i;
            gload_lds16(A + ((size_t)(m0 + (s << 3) + lrow) * kc + kch) * 8,
                        &L.A[c][s << 3][0]);
        }
        #pragma unroll
        for (int i = 0; i < 2; ++i) {
            const int s = (wv << 1) + i;
            gload_lds16(W + ((size_t)(n0 + (s << 3) + lrow) * kc + kch) * 8,
                        &L.B[c][s << 3][0]);
        }
    };
    auto compute = [&](int c) {
        #pragma unroll
        for (int ks = 0; ks < 2; ++ks) {
            short8 af[4];
            #pragma unroll
            for (int i = 0; i < 4; ++i) {
                const int ar = (mh << 6) + (i << 4) + fr;
                af[i] = *reinterpret_cast<const short8*>(
                    &L.A[c][ar][(((ks << 2) + grp) ^ (ar & 7)) << 3]);
            }
            #pragma unroll
            for (int n = 0; n < 2; ++n) {
                const int br = (nh << 5) + (n << 4) + fr;
                short8 bv = *reinterpret_cast<const short8*>(
                    &L.B[c][br][(((ks << 2) + grp) ^ (br & 7)) << 3]);
                #pragma unroll
                for (int i = 0; i < 4; ++i)
                    acc[i][n] = __builtin_amdgcn_mfma_f32_16x16x32_bf16(
                        af[i], bv, acc[i][n], 0, 0, 0);
            }
        }
    };

    const int KT = K >> 6;
    stage(0, 0);
    __syncthreads();
    int cur = 0;
    for (int kt = 1; kt < KT; ++kt) {
        stage(cur ^ 1, kt << 6);
        compute(cur);
        __syncthreads();
        cur ^= 1;
    }
    compute(cur);

    #pragma unroll
    for (int i = 0; i < 4; ++i) {
        const int mrow = m0 + (mh << 6) + (i << 4) + (grp << 2);
        #pragma unroll
        for (int n = 0; n < 2; ++n) {
            const int col = n0 + (nh << 5) + (n << 4) + fr;
            const float bv = bias[col];
            #pragma unroll
            for (int j = 0; j < 4; ++j) {
                float t = acc[i][n][j] + bv;
                if (ACT == 1) t = lrelu(t);
                size_t off = (size_t)(mrow + j) * N + col;
                if (C)   C[off] = t;
                if (Cbf) Cbf[off] = f2bf(t);
            }
        }
    }
}

// ---- fat: feat GEMM (0..127) + nbase GEMM (128..255), K=512
__global__ __launch_bounds__(256) void featnbase_kernel(
    const ushort* __restrict__ aminobf,
    const ushort* __restrict__ embWbf, const float* __restrict__ embB,
    float* __restrict__ feat, ushort* __restrict__ featbf,
    const ushort* __restrict__ nbWbf, const float* __restrict__ nbB,
    float* __restrict__ nbase, ushort* __restrict__ nbasebf)
{
    __shared__ GemmLds64 L;
    int blk = blockIdx.x;
    if (blk < 128)
        gemm64_dev<1>(aminobf, embWbf, embB, feat, featbf, EMB, INITD, blk & 31, blk >> 5, L);
    else {
        blk -= 128;
        gemm64_dev<1>(aminobf, nbWbf, nbB, nbase, nbasebf, EMB, INITD, blk & 31, blk >> 5, L);
    }
}

// ---- dot2 for round 0: 128 blocks x 32 rows
__global__ __launch_bounds__(256) void dot2_kernel(
    const float* __restrict__ center, const float* __restrict__ nbrbase,
    const float* __restrict__ alignWd,
    float* __restrict__ cdot, float* __restrict__ ndot)
{
    const int lane = threadIdx.x & 63;
    const int wv   = threadIdx.x >> 6;
    const int e    = lane << 2;
    const int rb   = blockIdx.x * 32 + wv * 8;
    float4 w0 = *reinterpret_cast<const float4*>(&alignWd[e]);
    float4 w1 = *reinterpret_cast<const float4*>(&alignWd[EMB + e]);
    #pragma unroll
    for (int i = 0; i < 8; ++i) {
        const int r = rb + i;
        float4 xc = *reinterpret_cast<const float4*>(&center[(size_t)r*EMB + e]);
        float4 xn = *reinterpret_cast<const float4*>(&nbrbase[(size_t)r*EMB + e]);
        float ac = xc.x*w0.x + xc.y*w0.y + xc.z*w0.z + xc.w*w0.w;
        float an = xn.x*w1.x + xn.y*w1.y + xn.z*w1.z + xn.w*w1.w;
        #pragma unroll
        for (int off = 32; off; off >>= 1) {
            ac += __shfl_xor(ac, off, 64);
            an += __shfl_xor(an, off, 64);
        }
        if (lane == 0) { cdot[r] = ac; ndot[r] = an; }
    }
}

// ---- D1: gather (softmax over 23 nbrs) + attend MFMA -> ctxbf (coalesced)
struct GALds { ushort ctxpre[16][256]; ushort ctx[16][256]; float wsum_s[16]; };

__global__ __launch_bounds__(512) void gatherattend_kernel(
    const float* __restrict__ cdot, const float* __restrict__ ndot,
    const int* __restrict__ idx, const ushort* __restrict__ nbr,
    const float* __restrict__ alignBd,
    const ushort* __restrict__ attWd, const float* __restrict__ attBd,
    ushort* __restrict__ ctxbf)
{
    __shared__ GALds L;
    const int tid = threadIdx.x;
    const int r0 = blockIdx.x * 16;

    {   // gather: 16 row-groups x 32 lanes; 23 loads fully unrolled
        const int row16 = tid >> 5, sub = tid & 31;
        const int r = r0 + row16, b = r >> 9;
        float sc = -3e38f, vm = 0.f; int rn = 0;
        if (sub < NBR) {
            int j = idx[(size_t)r*NBR + sub];
            int valid = (j >= 0);
            int jj = valid ? j : j + SEQ;   // JAX wrap: f[-1] = last row
            rn = b*SEQ + jj;
            vm = (float)valid;
            sc = lrelu(cdot[r] + ndot[rn] + alignBd[0]) + (valid ? 0.f : NEGV);
        }
        float m = sc;
        #pragma unroll
        for (int off = 16; off; off >>= 1) m = fmaxf(m, __shfl_xor(m, off, 32));
        float ev = (sub < NBR) ? expf(sc - m) : 0.f;
        float s = ev;
        #pragma unroll
        for (int off = 16; off; off >>= 1) s += __shfl_xor(s, off, 32);
        float wgt = ev * vm / s;
        float ws = wgt;
        #pragma unroll
        for (int off = 16; off; off >>= 1) ws += __shfl_xor(ws, off, 32);
        float a8[8] = {};
        const int e0 = sub << 3;
        #pragma unroll
        for (int n = 0; n < NBR; ++n) {
            float wn = __shfl(wgt, n, 32);
            int   rr = __shfl(rn, n, 32);
            uint4 v = *reinterpret_cast<const uint4*>(&nbr[(size_t)rr*EMB + e0]);
            float x[8]; unpack8(v, x);
            #pragma unroll
            for (int i = 0; i < 8; ++i) a8[i] += wn * x[i];
        }
        uint4 o;
        o.x = pk2(a8[0],a8[1]); o.y = pk2(a8[2],a8[3]);
        o.z = pk2(a8[4],a8[5]); o.w = pk2(a8[6],a8[7]);
        *reinterpret_cast<uint4*>(&L.ctxpre[row16][(sub ^ (row16&7)) << 3]) = o;
        if (sub == 0) L.wsum_s[row16] = ws;
    }
    __syncthreads();

    const int wv = tid >> 6, lane = tid & 63;
    const int fr = lane & 15, grp = lane >> 4;
    {   // attend: wave owns cols wv*32 + f*16 + fr, f in 0..1
        f32x4 acc[2] = {(f32x4){0,0,0,0},(f32x4){0,0,0,0}};
        #pragma unroll
        for (int kt = 0; kt < 8; ++kt) {
            short8 af = *reinterpret_cast<const short8*>(
                &L.ctxpre[fr][((((kt<<2)+grp) ^ (fr&7)) << 3)]);
            #pragma unroll
            for (int f = 0; f < 2; ++f) {
                const int col = (wv<<5) + (f<<4) + fr;
                short8 bv = *reinterpret_cast<const short8*>(
                    &attWd[(size_t)col*EMB + (kt<<5) + (grp<<3)]);
                acc[f] = __builtin_amdgcn_mfma_f32_16x16x32_bf16(af, bv, acc[f], 0, 0, 0);
            }
        }
        #pragma unroll
        for (int f = 0; f < 2; ++f) {
            const int col = (wv<<5) + (f<<4) + fr;
            const float bb = attBd[col];
            #pragma unroll
            for (int j = 0; j < 4; ++j) {
                const int row = (grp<<2) + j;
                L.ctx[row][col] = f2bf(elu1(acc[f][j] + L.wsum_s[row]*bb));
            }
        }
    }
    __syncthreads();
    {   // coalesced copy out
        const int row = tid >> 5, c = tid & 31;
        uint4 v = *reinterpret_cast<const uint4*>(&L.ctx[row][c << 3]);
        *reinterpret_cast<uint4*>(&ctxbf[(size_t)(r0+row)*EMB + (c << 3)]) = v;
    }
}

// ---- D2: fat gi (0..383) + gh (384..767) big-tile GEMMs, K=256, N=768
__global__ __launch_bounds__(256) void gigh_kernel(
    const ushort* __restrict__ ctxbf, const ushort* __restrict__ gwihd,
    const float* __restrict__ gbihd, ushort* __restrict__ gibf,
    const ushort* __restrict__ hprevbf, const ushort* __restrict__ gwhhd,
    const float* __restrict__ gbhhd, ushort* __restrict__ ghbf)
{
    __shared__ GemmLds64 L;
    int blk = blockIdx.x;
    if (blk < 384)
        gemm64_dev<0>(ctxbf, gwihd, gbihd, nullptr, gibf, G3, EMB, blk & 31, blk >> 5, L);
    else {
        blk -= 384;
        gemm64_dev<0>(hprevbf, gwhhd, gbhhd, nullptr, ghbf, G3, EMB, blk & 31, blk >> 5, L);
    }
}

// ---- D3: GRU (bf16 state) + next-round dot2 (or seq ad if LAST).
// LAST additionally: writes f32 act (output) and atomically accumulates
// seqfeat[b,:] = sum_s act*mask via LDS block-reduce.
template<int LAST>
__global__ __launch_bounds__(512) void grudot_kernel(
    const ushort* __restrict__ gibf, const ushort* __restrict__ ghbf,
    const ushort* __restrict__ hprevbf, const float* __restrict__ nextW,
    const float* __restrict__ mask,
    ushort* __restrict__ hbf, float* __restrict__ actout,
    ushort* __restrict__ actbf,
    float* __restrict__ cdotO, float* __restrict__ ndotO,
    float* __restrict__ seqfeatA)
{
    __shared__ float sred[16][256];
    const int tid = threadIdx.x;
    const int row = tid >> 5, sub = tid & 31;
    const int e0 = sub << 3;
    const size_t r = (size_t)blockIdx.x * 16 + row;
    const size_t gb = r*G3;
    uint4 giA = *reinterpret_cast<const uint4*>(&gibf[gb + e0]);
    uint4 giB = *reinterpret_cast<const uint4*>(&gibf[gb + 256 + e0]);
    uint4 giC = *reinterpret_cast<const uint4*>(&gibf[gb + 512 + e0]);
    uint4 ghA = *reinterpret_cast<const uint4*>(&ghbf[gb + e0]);
    uint4 ghB = *reinterpret_cast<const uint4*>(&ghbf[gb + 256 + e0]);
    uint4 ghC = *reinterpret_cast<const uint4*>(&ghbf[gb + 512 + e0]);
    uint4 hpv = *reinterpret_cast<const uint4*>(&hprevbf[r*EMB + e0]);
    float ir_[8], iz_[8], in_[8], hr_[8], hz_[8], hn_[8], hp_[8];
    unpack8(giA, ir_); unpack8(giB, iz_); unpack8(giC, in_);
    unpack8(ghA, hr_); unpack8(ghB, hz_); unpack8(ghC, hn_);
    unpack8(hpv, hp_);
    float hv8[8], av8[8];
    #pragma unroll
    for (int i = 0; i < 8; ++i) {
        float rg = sigm(ir_[i] + hr_[i]);
        float z  = sigm(iz_[i] + hz_[i]);
        float n  = tanhf(in_[i] + rg*hn_[i]);
        hv8[i] = (1.f - z)*n + z*hp_[i];
        av8[i] = fmaxf(hv8[i], 0.f);
    }
    if (LAST) {
        *reinterpret_cast<float4*>(&actout[r*EMB + e0])     = make_float4(av8[0],av8[1],av8[2],av8[3]);
        *reinterpret_cast<float4*>(&actout[r*EMB + e0 + 4]) = make_float4(av8[4],av8[5],av8[6],av8[7]);
    }
    uint4 hb, ab;
    hb.x = pk2(hv8[0],hv8[1]); hb.y = pk2(hv8[2],hv8[3]);
    hb.z = pk2(hv8[4],hv8[5]); hb.w = pk2(hv8[6],hv8[7]);
    ab.x = pk2(av8[0],av8[1]); ab.y = pk2(av8[2],av8[3]);
    ab.z = pk2(av8[4],av8[5]); ab.w = pk2(av8[6],av8[7]);
    *reinterpret_cast<uint4*>(&hbf[r*EMB + e0])   = hb;
    *reinterpret_cast<uint4*>(&actbf[r*EMB + e0]) = ab;
    float pc = 0.f, pn = 0.f;
    float4 w1a = *reinterpret_cast<const float4*>(&nextW[EMB + e0]);
    float4 w1b = *reinterpret_cast<const float4*>(&nextW[EMB + e0 + 4]);
    pn = av8[0]*w1a.x + av8[1]*w1a.y + av8[2]*w1a.z + av8[3]*w1a.w
       + av8[4]*w1b.x + av8[5]*w1b.y + av8[6]*w1b.z + av8[7]*w1b.w;
    if (!LAST) {
        float4 w0a = *reinterpret_cast<const float4*>(&nextW[e0]);
        float4 w0b = *reinterpret_cast<const float4*>(&nextW[e0 + 4]);
        pc = av8[0]*w0a.x + av8[1]*w0a.y + av8[2]*w0a.z + av8[3]*w0a.w
           + av8[4]*w0b.x + av8[5]*w0b.y + av8[6]*w0b.z + av8[7]*w0b.w;
    }
    #pragma unroll
    for (int off = 16; off; off >>= 1) {
        pn += __shfl_xor(pn, off, 32);
        if (!LAST) pc += __shfl_xor(pc, off, 32);
    }
    if (sub == 0) {
        if (!LAST) cdotO[r] = pc;
        ndotO[r] = pn;
    }
    if (LAST) {
        const float mk = mask[r];
        #pragma unroll
        for (int i = 0; i < 8; ++i) sred[row][e0 + i] = av8[i] * mk;
        __syncthreads();
        if (tid < 256) {
            float s = 0.f;
            #pragma unroll
            for (int rr = 0; rr < 16; ++rr) s += sred[rr][tid];
            atomicAdd(&seqfeatA[(blockIdx.x >> 5)*EMB + tid], s);
        }
    }
}

// ---- tail: tf GEMM only (128 blocks)
__global__ __launch_bounds__(256) void seqpre_kernel(
    const ushort* __restrict__ actbf, const ushort* __restrict__ satWbf,
    const float* __restrict__ satB, float* __restrict__ tf)
{
    __shared__ GemmLds64 L;
    gemm64_dev<0>(actbf, satWbf, satB, tf, nullptr, EMB, EMB,
                  blockIdx.x & 31, blockIdx.x >> 5, L);
}

// ---- seqstep T0: cmol + softmax + full PV + elu + GRU step 1.
// Grid 32: (b, quarter q). 512 thr, 8 waves.
__global__ __launch_bounds__(512) void seqstep0_kernel(
    const float* __restrict__ ad, const float* __restrict__ mask,
    const float* __restrict__ saB, const float* __restrict__ saW,
    const float* __restrict__ seqfeat, const float* __restrict__ tf,
    const ushort* __restrict__ sgwihbf, const float* __restrict__ sgbih,
    const ushort* __restrict__ sgwhhbf, const float* __restrict__ sgbhh,
    float* __restrict__ sgi, float* __restrict__ sfout,
    float* __restrict__ actseq)
{
    const int b = blockIdx.x >> 2, q = blockIdx.x & 3;
    const int tid = threadIdx.x, lane = tid & 63, wv = tid >> 6;
    __shared__ float xs[EMB], hs[EMB], gis[192], ghs[192];
    __shared__ float w_s[SEQ], red[SEQ], pv[2][EMB];
    if (tid < EMB) {
        float sf = seqfeat[b*EMB + tid];
        hs[tid] = sf;
        red[tid] = fmaxf(sf, 0.f) * saW[tid];
    }
    __syncthreads();
    for (int off = 128; off; off >>= 1) {
        if (tid < off) red[tid] += red[tid + off];
        __syncthreads();
    }
    const float cmol = red[0];
    __syncthreads();
    const float mk = mask[b*SEQ + tid];
    const float sc = lrelu(cmol + ad[b*SEQ + tid] + saB[0]) + (mk == 0.f ? NEGV : 0.f);
    red[tid] = sc; __syncthreads();
    for (int off = 256; off; off >>= 1) {
        if (tid < off) red[tid] = fmaxf(red[tid], red[tid + off]);
        __syncthreads();
    }
    const float m = red[0]; __syncthreads();
    const float ev = expf(sc - m);
    red[tid] = ev; __syncthreads();
    for (int off = 256; off; off >>= 1) {
        if (tid < off) red[tid] += red[tid + off];
        __syncthreads();
    }
    w_s[tid] = ev / red[0] * mk;
    __syncthreads();
    {   // full PV: e = tid&255, two 256-s chunks
        const int e = tid & 255, scn = tid >> 8;
        const float* tfb = &tf[((size_t)b*SEQ + scn*256)*EMB + e];
        float acc = 0.f;
        #pragma unroll 4
        for (int s = 0; s < 256; ++s)
            acc += w_s[scn*256 + s] * tfb[(size_t)s*EMB];
        pv[scn][e] = acc;
    }
    __syncthreads();
    if (tid < EMB) xs[tid] = elu1(pv[0][tid] + pv[1][tid]);
    __syncthreads();
    // matvecs: 384 rows (192 wih@xs + 192 whh@hs), 8 waves x 48
    for (int i = 0; i < 48; ++i) {
        const int l = wv * 48 + i;
        const int iswih = (l < 192);
        const int ll = iswih ? l : l - 192;
        const int g = (ll >> 6)*EMB + (q << 6) + (ll & 63);
        const ushort* Wm = iswih ? sgwihbf : sgwhhbf;
        ushort4 w4 = *reinterpret_cast<const ushort4*>(&Wm[(size_t)g*EMB + (lane << 2)]);
        float4 x4 = *reinterpret_cast<const float4*>(iswih ? &xs[lane << 2] : &hs[lane << 2]);
        float d = bf2f(w4.x)*x4.x + bf2f(w4.y)*x4.y + bf2f(w4.z)*x4.z + bf2f(w4.w)*x4.w;
        #pragma unroll
        for (int off = 32; off; off >>= 1) d += __shfl_xor(d, off, 64);
        if (lane == 0) {
            if (iswih) {
                d += sgbih[g];
                gis[ll] = d;
                sgi[b*G3 + g] = d;
            } else {
                ghs[ll] = d + sgbhh[g];
            }
        }
    }
    __syncthreads();
    if (tid < 64) {
        const int e = (q << 6) + tid;
        float rg = sigm(gis[tid]       + ghs[tid]);
        float z  = sigm(gis[64 + tid]  + ghs[64 + tid]);
        float n  = tanhf(gis[128 + tid] + rg*ghs[128 + tid]);
        float hv = (1.f - z)*n + z*hs[e];
        sfout[b*EMB + e]  = hv;
        actseq[b*EMB + e] = fmaxf(hv, 0.f);
    }
}

// ---- seqstep T1: gi from global, gh matvec, combine. Grid 32.
__global__ __launch_bounds__(512) void seqstep1_kernel(
    const float* __restrict__ sfin,
    const ushort* __restrict__ sgwhhbf, const float* __restrict__ sgbhh,
    const float* __restrict__ sgi, float* __restrict__ sfout,
    float* __restrict__ actseq)
{
    const int b = blockIdx.x >> 2, q = blockIdx.x & 3;
    const int tid = threadIdx.x, lane = tid & 63, wv = tid >> 6;
    __shared__ float hs[EMB];
    __shared__ float gis[192], ghs[192];
    if (tid < EMB) hs[tid] = sfin[b*EMB + tid];
    for (int l = tid; l < 192; l += 512) {
        int g = (l >> 6)*EMB + (q << 6) + (l & 63);
        gis[l] = sgi[b*G3 + g];
    }
    __syncthreads();
    for (int i = 0; i < 24; ++i) {
        const int l = wv * 24 + i;
        const int g = (l >> 6)*EMB + (q << 6) + (l & 63);
        ushort4 w4 = *reinterpret_cast<const ushort4*>(&sgwhhbf[(size_t)g*EMB + (lane << 2)]);
        float4 h4 = *reinterpret_cast<const float4*>(&hs[lane << 2]);
        float d = bf2f(w4.x)*h4.x + bf2f(w4.y)*h4.y + bf2f(w4.z)*h4.z + bf2f(w4.w)*h4.w;
        #pragma unroll
        for (int off = 32; off; off >>= 1) d += __shfl_xor(d, off, 64);
        if (lane == 0) ghs[l] = d + sgbhh[g];
    }
    __syncthreads();
    if (tid < 64) {
        const int e = (q << 6) + tid;
        float rg = sigm(gis[tid]       + ghs[tid]);
        float z  = sigm(gis[64 + tid]  + ghs[64 + tid]);
        float n  = tanhf(gis[128 + tid] + rg*ghs[128 + tid]);
        float hv = (1.f - z)*n + z*hs[e];
        sfout[b*EMB + e]  = hv;
        actseq[b*EMB + e] = fmaxf(hv, 0.f);
    }
}

extern "C" void kernel_launch(void* const* d_in, const int* in_sizes, int n_in,
                              void* d_out, int out_size, void* d_ws, size_t ws_size,
                              hipStream_t stream) {
    (void)in_sizes; (void)n_in; (void)out_size; (void)ws_size;
    const float* amino  = (const float*)d_in[0];
    const float* mask   = (const float*)d_in[1];
    const float* embW   = (const float*)d_in[2];
    const float* embB   = (const float*)d_in[3];
    const float* nbW    = (const float*)d_in[4];
    const float* nbB    = (const float*)d_in[5];
    const float* alignW = (const float*)d_in[6];
    const float* alignB = (const float*)d_in[7];
    const float* attW   = (const float*)d_in[8];
    const float* attB   = (const float*)d_in[9];
    const float* gwih   = (const float*)d_in[10];
    const float* gwhh   = (const float*)d_in[11];
    const float* gbih   = (const float*)d_in[12];
    const float* gbhh   = (const float*)d_in[13];
    const float* saW    = (const float*)d_in[14];
    const float* saB    = (const float*)d_in[15];
    const float* satW   = (const float*)d_in[16];
    const float* satB   = (const float*)d_in[17];
    const float* sgwih  = (const float*)d_in[18];
    const float* sgbih  = (const float*)d_in[19];
    const float* sgwhh  = (const float*)d_in[20];
    const float* sgbhh  = (const float*)d_in[21];
    const int*   idx    = (const int*)d_in[22];

    char* cur = (char*)d_ws;
    auto alloc = [&](size_t bytes) -> char* {
        char* p = cur; cur += (bytes + 255) & ~(size_t)255; return p;
    };
    float* feat    = (float*)alloc((size_t)BS*EMB*4);
    float* nbase   = (float*)alloc((size_t)BS*EMB*4);
    float* tf      = (float*)alloc((size_t)BS*EMB*4);
    float* cdot    = (float*)alloc(BS*4);
    float* ndot    = (float*)alloc(BS*4);   // doubles as ad after round 2
    float* seqfeat = (float*)alloc(BSZ*EMB*4);
    float* sf2     = (float*)alloc(BSZ*EMB*4);
    float* sgi     = (float*)alloc(BSZ*G3*4);
    ushort* aminobf  = (ushort*)alloc((size_t)BS*INITD*2);
    ushort* featbf   = (ushort*)alloc((size_t)BS*EMB*2);
    ushort* nbasebf  = (ushort*)alloc((size_t)BS*EMB*2);
    ushort* actbf    = (ushort*)alloc((size_t)BS*EMB*2);
    ushort* hbf      = (ushort*)alloc((size_t)BS*EMB*2);
    ushort* ctxbf    = (ushort*)alloc((size_t)BS*EMB*2);
    ushort* gibf     = (ushort*)alloc((size_t)BS*G3*2);
    ushort* ghbf     = (ushort*)alloc((size_t)BS*G3*2);
    ushort* embWbf   = (ushort*)alloc((size_t)EMB*INITD*2);
    ushort* nbWbf    = (ushort*)alloc((size_t)EMB*INITD*2);
    ushort* attWbf   = (ushort*)alloc((size_t)3*EMB*EMB*2);
    ushort* gwihbf   = (ushort*)alloc((size_t)3*G3*EMB*2);
    ushort* gwhhbf   = (ushort*)alloc((size_t)3*G3*EMB*2);
    ushort* satWbf   = (ushort*)alloc((size_t)EMB*EMB*2);
    ushort* sgwihbf  = (ushort*)alloc((size_t)G3*EMB*2);
    ushort* sgwhhbf  = (ushort*)alloc((size_t)G3*EMB*2);

    float* out    = (float*)d_out;
    float* actseq = out;               // (B,E)
    float* act    = out + BSZ*EMB;     // (B,S,E)

    convert_flat<<<2048, 256, 0, stream>>>(
        amino, aminobf, embW, embWbf, nbW, nbWbf, attW, attWbf,
        gwih, gwihbf, gwhh, gwhhbf, satW, satWbf,
        sgwih, sgwihbf, sgwhh, sgwhhbf, seqfeat);

    featnbase_kernel<<<256, 256, 0, stream>>>(
        aminobf, embWbf, embB, feat, featbf, nbWbf, nbB, nbase, nbasebf);

    dot2_kernel<<<128, 256, 0, stream>>>(feat, nbase, alignW, cdot, ndot);

    for (int d = 0; d < 3; ++d) {
        const ushort* nbrbf   = (d == 0) ? nbasebf : actbf;
        const ushort* hprevbf = (d == 0) ? featbf  : hbf;
        gatherattend_kernel<<<BS/16, 512, 0, stream>>>(
            cdot, ndot, idx, nbrbf, alignB + d,
            attWbf + (size_t)d*EMB*EMB, attB + d*EMB, ctxbf);
        gigh_kernel<<<768, 256, 0, stream>>>(
            ctxbf, gwihbf + (size_t)d*G3*EMB, gbih + d*G3, gibf,
            hprevbf, gwhhbf + (size_t)d*G3*EMB, gbhh + d*G3, ghbf);
        if (d < 2) {
            grudot_kernel<0><<<BS/16, 512, 0, stream>>>(
                gibf, ghbf, hprevbf, alignW + (d+1)*2*EMB, mask,
                hbf, act, actbf, cdot, ndot, seqfeat);
        } else {
            grudot_kernel<1><<<BS/16, 512, 0, stream>>>(
                gibf, ghbf, hprevbf, saW, mask,
                hbf, act, actbf, cdot, ndot, seqfeat);   // ndot <- ad
        }
    }

    seqpre_kernel<<<128, 256, 0, stream>>>(actbf, satWbf, satB, tf);
    seqstep0_kernel<<<32, 512, 0, stream>>>(
        ndot, mask, saB, saW, seqfeat, tf,
        sgwihbf, sgbih, sgwhhbf, sgbhh, sgi, sf2, actseq);
    seqstep1_kernel<<<32, 512, 0, stream>>>(
        sf2, sgwhhbf, sgbhh, sgi, seqfeat, actseq);
}

// Round 13
// 164.593 us; speedup vs baseline: 5.8135x; 1.0756x over previous
//
#include <hip/hip_runtime.h>
#include <math.h>

// ProGAT: B=8,S=512,NB=23,INIT=512,E=256,R=3,T=2
// R13: R12 with the tail un-folded: 128-block seqpv2 (cmol inline) + R11
// seqstep template. R12's 32-block full-PV seqstep0 was a 57us latency chain.

#define BSZ   8
#define SEQ   512
#define NBR   23
#define EMB   256
#define INITD 512
#define BS    (BSZ*SEQ)     // 4096
#define G3    (3*EMB)       // 768
#define NEGV  -9e8f

typedef __attribute__((ext_vector_type(8))) short short8;
typedef __attribute__((ext_vector_type(4))) float f32x4;

__device__ __forceinline__ float lrelu(float x){ return x > 0.f ? x : 0.01f*x; }
__device__ __forceinline__ float elu1 (float x){ return x > 0.f ? x : (expf(x)-1.f); }
__device__ __forceinline__ float sigm (float x){ return 1.f/(1.f+expf(-x)); }
__device__ __forceinline__ float bf2f(ushort u){
    union { unsigned int i; float f; } v; v.i = ((unsigned int)u) << 16; return v.f;
}
__device__ __forceinline__ ushort f2bf(float f){
    union { float f; unsigned int i; } v; v.f = f;
    unsigned int u = v.i;
    return (ushort)((u + 0x7FFFu + ((u >> 16) & 1u)) >> 16);   // RNE
}
__device__ __forceinline__ unsigned pk2(float a, float b){
    return (unsigned)f2bf(a) | ((unsigned)f2bf(b) << 16);
}
__device__ __forceinline__ void unpack8(uint4 v, float* o) {
    o[0]=bf2f((ushort)(v.x&0xffff)); o[1]=bf2f((ushort)(v.x>>16));
    o[2]=bf2f((ushort)(v.y&0xffff)); o[3]=bf2f((ushort)(v.y>>16));
    o[4]=bf2f((ushort)(v.z&0xffff)); o[5]=bf2f((ushort)(v.z>>16));
    o[6]=bf2f((ushort)(v.w&0xffff)); o[7]=bf2f((ushort)(v.w>>16));
}

__device__ __forceinline__ void gload_lds16(const void* g, void* l) {
    __builtin_amdgcn_global_load_lds(
        (const __attribute__((address_space(1))) unsigned int*)g,
        (__attribute__((address_space(3))) unsigned int*)l,
        16, 0, 0);
}

// ---- balanced flat converter: 9 bf16 segments + seqfeat zero-fill.
__global__ __launch_bounds__(256) void convert_flat(
    const float* __restrict__ amino, ushort* __restrict__ aminobf,
    const float* __restrict__ embW,  ushort* __restrict__ embWbf,
    const float* __restrict__ nbW,   ushort* __restrict__ nbWbf,
    const float* __restrict__ attW,  ushort* __restrict__ attWbf,
    const float* __restrict__ gwih,  ushort* __restrict__ gwihbf,
    const float* __restrict__ gwhh,  ushort* __restrict__ gwhhbf,
    const float* __restrict__ satW,  ushort* __restrict__ satWbf,
    const float* __restrict__ sgwih, ushort* __restrict__ sgwihbf,
    const float* __restrict__ sgwhh, ushort* __restrict__ sgwhhbf,
    float* __restrict__ seqfeatZ)
{
    const unsigned stride = gridDim.x * 256;
    for (unsigned u = blockIdx.x*256 + threadIdx.x; u < 524544u; u += stride) {
        const float* s; ushort* d; unsigned lu;
        if      (u < 262144u) { s=amino; d=aminobf; lu=u; }
        else if (u < 278528u) { s=embW;  d=embWbf;  lu=u-262144u; }
        else if (u < 294912u) { s=nbW;   d=nbWbf;   lu=u-278528u; }
        else if (u < 319488u) { s=attW;  d=attWbf;  lu=u-294912u; }
        else if (u < 393216u) { s=gwih;  d=gwihbf;  lu=u-319488u; }
        else if (u < 466944u) { s=gwhh;  d=gwhhbf;  lu=u-393216u; }
        else if (u < 475136u) { s=satW;  d=satWbf;  lu=u-466944u; }
        else if (u < 499712u) { s=sgwih; d=sgwihbf; lu=u-475136u; }
        else if (u < 524288u) { s=sgwhh; d=sgwhhbf; lu=u-499712u; }
        else {
            unsigned i = (u - 524288u) * 8;
            *reinterpret_cast<float4*>(&seqfeatZ[i])     = make_float4(0,0,0,0);
            *reinterpret_cast<float4*>(&seqfeatZ[i + 4]) = make_float4(0,0,0,0);
            continue;
        }
        size_t i = (size_t)lu * 8;
        float4 a = *reinterpret_cast<const float4*>(s + i);
        float4 b = *reinterpret_cast<const float4*>(s + i + 4);
        uint4 o;
        o.x = pk2(a.x, a.y); o.y = pk2(a.z, a.w);
        o.z = pk2(b.x, b.y); o.w = pk2(b.z, b.w);
        *reinterpret_cast<uint4*>(d + i) = o;
    }
}

// ---- 128x64 MFMA GEMM; global_load_lds staging, dbuf
struct GemmLds64 { ushort A[2][128][64]; ushort B[2][64][64]; };

template<int ACT>
__device__ __forceinline__ void gemm64_dev(
    const ushort* __restrict__ A, const ushort* __restrict__ W,
    const float* __restrict__ bias,
    float* __restrict__ C, ushort* __restrict__ Cbf,
    int N, int K, int bx, int by, GemmLds64& L)
{
    const int tid = threadIdx.x;
    const int m0 = bx * 128, n0 = by * 64;
    const int wv = tid >> 6, lane = tid & 63;
    const int fr = lane & 15, grp = lane >> 4;
    const int kc = K >> 3;
    const int mh = wv & 1, nh = wv >> 1;
    const int lrow = lane >> 3;
    const int csrc = (lane & 7) ^ lrow;

    f32x4 acc[4][2];
    #pragma unroll
    for (int i = 0; i < 4; ++i)
        #pragma unroll
        for (int n = 0; n < 2; ++n) acc[i][n] = (f32x4){0.f,0.f,0.f,0.f};

    auto stage = [&](int c, int k0) {
        const int kch = (k0 >> 3) + csrc;
        #pragma unroll
        for (int i = 0; i < 4; ++i) {
            const int s = (wv << 2) + i;
            gload_lds16(A + ((size_t)(m0 + (s << 3) + lrow) * kc + kch) * 8,
                        &L.A[c][s << 3][0]);
        }
        #pragma unroll
        for (int i = 0; i < 2; ++i) {
            const int s = (wv << 1) + i;
            gload_lds16(W + ((size_t)(n0 + (s << 3) + lrow) * kc + kch) * 8,
                        &L.B[c][s << 3][0]);
        }
    };
    auto compute = [&](int c) {
        #pragma unroll
        for (int ks = 0; ks < 2; ++ks) {
            short8 af[4];
            #pragma unroll
            for (int i = 0; i < 4; ++i) {
                const int ar = (mh << 6) + (i << 4) + fr;
                af[i] = *reinterpret_cast<const short8*>(
                    &L.A[c][ar][(((ks << 2) + grp) ^ (ar & 7)) << 3]);
            }
            #pragma unroll
            for (int n = 0; n < 2; ++n) {
                const int br = (nh << 5) + (n << 4) + fr;
                short8 bv = *reinterpret_cast<const short8*>(
                    &L.B[c][br][(((ks << 2) + grp) ^ (br & 7)) << 3]);
                #pragma unroll
                for (int i = 0; i < 4; ++i)
                    acc[i][n] = __builtin_amdgcn_mfma_f32_16x16x32_bf16(
                        af[i], bv, acc[i][n], 0, 0, 0);
            }
        }
    };

    const int KT = K >> 6;
    stage(0, 0);
    __syncthreads();
    int cur = 0;
    for (int kt = 1; kt < KT; ++kt) {
        stage(cur ^ 1, kt << 6);
        compute(cur);
        __syncthreads();
        cur ^= 1;
    }
    compute(cur);

    #pragma unroll
    for (int i = 0; i < 4; ++i) {
        const int mrow = m0 + (mh << 6) + (i << 4) + (grp << 2);
        #pragma unroll
        for (int n = 0; n < 2; ++n) {
            const int col = n0 + (nh << 5) + (n << 4) + fr;
            const float bv = bias[col];
            #pragma unroll
            for (int j = 0; j < 4; ++j) {
                float t = acc[i][n][j] + bv;
                if (ACT == 1) t = lrelu(t);
                size_t off = (size_t)(mrow + j) * N + col;
                if (C)   C[off] = t;
                if (Cbf) Cbf[off] = f2bf(t);
            }
        }
    }
}

// ---- fat: feat GEMM (0..127) + nbase GEMM (128..255), K=512
__global__ __launch_bounds__(256) void featnbase_kernel(
    const ushort* __restrict__ aminobf,
    const ushort* __restrict__ embWbf, const float* __restrict__ embB,
    float* __restrict__ feat, ushort* __restrict__ featbf,
    const ushort* __restrict__ nbWbf, const float* __restrict__ nbB,
    float* __restrict__ nbase, ushort* __restrict__ nbasebf)
{
    __shared__ GemmLds64 L;
    int blk = blockIdx.x;
    if (blk < 128)
        gemm64_dev<1>(aminobf, embWbf, embB, feat, featbf, EMB, INITD, blk & 31, blk >> 5, L);
    else {
        blk -= 128;
        gemm64_dev<1>(aminobf, nbWbf, nbB, nbase, nbasebf, EMB, INITD, blk & 31, blk >> 5, L);
    }
}

// ---- dot2 for round 0: 128 blocks x 32 rows
__global__ __launch_bounds__(256) void dot2_kernel(
    const float* __restrict__ center, const float* __restrict__ nbrbase,
    const float* __restrict__ alignWd,
    float* __restrict__ cdot, float* __restrict__ ndot)
{
    const int lane = threadIdx.x & 63;
    const int wv   = threadIdx.x >> 6;
    const int e    = lane << 2;
    const int rb   = blockIdx.x * 32 + wv * 8;
    float4 w0 = *reinterpret_cast<const float4*>(&alignWd[e]);
    float4 w1 = *reinterpret_cast<const float4*>(&alignWd[EMB + e]);
    #pragma unroll
    for (int i = 0; i < 8; ++i) {
        const int r = rb + i;
        float4 xc = *reinterpret_cast<const float4*>(&center[(size_t)r*EMB + e]);
        float4 xn = *reinterpret_cast<const float4*>(&nbrbase[(size_t)r*EMB + e]);
        float ac = xc.x*w0.x + xc.y*w0.y + xc.z*w0.z + xc.w*w0.w;
        float an = xn.x*w1.x + xn.y*w1.y + xn.z*w1.z + xn.w*w1.w;
        #pragma unroll
        for (int off = 32; off; off >>= 1) {
            ac += __shfl_xor(ac, off, 64);
            an += __shfl_xor(an, off, 64);
        }
        if (lane == 0) { cdot[r] = ac; ndot[r] = an; }
    }
}

// ---- D1: gather (softmax over 23 nbrs) + attend MFMA -> ctxbf
struct GALds { ushort ctxpre[16][256]; ushort ctx[16][256]; float wsum_s[16]; };

__global__ __launch_bounds__(512) void gatherattend_kernel(
    const float* __restrict__ cdot, const float* __restrict__ ndot,
    const int* __restrict__ idx, const ushort* __restrict__ nbr,
    const float* __restrict__ alignBd,
    const ushort* __restrict__ attWd, const float* __restrict__ attBd,
    ushort* __restrict__ ctxbf)
{
    __shared__ GALds L;
    const int tid = threadIdx.x;
    const int r0 = blockIdx.x * 16;

    {   // gather
        const int row16 = tid >> 5, sub = tid & 31;
        const int r = r0 + row16, b = r >> 9;
        float sc = -3e38f, vm = 0.f; int rn = 0;
        if (sub < NBR) {
            int j = idx[(size_t)r*NBR + sub];
            int valid = (j >= 0);
            int jj = valid ? j : j + SEQ;   // JAX wrap: f[-1] = last row
            rn = b*SEQ + jj;
            vm = (float)valid;
            sc = lrelu(cdot[r] + ndot[rn] + alignBd[0]) + (valid ? 0.f : NEGV);
        }
        float m = sc;
        #pragma unroll
        for (int off = 16; off; off >>= 1) m = fmaxf(m, __shfl_xor(m, off, 32));
        float ev = (sub < NBR) ? expf(sc - m) : 0.f;
        float s = ev;
        #pragma unroll
        for (int off = 16; off; off >>= 1) s += __shfl_xor(s, off, 32);
        float wgt = ev * vm / s;
        float ws = wgt;
        #pragma unroll
        for (int off = 16; off; off >>= 1) ws += __shfl_xor(ws, off, 32);
        float a8[8] = {};
        const int e0 = sub << 3;
        #pragma unroll
        for (int n = 0; n < NBR; ++n) {
            float wn = __shfl(wgt, n, 32);
            int   rr = __shfl(rn, n, 32);
            uint4 v = *reinterpret_cast<const uint4*>(&nbr[(size_t)rr*EMB + e0]);
            float x[8]; unpack8(v, x);
            #pragma unroll
            for (int i = 0; i < 8; ++i) a8[i] += wn * x[i];
        }
        uint4 o;
        o.x = pk2(a8[0],a8[1]); o.y = pk2(a8[2],a8[3]);
        o.z = pk2(a8[4],a8[5]); o.w = pk2(a8[6],a8[7]);
        *reinterpret_cast<uint4*>(&L.ctxpre[row16][(sub ^ (row16&7)) << 3]) = o;
        if (sub == 0) L.wsum_s[row16] = ws;
    }
    __syncthreads();

    const int wv = tid >> 6, lane = tid & 63;
    const int fr = lane & 15, grp = lane >> 4;
    {   // attend MFMA
        f32x4 acc[2] = {(f32x4){0,0,0,0},(f32x4){0,0,0,0}};
        #pragma unroll
        for (int kt = 0; kt < 8; ++kt) {
            short8 af = *reinterpret_cast<const short8*>(
                &L.ctxpre[fr][((((kt<<2)+grp) ^ (fr&7)) << 3)]);
            #pragma unroll
            for (int f = 0; f < 2; ++f) {
                const int col = (wv<<5) + (f<<4) + fr;
                short8 bv = *reinterpret_cast<const short8*>(
                    &attWd[(size_t)col*EMB + (kt<<5) + (grp<<3)]);
                acc[f] = __builtin_amdgcn_mfma_f32_16x16x32_bf16(af, bv, acc[f], 0, 0, 0);
            }
        }
        #pragma unroll
        for (int f = 0; f < 2; ++f) {
            const int col = (wv<<5) + (f<<4) + fr;
            const float bb = attBd[col];
            #pragma unroll
            for (int j = 0; j < 4; ++j) {
                const int row = (grp<<2) + j;
                L.ctx[row][col] = f2bf(elu1(acc[f][j] + L.wsum_s[row]*bb));
            }
        }
    }
    __syncthreads();
    {   // coalesced copy out
        const int row = tid >> 5, c = tid & 31;
        uint4 v = *reinterpret_cast<const uint4*>(&L.ctx[row][c << 3]);
        *reinterpret_cast<uint4*>(&ctxbf[(size_t)(r0+row)*EMB + (c << 3)]) = v;
    }
}

// ---- D2: fat gi (0..383) + gh (384..767) big-tile GEMMs
__global__ __launch_bounds__(256) void gigh_kernel(
    const ushort* __restrict__ ctxbf, const ushort* __restrict__ gwihd,
    const float* __restrict__ gbihd, ushort* __restrict__ gibf,
    const ushort* __restrict__ hprevbf, const ushort* __restrict__ gwhhd,
    const float* __restrict__ gbhhd, ushort* __restrict__ ghbf)
{
    __shared__ GemmLds64 L;
    int blk = blockIdx.x;
    if (blk < 384)
        gemm64_dev<0>(ctxbf, gwihd, gbihd, nullptr, gibf, G3, EMB, blk & 31, blk >> 5, L);
    else {
        blk -= 384;
        gemm64_dev<0>(hprevbf, gwhhd, gbhhd, nullptr, ghbf, G3, EMB, blk & 31, blk >> 5, L);
    }
}

// ---- D3: GRU (bf16 state) + next-round dot2 (or seq ad if LAST).
// LAST: f32 act out + atomic seqfeat accumulation.
template<int LAST>
__global__ __launch_bounds__(512) void grudot_kernel(
    const ushort* __restrict__ gibf, const ushort* __restrict__ ghbf,
    const ushort* __restrict__ hprevbf, const float* __restrict__ nextW,
    const float* __restrict__ mask,
    ushort* __restrict__ hbf, float* __restrict__ actout,
    ushort* __restrict__ actbf,
    float* __restrict__ cdotO, float* __restrict__ ndotO,
    float* __restrict__ seqfeatA)
{
    __shared__ float sred[16][256];
    const int tid = threadIdx.x;
    const int row = tid >> 5, sub = tid & 31;
    const int e0 = sub << 3;
    const size_t r = (size_t)blockIdx.x * 16 + row;
    const size_t gb = r*G3;
    uint4 giA = *reinterpret_cast<const uint4*>(&gibf[gb + e0]);
    uint4 giB = *reinterpret_cast<const uint4*>(&gibf[gb + 256 + e0]);
    uint4 giC = *reinterpret_cast<const uint4*>(&gibf[gb + 512 + e0]);
    uint4 ghA = *reinterpret_cast<const uint4*>(&ghbf[gb + e0]);
    uint4 ghB = *reinterpret_cast<const uint4*>(&ghbf[gb + 256 + e0]);
    uint4 ghC = *reinterpret_cast<const uint4*>(&ghbf[gb + 512 + e0]);
    uint4 hpv = *reinterpret_cast<const uint4*>(&hprevbf[r*EMB + e0]);
    float ir_[8], iz_[8], in_[8], hr_[8], hz_[8], hn_[8], hp_[8];
    unpack8(giA, ir_); unpack8(giB, iz_); unpack8(giC, in_);
    unpack8(ghA, hr_); unpack8(ghB, hz_); unpack8(ghC, hn_);
    unpack8(hpv, hp_);
    float hv8[8], av8[8];
    #pragma unroll
    for (int i = 0; i < 8; ++i) {
        float rg = sigm(ir_[i] + hr_[i]);
        float z  = sigm(iz_[i] + hz_[i]);
        float n  = tanhf(in_[i] + rg*hn_[i]);
        hv8[i] = (1.f - z)*n + z*hp_[i];
        av8[i] = fmaxf(hv8[i], 0.f);
    }
    if (LAST) {
        *reinterpret_cast<float4*>(&actout[r*EMB + e0])     = make_float4(av8[0],av8[1],av8[2],av8[3]);
        *reinterpret_cast<float4*>(&actout[r*EMB + e0 + 4]) = make_float4(av8[4],av8[5],av8[6],av8[7]);
    }
    uint4 hb, ab;
    hb.x = pk2(hv8[0],hv8[1]); hb.y = pk2(hv8[2],hv8[3]);
    hb.z = pk2(hv8[4],hv8[5]); hb.w = pk2(hv8[6],hv8[7]);
    ab.x = pk2(av8[0],av8[1]); ab.y = pk2(av8[2],av8[3]);
    ab.z = pk2(av8[4],av8[5]); ab.w = pk2(av8[6],av8[7]);
    *reinterpret_cast<uint4*>(&hbf[r*EMB + e0])   = hb;
    *reinterpret_cast<uint4*>(&actbf[r*EMB + e0]) = ab;
    float pc = 0.f, pn = 0.f;
    float4 w1a = *reinterpret_cast<const float4*>(&nextW[EMB + e0]);
    float4 w1b = *reinterpret_cast<const float4*>(&nextW[EMB + e0 + 4]);
    pn = av8[0]*w1a.x + av8[1]*w1a.y + av8[2]*w1a.z + av8[3]*w1a.w
       + av8[4]*w1b.x + av8[5]*w1b.y + av8[6]*w1b.z + av8[7]*w1b.w;
    if (!LAST) {
        float4 w0a = *reinterpret_cast<const float4*>(&nextW[e0]);
        float4 w0b = *reinterpret_cast<const float4*>(&nextW[e0 + 4]);
        pc = av8[0]*w0a.x + av8[1]*w0a.y + av8[2]*w0a.z + av8[3]*w0a.w
           + av8[4]*w0b.x + av8[5]*w0b.y + av8[6]*w0b.z + av8[7]*w0b.w;
    }
    #pragma unroll
    for (int off = 16; off; off >>= 1) {
        pn += __shfl_xor(pn, off, 32);
        if (!LAST) pc += __shfl_xor(pc, off, 32);
    }
    if (sub == 0) {
        if (!LAST) cdotO[r] = pc;
        ndotO[r] = pn;
    }
    if (LAST) {
        const float mk = mask[r];
        #pragma unroll
        for (int i = 0; i < 8; ++i) sred[row][e0 + i] = av8[i] * mk;
        __syncthreads();
        if (tid < 256) {
            float s = 0.f;
            #pragma unroll
            for (int rr = 0; rr < 16; ++rr) s += sred[rr][tid];
            atomicAdd(&seqfeatA[(blockIdx.x >> 5)*EMB + tid], s);
        }
    }
}

// ---- tail: tf GEMM only (128 blocks)
__global__ __launch_bounds__(256) void seqpre_kernel(
    const ushort* __restrict__ actbf, const ushort* __restrict__ satWbf,
    const float* __restrict__ satB, float* __restrict__ tf)
{
    __shared__ GemmLds64 L;
    gemm64_dev<0>(actbf, satWbf, satB, tf, nullptr, EMB, EMB,
                  blockIdx.x & 31, blockIdx.x >> 5, L);
}

// ---- seqpv2: cmol (inline, redundant per block) + softmax + 32-s PV strip.
// Block (st, b) -> partial[b,st,:].
__global__ __launch_bounds__(256) void seqpv2_kernel(
    const float* __restrict__ ad, const float* __restrict__ mask,
    const float* __restrict__ saB, const float* __restrict__ saW,
    const float* __restrict__ seqfeat, const float* __restrict__ tf,
    float* __restrict__ partial)
{
    const int st = blockIdx.x, b = blockIdx.y;
    const int tid = threadIdx.x;
    __shared__ float w_s[SEQ];
    __shared__ float red[256];
    // cmol = relu(seqfeat[b])·saW
    red[tid] = fmaxf(seqfeat[b*EMB + tid], 0.f) * saW[tid];
    __syncthreads();
    for (int off = 128; off; off >>= 1) {
        if (tid < off) red[tid] += red[tid + off];
        __syncthreads();
    }
    const float cb = red[0];
    __syncthreads();
    float mk0 = mask[b*SEQ + tid], mk1 = mask[b*SEQ + 256 + tid];
    float bb = saB[0];
    float s0 = lrelu(cb + ad[b*SEQ + tid] + bb)       + (mk0 == 0.f ? NEGV : 0.f);
    float s1 = lrelu(cb + ad[b*SEQ + 256 + tid] + bb) + (mk1 == 0.f ? NEGV : 0.f);
    red[tid] = fmaxf(s0, s1); __syncthreads();
    for (int off = 128; off; off >>= 1) {
        if (tid < off) red[tid] = fmaxf(red[tid], red[tid + off]);
        __syncthreads();
    }
    float m = red[0]; __syncthreads();
    float e0 = expf(s0 - m), e1 = expf(s1 - m);
    red[tid] = e0 + e1; __syncthreads();
    for (int off = 128; off; off >>= 1) {
        if (tid < off) red[tid] += red[tid + off];
        __syncthreads();
    }
    float inv = 1.f / red[0];
    w_s[tid]       = e0 * inv * mk0;
    w_s[tid + 256] = e1 * inv * mk1;
    __syncthreads();
    float acc = 0.f;
    const int s0i = st * 32;
    #pragma unroll 4
    for (int s = s0i; s < s0i + 32; ++s)
        acc += w_s[s] * tf[((size_t)b*SEQ + s)*EMB + tid];
    partial[((size_t)b*16 + st)*EMB + tid] = acc;
}

// Fused tail GRU step (R11-proven). Grid 32: (b, quarter q). 512 thr, 8 waves.
template<int T0>
__global__ __launch_bounds__(512) void seqstep_kernel(
    const float* __restrict__ partial, const float* __restrict__ sfin,
    const ushort* __restrict__ sgwihbf, const float* __restrict__ sgbih,
    const ushort* __restrict__ sgwhhbf, const float* __restrict__ sgbhh,
    float* __restrict__ sgi, float* __restrict__ sfout,
    float* __restrict__ actseq)
{
    const int b = blockIdx.x >> 2, q = blockIdx.x & 3;
    const int tid = threadIdx.x, lane = tid & 63, wv = tid >> 6;
    __shared__ float xs[EMB];
    __shared__ float hs[EMB];
    __shared__ float gis[192], ghs[192];
    if (tid < EMB) {
        hs[tid] = sfin[b*EMB + tid];
        if (T0) {
            float a = 0.f;
            #pragma unroll
            for (int st = 0; st < 16; ++st)
                a += partial[((size_t)b*16 + st)*EMB + tid];
            xs[tid] = elu1(a);
        }
    }
    if (!T0) {
        for (int l = tid; l < 192; l += 512) {
            int g = (l >> 6)*EMB + (q << 6) + (l & 63);
            gis[l] = sgi[b*G3 + g];
        }
    }
    __syncthreads();
    const int nrows = T0 ? 384 : 192;
    const int rpw = nrows >> 3;
    for (int i = 0; i < rpw; ++i) {
        const int l = wv * rpw + i;
        const int iswih = T0 && (l < 192);
        const int ll = (T0 && l >= 192) ? l - 192 : l;
        const int g = (ll >> 6)*EMB + (q << 6) + (ll & 63);
        const ushort* Wm = iswih ? sgwihbf : sgwhhbf;
        ushort4 w4 = *reinterpret_cast<const ushort4*>(&Wm[(size_t)g*EMB + (lane << 2)]);
        float4 x4 = *reinterpret_cast<const float4*>(iswih ? &xs[lane << 2] : &hs[lane << 2]);
        float d = bf2f(w4.x)*x4.x + bf2f(w4.y)*x4.y + bf2f(w4.z)*x4.z + bf2f(w4.w)*x4.w;
        #pragma unroll
        for (int off = 32; off; off >>= 1) d += __shfl_xor(d, off, 64);
        if (lane == 0) {
            if (iswih) {
                d += sgbih[g];
                gis[ll] = d;
                sgi[b*G3 + g] = d;
            } else {
                ghs[ll] = d + sgbhh[g];
            }
        }
    }
    __syncthreads();
    if (tid < 64) {
        const int e = (q << 6) + tid;
        float rg = sigm(gis[tid]       + ghs[tid]);
        float z  = sigm(gis[64 + tid]  + ghs[64 + tid]);
        float n  = tanhf(gis[128 + tid] + rg*ghs[128 + tid]);
        float hv = (1.f - z)*n + z*hs[e];
        sfout[b*EMB + e]  = hv;
        actseq[b*EMB + e] = fmaxf(hv, 0.f);
    }
}

extern "C" void kernel_launch(void* const* d_in, const int* in_sizes, int n_in,
                              void* d_out, int out_size, void* d_ws, size_t ws_size,
                              hipStream_t stream) {
    (void)in_sizes; (void)n_in; (void)out_size; (void)ws_size;
    const float* amino  = (const float*)d_in[0];
    const float* mask   = (const float*)d_in[1];
    const float* embW   = (const float*)d_in[2];
    const float* embB   = (const float*)d_in[3];
    const float* nbW    = (const float*)d_in[4];
    const float* nbB    = (const float*)d_in[5];
    const float* alignW = (const float*)d_in[6];
    const float* alignB = (const float*)d_in[7];
    const float* attW   = (const float*)d_in[8];
    const float* attB   = (const float*)d_in[9];
    const float* gwih   = (const float*)d_in[10];
    const float* gwhh   = (const float*)d_in[11];
    const float* gbih   = (const float*)d_in[12];
    const float* gbhh   = (const float*)d_in[13];
    const float* saW    = (const float*)d_in[14];
    const float* saB    = (const float*)d_in[15];
    const float* satW   = (const float*)d_in[16];
    const float* satB   = (const float*)d_in[17];
    const float* sgwih  = (const float*)d_in[18];
    const float* sgbih  = (const float*)d_in[19];
    const float* sgwhh  = (const float*)d_in[20];
    const float* sgbhh  = (const float*)d_in[21];
    const int*   idx    = (const int*)d_in[22];

    char* cur = (char*)d_ws;
    auto alloc = [&](size_t bytes) -> char* {
        char* p = cur; cur += (bytes + 255) & ~(size_t)255; return p;
    };
    float* feat    = (float*)alloc((size_t)BS*EMB*4);
    float* nbase   = (float*)alloc((size_t)BS*EMB*4);
    float* tf      = (float*)alloc((size_t)BS*EMB*4);
    float* cdot    = (float*)alloc(BS*4);
    float* ndot    = (float*)alloc(BS*4);   // doubles as ad after round 2
    float* seqfeat = (float*)alloc(BSZ*EMB*4);
    float* sf2     = (float*)alloc(BSZ*EMB*4);
    float* sgi     = (float*)alloc(BSZ*G3*4);
    float* partial = (float*)alloc((size_t)BSZ*16*EMB*4);
    ushort* aminobf  = (ushort*)alloc((size_t)BS*INITD*2);
    ushort* featbf   = (ushort*)alloc((size_t)BS*EMB*2);
    ushort* nbasebf  = (ushort*)alloc((size_t)BS*EMB*2);
    ushort* actbf    = (ushort*)alloc((size_t)BS*EMB*2);
    ushort* hbf      = (ushort*)alloc((size_t)BS*EMB*2);
    ushort* ctxbf    = (ushort*)alloc((size_t)BS*EMB*2);
    ushort* gibf     = (ushort*)alloc((size_t)BS*G3*2);
    ushort* ghbf     = (ushort*)alloc((size_t)BS*G3*2);
    ushort* embWbf   = (ushort*)alloc((size_t)EMB*INITD*2);
    ushort* nbWbf    = (ushort*)alloc((size_t)EMB*INITD*2);
    ushort* attWbf   = (ushort*)alloc((size_t)3*EMB*EMB*2);
    ushort* gwihbf   = (ushort*)alloc((size_t)3*G3*EMB*2);
    ushort* gwhhbf   = (ushort*)alloc((size_t)3*G3*EMB*2);
    ushort* satWbf   = (ushort*)alloc((size_t)EMB*EMB*2);
    ushort* sgwihbf  = (ushort*)alloc((size_t)G3*EMB*2);
    ushort* sgwhhbf  = (ushort*)alloc((size_t)G3*EMB*2);

    float* out    = (float*)d_out;
    float* actseq = out;               // (B,E)
    float* act    = out + BSZ*EMB;     // (B,S,E)

    convert_flat<<<2048, 256, 0, stream>>>(
        amino, aminobf, embW, embWbf, nbW, nbWbf, attW, attWbf,
        gwih, gwihbf, gwhh, gwhhbf, satW, satWbf,
        sgwih, sgwihbf, sgwhh, sgwhhbf, seqfeat);

    featnbase_kernel<<<256, 256, 0, stream>>>(
        aminobf, embWbf, embB, feat, featbf, nbWbf, nbB, nbase, nbasebf);

    dot2_kernel<<<128, 256, 0, stream>>>(feat, nbase, alignW, cdot, ndot);

    for (int d = 0; d < 3; ++d) {
        const ushort* nbrbf   = (d == 0) ? nbasebf : actbf;
        const ushort* hprevbf = (d == 0) ? featbf  : hbf;
        gatherattend_kernel<<<BS/16, 512, 0, stream>>>(
            cdot, ndot, idx, nbrbf, alignB + d,
            attWbf + (size_t)d*EMB*EMB, attB + d*EMB, ctxbf);
        gigh_kernel<<<768, 256, 0, stream>>>(
            ctxbf, gwihbf + (size_t)d*G3*EMB, gbih + d*G3, gibf,
            hprevbf, gwhhbf + (size_t)d*G3*EMB, gbhh + d*G3, ghbf);
        if (d < 2) {
            grudot_kernel<0><<<BS/16, 512, 0, stream>>>(
                gibf, ghbf, hprevbf, alignW + (d+1)*2*EMB, mask,
                hbf, act, actbf, cdot, ndot, seqfeat);
        } else {
            grudot_kernel<1><<<BS/16, 512, 0, stream>>>(
                gibf, ghbf, hprevbf, saW, mask,
                hbf, act, actbf, cdot, ndot, seqfeat);   // ndot <- ad
        }
    }

    seqpre_kernel<<<128, 256, 0, stream>>>(actbf, satWbf, satB, tf);
    seqpv2_kernel<<<dim3(16, BSZ), 256, 0, stream>>>(
        ndot, mask, saB, saW, seqfeat, tf, partial);
    seqstep_kernel<1><<<32, 512, 0, stream>>>(
        partial, seqfeat, sgwihbf, sgbih, sgwhhbf, sgbhh, sgi, sf2, actseq);
    seqstep_kernel<0><<<32, 512, 0, stream>>>(
        partial, sf2, sgwihbf, sgbih, sgwhhbf, sgbhh, sgi, seqfeat, actseq);
}